// Round 3
// baseline (1536.243 us; speedup 1.0000x reference)
//
#include <hip/hip_runtime.h>
#include <cmath>

constexpr int Bq = 8, Lq = 32768, Dq = 64, Nq = 16, NLq = 4;
constexpr int CLq = 64, NCq = 512;            // NCq*CLq == Lq
constexpr int PT = Bq * Lq / 16;              // 16384 position-tiles of 16

typedef _Float16 f16;
typedef _Float16 half4 __attribute__((ext_vector_type(4)));
typedef float f32x4 __attribute__((ext_vector_type(4)));
typedef float f32x2 __attribute__((ext_vector_type(2)));

static __device__ __forceinline__ float sigm(float x) { return 1.0f / (1.0f + __expf(-x)); }
static __device__ __forceinline__ float gelu_t(float x) {
  return x * sigm(1.5957691216057308f * fmaf(0.044715f * x * x, x, x));
}

// -------- setup: per (layer,d,n) lambda = exp(dtA), dC2 = 2*C*(lambda-1)/A, lambda^CL --------
__global__ __launch_bounds__(256) void k_setup(
    const float* __restrict__ log_dt, const float* __restrict__ log_A_real,
    const float* __restrict__ A_imag, const float* __restrict__ C_re,
    const float* __restrict__ C_im,
    f32x2* __restrict__ LAM, f32x2* __restrict__ DC2, f32x2* __restrict__ LCL) {
  int idx = blockIdx.x * 256 + threadIdx.x;
  if (idx >= NLq * Dq * Nq) return;
  int di = idx / Nq;
  float dt = expf(log_dt[di]);
  float Ar = -expf(log_A_real[idx]);
  float Ai = A_imag[idx];
  float dr = Ar * dt, dmi = Ai * dt;
  float er = expf(dr);
  float lr = er * cosf(dmi), li = er * sinf(dmi);
  float inv = 1.0f / (Ar * Ar + Ai * Ai);
  float e1r = lr - 1.0f, e1i = li;
  float qr = (e1r * Ar + e1i * Ai) * inv;
  float qi = (e1i * Ar - e1r * Ai) * inv;
  float cr = C_re[idx], ci = C_im[idx];
  LAM[idx] = f32x2{lr, li};
  DC2[idx] = f32x2{2.0f * (cr * qr - ci * qi), 2.0f * (cr * qi + ci * qr)};
  float erc = expf(dr * (float)CLq);
  LCL[idx] = f32x2{erc * cosf(dmi * (float)CLq), erc * sinf(dmi * (float)CLq)};
}

// -------- init: x = relu(w_init*in + b_init), write LN stats --------
__global__ __launch_bounds__(256) void k_init(
    const float* __restrict__ inp, const float* __restrict__ w_init,
    const float* __restrict__ b_init, float* __restrict__ X, f32x2* __restrict__ STATS) {
  int lane = threadIdx.x & 63;
  int wv = (blockIdx.x * 256 + threadIdx.x) >> 6;
  int nw = gridDim.x * 4;
  int pl = lane & 15, qh = lane >> 4;
  for (int pt = wv; pt < PT; pt += nw) {
    int pos = pt * 16 + pl;
    float v = inp[pos];
    float s = 0.f, s2 = 0.f;
#pragma unroll
    for (int q = 0; q < 4; q++) {
      int d0 = q * 16 + qh * 4;
      f32x4 w4 = *(const f32x4*)(w_init + d0);
      f32x4 b4 = *(const f32x4*)(b_init + d0);
      f32x4 o;
#pragma unroll
      for (int j = 0; j < 4; j++) {
        float t = fmaf(w4[j], v, b4[j]);
        t = t > 0.f ? t : 0.f;
        o[j] = t; s += t; s2 += t * t;
      }
      *(f32x4*)(X + (size_t)pos * 64 + d0) = o;
    }
    s += __shfl_xor(s, 16); s += __shfl_xor(s, 32);
    s2 += __shfl_xor(s2, 16); s2 += __shfl_xor(s2, 32);
    if (qh == 0) {
      float m = s * (1.0f / 64.0f);
      float var = s2 * (1.0f / 64.0f) - m * m;
      STATS[pos] = f32x2{m, rsqrtf(var + 1e-5f)};
    }
  }
}

// -------- pass1: per-chunk local scan, store end states --------
__global__ __launch_bounds__(256) void k_pass1(
    const float* __restrict__ X, const f32x2* __restrict__ STATS,
    const f32x2* __restrict__ LAM, const float* __restrict__ lnw,
    const float* __restrict__ lnb, f32x2* __restrict__ S) {
  int lane = threadIdx.x & 63;
  int w = blockIdx.x * 4 + (threadIdx.x >> 6);
  int b = w / NCq, c = w % NCq;
  int d = lane;
  float lr[16], li[16];
  const f32x2* lam = LAM + d * Nq;
#pragma unroll
  for (int n = 0; n < 16; n++) { f32x2 t = lam[n]; lr[n] = t.x; li[n] = t.y; }
  float wd = lnw[d], bd = lnb[d];
  float sr[16], si[16];
#pragma unroll
  for (int n = 0; n < 16; n++) { sr[n] = 0.f; si[n] = 0.f; }
  const float* xp = X + ((size_t)b * Lq + (size_t)c * CLq) * 64 + d;
  const f32x2* st = STATS + (b * Lq + c * CLq);
#pragma unroll 4
  for (int l = 0; l < CLq; l++) {
    float x = xp[(size_t)l * 64];
    f32x2 ms = st[l];
    float z = fmaf((x - ms.x) * ms.y, wd, bd);
#pragma unroll
    for (int n = 0; n < 16; n++) {
      float nr = fmaf(lr[n], sr[n], fmaf(-li[n], si[n], z));
      float ni = fmaf(lr[n], si[n], li[n] * sr[n]);
      sr[n] = nr; si[n] = ni;
    }
  }
  f32x2* outp = S + (size_t)((b * NCq + c) * 64 + d) * 16;
#pragma unroll
  for (int n = 0; n < 16; n++) outp[n] = f32x2{sr[n], si[n]};
}

// -------- pass2: sequential combine across chunks; replace S[c] with initial state --------
__global__ __launch_bounds__(256) void k_pass2(f32x2* __restrict__ S, const f32x2* __restrict__ LCL) {
  int tid = blockIdx.x * 256 + threadIdx.x;  // 8192 = B*D*N
  int n = tid & 15, d = (tid >> 4) & 63, b = tid >> 10;
  f32x2 lam = LCL[d * 16 + n];
  float cr = 0.f, ci = 0.f;
  for (int c = 0; c < NCq; c++) {
    int idx = ((b * NCq + c) * 64 + d) * 16 + n;
    f32x2 t = S[idx];
    S[idx] = f32x2{cr, ci};
    float nr = fmaf(lam.x, cr, fmaf(-lam.y, ci, t.x));
    float ni = fmaf(lam.x, ci, fmaf(lam.y, cr, t.y));
    cr = nr; ci = ni;
  }
}

// -------- pass3: rescan with carried init state, y = 2ReSum(dC*s)+Dskip*z, gelu, f16 out --------
__global__ __launch_bounds__(256) void k_pass3(
    const float* __restrict__ X, const f32x2* __restrict__ STATS, const f32x2* __restrict__ S,
    const f32x2* __restrict__ LAM, const f32x2* __restrict__ DC2,
    const float* __restrict__ lnw, const float* __restrict__ lnb,
    const float* __restrict__ dskip, f16* __restrict__ Y16) {
  int lane = threadIdx.x & 63;
  int w = blockIdx.x * 4 + (threadIdx.x >> 6);
  int b = w / NCq, c = w % NCq;
  int d = lane;
  float lr[16], li[16], cr2[16], ci2[16];
  const f32x2* lam = LAM + d * 16;
  const f32x2* dc = DC2 + d * 16;
#pragma unroll
  for (int n = 0; n < 16; n++) {
    f32x2 t = lam[n]; lr[n] = t.x; li[n] = t.y;
    f32x2 u = dc[n]; cr2[n] = u.x; ci2[n] = u.y;
  }
  float wd = lnw[d], bd = lnb[d], dk = dskip[d];
  float sr[16], si[16];
  const f32x2* s0 = S + (size_t)((b * NCq + c) * 64 + d) * 16;
#pragma unroll
  for (int n = 0; n < 16; n++) { f32x2 t = s0[n]; sr[n] = t.x; si[n] = t.y; }
  const float* xp = X + ((size_t)b * Lq + (size_t)c * CLq) * 64 + d;
  f16* yp = Y16 + ((size_t)b * Lq + (size_t)c * CLq) * 64 + d;
  const f32x2* st = STATS + (b * Lq + c * CLq);
#pragma unroll 2
  for (int l = 0; l < CLq; l++) {
    float x = xp[(size_t)l * 64];
    f32x2 ms = st[l];
    float z = fmaf((x - ms.x) * ms.y, wd, bd);
    float y = dk * z;
#pragma unroll
    for (int n = 0; n < 16; n++) {
      float nr = fmaf(lr[n], sr[n], fmaf(-li[n], si[n], z));
      float ni = fmaf(lr[n], si[n], li[n] * sr[n]);
      sr[n] = nr; si[n] = ni;
      y = fmaf(cr2[n], nr, fmaf(-ci2[n], ni, y));
    }
    yp[(size_t)l * 64] = (f16)gelu_t(y);
  }
}

// -------- fused GLU + FF block; weights fragment-packed in LDS --------
// LDS: sWg[8et][4ks][64lane] half4 (16KB), sW1 same (16KB), sW2[4dt][8ks][64lane] (16KB)
// floats @49152: bg[128], b1[128], b2[64], lnw[64], lnb[64] (1792B). Total 50944B -> 3 blocks/CU.
__global__ __launch_bounds__(256, 3) void k_gluff(
    const f16* __restrict__ Y16, const float* __restrict__ Wg, const float* __restrict__ bg,
    const float* __restrict__ W1, const float* __restrict__ b1,
    const float* __restrict__ W2, const float* __restrict__ b2,
    const float* __restrict__ lnw, const float* __restrict__ lnb,
    float* __restrict__ X, f32x2* __restrict__ STATS) {
  __shared__ __align__(16) unsigned char smemraw[50944];
  half4* sWg = (half4*)smemraw;          // 2048 slots
  half4* sW1 = sWg + 2048;
  half4* sW2 = sW1 + 2048;
  float* sf = (float*)(smemraw + 49152);
  int tid = threadIdx.x;
#pragma unroll
  for (int it = 0; it < 8; it++) {
    int s = it * 256 + tid;              // (et,ks,lane) slot for Wg/W1
    int ls = s & 63, ks = (s >> 6) & 3, et = s >> 8;
    int pls = ls & 15, qhs = ls >> 4;
    int off = (et * 16 + pls) * 64 + ks * 16 + qhs * 4;
    f32x4 w4 = *(const f32x4*)(Wg + off);
    sWg[s] = half4{(f16)w4[0], (f16)w4[1], (f16)w4[2], (f16)w4[3]};
    f32x4 u4 = *(const f32x4*)(W1 + off);
    sW1[s] = half4{(f16)u4[0], (f16)u4[1], (f16)u4[2], (f16)u4[3]};
    int ks2 = (s >> 6) & 7, dt = s >> 9;  // (dt,ks,lane) slot for W2
    f32x4 v4 = *(const f32x4*)(W2 + (dt * 16 + pls) * 128 + ks2 * 16 + qhs * 4);
    sW2[s] = half4{(f16)v4[0], (f16)v4[1], (f16)v4[2], (f16)v4[3]};
  }
  if (tid < 192) {
    float v;
    if (tid < 128) v = bg[tid];
    else v = b1[tid - 128 + 64];   // placeholder lane; real fill below
    (void)v;
  }
  // biases/LN params: 448 floats
  if (tid < 224) {
    int t2 = tid * 2;
    float v0, v1;
    if (t2 < 128)      { v0 = bg[t2];        v1 = bg[t2 + 1]; }
    else if (t2 < 256) { v0 = b1[t2 - 128];  v1 = b1[t2 - 127]; }
    else if (t2 < 320) { v0 = b2[t2 - 256];  v1 = b2[t2 - 255]; }
    else if (t2 < 384) { v0 = lnw[t2 - 320]; v1 = lnw[t2 - 319]; }
    else               { v0 = lnb[t2 - 384]; v1 = lnb[t2 - 383]; }
    sf[t2] = v0; sf[t2 + 1] = v1;
  }
  __syncthreads();

  int lane = tid & 63;
  int wv = (blockIdx.x * 256 + tid) >> 6;
  int nw = gridDim.x * 4;
  int pl = lane & 15, qh = lane >> 4;
  const float* bgF = sf;
  const float* b1F = sf + 128;
  const float* b2F = sf + 256;
  const float* lnwF = sf + 320;
  const float* lnbF = sf + 384;

  for (int pt = wv; pt < PT; pt += nw) {
    int pos = pt * 16 + pl;
    half4 yb[4];
#pragma unroll
    for (int ks = 0; ks < 4; ks++)
      yb[ks] = *(const half4*)(Y16 + (size_t)pos * 64 + ks * 16 + qh * 4);
    f32x4 xv[4];
#pragma unroll
    for (int q = 0; q < 4; q++)
      xv[q] = *(const f32x4*)(X + (size_t)pos * 64 + q * 16 + qh * 4);
    f32x4 accg[8];
#pragma unroll
    for (int et = 0; et < 8; et++) accg[et] = *(const f32x4*)(bgF + et * 16 + qh * 4);
#pragma unroll
    for (int ks = 0; ks < 4; ks++)
#pragma unroll
      for (int et = 0; et < 8; et++)
        accg[et] = __builtin_amdgcn_mfma_f32_16x16x16f16(sWg[(et * 4 + ks) * 64 + lane],
                                                         yb[ks], accg[et], 0, 0, 0);
    float s = 0.f, s2 = 0.f;
#pragma unroll
    for (int q = 0; q < 4; q++)
#pragma unroll
      for (int r = 0; r < 4; r++) {
        xv[q][r] += accg[q][r] * sigm(accg[q + 4][r]);
        s += xv[q][r]; s2 += xv[q][r] * xv[q][r];
      }
    s += __shfl_xor(s, 16); s += __shfl_xor(s, 32);
    s2 += __shfl_xor(s2, 16); s2 += __shfl_xor(s2, 32);
    float m = s * (1.0f / 64.0f);
    float rstd = rsqrtf(s2 * (1.0f / 64.0f) - m * m + 1e-5f);
    // FF
    half4 bf[4];
#pragma unroll
    for (int ks = 0; ks < 4; ks++) {
      f32x4 lw = *(const f32x4*)(lnwF + ks * 16 + qh * 4);
      f32x4 lb = *(const f32x4*)(lnbF + ks * 16 + qh * 4);
      f32x4 z;
#pragma unroll
      for (int j = 0; j < 4; j++) z[j] = fmaf((xv[ks][j] - m) * rstd, lw[j], lb[j]);
      bf[ks] = half4{(f16)z[0], (f16)z[1], (f16)z[2], (f16)z[3]};
    }
    f32x4 acc1[8];
#pragma unroll
    for (int et = 0; et < 8; et++) acc1[et] = *(const f32x4*)(b1F + et * 16 + qh * 4);
#pragma unroll
    for (int ks = 0; ks < 4; ks++)
#pragma unroll
      for (int et = 0; et < 8; et++)
        acc1[et] = __builtin_amdgcn_mfma_f32_16x16x16f16(sW1[(et * 4 + ks) * 64 + lane],
                                                         bf[ks], acc1[et], 0, 0, 0);
    half4 h2[8];
#pragma unroll
    for (int et = 0; et < 8; et++)
      h2[et] = half4{(f16)gelu_t(acc1[et][0]), (f16)gelu_t(acc1[et][1]),
                     (f16)gelu_t(acc1[et][2]), (f16)gelu_t(acc1[et][3])};
    f32x4 acc2[4];
#pragma unroll
    for (int dt = 0; dt < 4; dt++) acc2[dt] = *(const f32x4*)(b2F + dt * 16 + qh * 4);
#pragma unroll
    for (int ks = 0; ks < 8; ks++)
#pragma unroll
      for (int dt = 0; dt < 4; dt++)
        acc2[dt] = __builtin_amdgcn_mfma_f32_16x16x16f16(sW2[(dt * 8 + ks) * 64 + lane],
                                                         h2[ks], acc2[dt], 0, 0, 0);
    s = 0.f; s2 = 0.f;
#pragma unroll
    for (int dt = 0; dt < 4; dt++)
#pragma unroll
      for (int r = 0; r < 4; r++) {
        xv[dt][r] += acc2[dt][r];
        s += xv[dt][r]; s2 += xv[dt][r] * xv[dt][r];
      }
#pragma unroll
    for (int q = 0; q < 4; q++)
      *(f32x4*)(X + (size_t)pos * 64 + q * 16 + qh * 4) = xv[q];
    s += __shfl_xor(s, 16); s += __shfl_xor(s, 32);
    s2 += __shfl_xor(s2, 16); s2 += __shfl_xor(s2, 32);
    if (qh == 0) {
      float mm = s * (1.0f / 64.0f);
      float var = s2 * (1.0f / 64.0f) - mm * mm;
      STATS[pos] = f32x2{mm, rsqrtf(var + 1e-5f)};
    }
  }
}

// -------- head: z=LN(x,norm); r=relu(Wf z + bf); out = wz.r + bz --------
__global__ __launch_bounds__(256) void k_head(
    const float* __restrict__ X, const f32x2* __restrict__ STATS,
    const float* __restrict__ nw_, const float* __restrict__ nb_,
    const float* __restrict__ Wf, const float* __restrict__ bfb,
    const float* __restrict__ wz, const float* __restrict__ bz,
    float* __restrict__ outp) {
  int lane = threadIdx.x & 63;
  int wv = (blockIdx.x * 256 + threadIdx.x) >> 6;
  int nwv = gridDim.x * 4;
  int pl = lane & 15, qh = lane >> 4;
  half4 af[4][4];
#pragma unroll
  for (int et = 0; et < 4; et++)
#pragma unroll
    for (int ks = 0; ks < 4; ks++) {
      f32x4 w4 = *(const f32x4*)(Wf + (et * 16 + pl) * 64 + ks * 16 + qh * 4);
      af[et][ks] = half4{(f16)w4[0], (f16)w4[1], (f16)w4[2], (f16)w4[3]};
    }
  float bz0 = bz[0];
  for (int pt = wv; pt < PT; pt += nwv) {
    int pos = pt * 16 + pl;
    f32x2 ms = STATS[pos];
    half4 bf[4];
#pragma unroll
    for (int ks = 0; ks < 4; ks++) {
      f32x4 x4 = *(const f32x4*)(X + (size_t)pos * 64 + ks * 16 + qh * 4);
      f32x4 lw = *(const f32x4*)(nw_ + ks * 16 + qh * 4);
      f32x4 lb = *(const f32x4*)(nb_ + ks * 16 + qh * 4);
      f32x4 z;
#pragma unroll
      for (int j = 0; j < 4; j++) z[j] = fmaf((x4[j] - ms.x) * ms.y, lw[j], lb[j]);
      bf[ks] = half4{(f16)z[0], (f16)z[1], (f16)z[2], (f16)z[3]};
    }
    f32x4 acc[4];
#pragma unroll
    for (int et = 0; et < 4; et++) acc[et] = *(const f32x4*)(bfb + et * 16 + qh * 4);
#pragma unroll
    for (int ks = 0; ks < 4; ks++)
#pragma unroll
      for (int et = 0; et < 4; et++)
        acc[et] = __builtin_amdgcn_mfma_f32_16x16x16f16(af[et][ks], bf[ks], acc[et], 0, 0, 0);
    float o = 0.f;
#pragma unroll
    for (int et = 0; et < 4; et++) {
      f32x4 wzv = *(const f32x4*)(wz + et * 16 + qh * 4);
#pragma unroll
      for (int r = 0; r < 4; r++) {
        float rv = acc[et][r];
        rv = rv > 0.f ? rv : 0.f;
        o = fmaf(wzv[r], rv, o);
      }
    }
    o += __shfl_xor(o, 16); o += __shfl_xor(o, 32);
    if (qh == 0) outp[pos] = o + bz0;
  }
}

extern "C" void kernel_launch(void* const* d_in, const int* in_sizes, int n_in,
                              void* d_out, int out_size, void* d_ws, size_t ws_size,
                              hipStream_t stream) {
  (void)in_sizes; (void)n_in; (void)out_size; (void)ws_size;
  const float* inputs   = (const float*)d_in[0];
  const float* w_init   = (const float*)d_in[1];
  const float* b_init   = (const float*)d_in[2];
  const float* s4_ln_w  = (const float*)d_in[3];
  const float* s4_ln_b  = (const float*)d_in[4];
  const float* log_dt   = (const float*)d_in[5];
  const float* log_A    = (const float*)d_in[6];
  const float* A_imag   = (const float*)d_in[7];
  const float* C_re     = (const float*)d_in[8];
  const float* C_im     = (const float*)d_in[9];
  const float* D_skip   = (const float*)d_in[10];
  const float* s4_out_w = (const float*)d_in[11];
  const float* s4_out_b = (const float*)d_in[12];
  const float* ff_ln_w  = (const float*)d_in[13];
  const float* ff_ln_b  = (const float*)d_in[14];
  const float* ff_w1    = (const float*)d_in[15];
  const float* ff_b1    = (const float*)d_in[16];
  const float* ff_w2    = (const float*)d_in[17];
  const float* ff_b2    = (const float*)d_in[18];
  const float* norm_w   = (const float*)d_in[19];
  const float* norm_b   = (const float*)d_in[20];
  const float* w_final1 = (const float*)d_in[21];
  const float* b_final1 = (const float*)d_in[22];
  const float* w_zero   = (const float*)d_in[23];
  const float* b_zero   = (const float*)d_in[24];

  char* w8 = (char*)d_ws;
  float* X    = (float*)w8;                                   // 64 MiB
  f16*   Y16  = (f16*)(w8 + (size_t)67108864);                // 32 MiB
  f32x2* S    = (f32x2*)(w8 + (size_t)67108864 + 33554432);   // 32 MiB
  f32x2* STATS= (f32x2*)(w8 + (size_t)67108864 + 33554432 + 33554432);  // 2 MiB
  f32x2* LAM  = STATS + (size_t)Bq * Lq;
  f32x2* DC2  = LAM + NLq * Dq * Nq;
  f32x2* LCL  = DC2 + NLq * Dq * Nq;

  k_setup<<<16, 256, 0, stream>>>(log_dt, log_A, A_imag, C_re, C_im, LAM, DC2, LCL);
  k_init<<<2048, 256, 0, stream>>>(inputs, w_init, b_init, X, STATS);
  for (int i = 0; i < NLq; i++) {
    k_pass1<<<Bq * NCq / 4, 256, 0, stream>>>(X, STATS, LAM + i * Dq * Nq,
                                              s4_ln_w + i * Dq, s4_ln_b + i * Dq, S);
    k_pass2<<<Bq * Dq * Nq / 256, 256, 0, stream>>>(S, LCL + i * Dq * Nq);
    k_pass3<<<Bq * NCq / 4, 256, 0, stream>>>(X, STATS, S, LAM + i * Dq * Nq, DC2 + i * Dq * Nq,
                                              s4_ln_w + i * Dq, s4_ln_b + i * Dq,
                                              D_skip + i * Dq, Y16);
    k_gluff<<<1024, 256, 0, stream>>>(Y16, s4_out_w + i * 128 * 64, s4_out_b + i * 128,
                                      ff_w1 + i * 128 * 64, ff_b1 + i * 128,
                                      ff_w2 + i * 64 * 128, ff_b2 + i * 64,
                                      ff_ln_w + i * Dq, ff_ln_b + i * Dq, X, STATS);
  }
  k_head<<<2048, 256, 0, stream>>>(X, STATS, norm_w, norm_b, w_final1, b_final1,
                                   w_zero, b_zero, (float*)d_out);
}

// Round 4
// 898.472 us; speedup vs baseline: 1.7098x; 1.7098x over previous
//
#include <hip/hip_runtime.h>
#include <cmath>

constexpr int Bq = 8, Lq = 32768, Dq = 64, Nq = 16, NLq = 4;
constexpr int CLq = 64, NCq = 512;            // NCq*CLq == Lq
constexpr int PT = Bq * Lq / 16;              // 16384 position-tiles of 16

typedef _Float16 f16;
typedef _Float16 half4 __attribute__((ext_vector_type(4)));
typedef _Float16 half8 __attribute__((ext_vector_type(8)));
typedef float f32x4 __attribute__((ext_vector_type(4)));
typedef float f32x2 __attribute__((ext_vector_type(2)));

static __device__ __forceinline__ float sigm(float x) { return 1.0f / (1.0f + __expf(-x)); }
static __device__ __forceinline__ float gelu_t(float x) {
  return x * sigm(1.5957691216057308f * fmaf(0.044715f * x * x, x, x));
}

// -------- setup: lambda = exp(dtA), dC2 = 2*C*(lambda-1)/A, lambda^CL, lambda^(64*CL) --------
__global__ __launch_bounds__(256) void k_setup(
    const float* __restrict__ log_dt, const float* __restrict__ log_A_real,
    const float* __restrict__ A_imag, const float* __restrict__ C_re,
    const float* __restrict__ C_im,
    f32x2* __restrict__ LAM, f32x2* __restrict__ DC2, f32x2* __restrict__ LCL,
    f32x2* __restrict__ LC64) {
  int idx = blockIdx.x * 256 + threadIdx.x;
  if (idx >= NLq * Dq * Nq) return;
  int di = idx / Nq;
  float dt = expf(log_dt[di]);
  float Ar = -expf(log_A_real[idx]);
  float Ai = A_imag[idx];
  float dr = Ar * dt, dmi = Ai * dt;
  float er = expf(dr);
  float lr = er * cosf(dmi), li = er * sinf(dmi);
  float inv = 1.0f / (Ar * Ar + Ai * Ai);
  float e1r = lr - 1.0f, e1i = li;
  float qr = (e1r * Ar + e1i * Ai) * inv;
  float qi = (e1i * Ar - e1r * Ai) * inv;
  float cr = C_re[idx], ci = C_im[idx];
  LAM[idx] = f32x2{lr, li};
  DC2[idx] = f32x2{2.0f * (cr * qr - ci * qi), 2.0f * (cr * qi + ci * qr)};
  float erc = expf(dr * (float)CLq);
  LCL[idx] = f32x2{erc * cosf(dmi * (float)CLq), erc * sinf(dmi * (float)CLq)};
  float e64 = expf(dr * (float)(CLq * 64));
  LC64[idx] = f32x2{e64 * cosf(dmi * (float)(CLq * 64)), e64 * sinf(dmi * (float)(CLq * 64))};
}

// -------- init: x = relu(w_init*in + b_init), write LN stats --------
__global__ __launch_bounds__(256) void k_init(
    const float* __restrict__ inp, const float* __restrict__ w_init,
    const float* __restrict__ b_init, float* __restrict__ X, f32x2* __restrict__ STATS) {
  int lane = threadIdx.x & 63;
  int wv = (blockIdx.x * 256 + threadIdx.x) >> 6;
  int nw = gridDim.x * 4;
  int pl = lane & 15, qh = lane >> 4;
  for (int pt = wv; pt < PT; pt += nw) {
    int pos = pt * 16 + pl;
    float v = inp[pos];
    float s = 0.f, s2 = 0.f;
#pragma unroll
    for (int q = 0; q < 4; q++) {
      int d0 = q * 16 + qh * 4;
      f32x4 w4 = *(const f32x4*)(w_init + d0);
      f32x4 b4 = *(const f32x4*)(b_init + d0);
      f32x4 o;
#pragma unroll
      for (int j = 0; j < 4; j++) {
        float t = fmaf(w4[j], v, b4[j]);
        t = t > 0.f ? t : 0.f;
        o[j] = t; s += t; s2 += t * t;
      }
      *(f32x4*)(X + (size_t)pos * 64 + d0) = o;
    }
    s += __shfl_xor(s, 16); s += __shfl_xor(s, 32);
    s2 += __shfl_xor(s2, 16); s2 += __shfl_xor(s2, 32);
    if (qh == 0) {
      float m = s * (1.0f / 64.0f);
      float var = s2 * (1.0f / 64.0f) - m * m;
      STATS[pos] = f32x2{m, rsqrtf(var + 1e-5f)};
    }
  }
}

// -------- pass1: per-chunk local scan, store end states --------
__global__ __launch_bounds__(256) void k_pass1(
    const float* __restrict__ X, const f32x2* __restrict__ STATS,
    const f32x2* __restrict__ LAM, const float* __restrict__ lnw,
    const float* __restrict__ lnb, f32x2* __restrict__ S) {
  int lane = threadIdx.x & 63;
  int w = blockIdx.x * 4 + (threadIdx.x >> 6);
  int b = w / NCq, c = w % NCq;
  int d = lane;
  float lr[16], li[16];
  const f32x2* lam = LAM + d * Nq;
#pragma unroll
  for (int n = 0; n < 16; n++) { f32x2 t = lam[n]; lr[n] = t.x; li[n] = t.y; }
  float wd = lnw[d], bd = lnb[d];
  float sr[16], si[16];
#pragma unroll
  for (int n = 0; n < 16; n++) { sr[n] = 0.f; si[n] = 0.f; }
  const float* xp = X + ((size_t)b * Lq + (size_t)c * CLq) * 64 + d;
  const f32x2* st = STATS + (b * Lq + c * CLq);
#pragma unroll 4
  for (int l = 0; l < CLq; l++) {
    float x = xp[(size_t)l * 64];
    f32x2 ms = st[l];
    float z = fmaf((x - ms.x) * ms.y, wd, bd);
#pragma unroll
    for (int n = 0; n < 16; n++) {
      float nr = fmaf(lr[n], sr[n], fmaf(-li[n], si[n], z));
      float ni = fmaf(lr[n], si[n], li[n] * sr[n]);
      sr[n] = nr; si[n] = ni;
    }
  }
  f32x2* outp = S + (size_t)((b * NCq + c) * 64 + d) * 16;
#pragma unroll
  for (int n = 0; n < 16; n++) outp[n] = f32x2{sr[n], si[n]};
}

// -------- pass2a: local scan over 64-chunk groups (in-place exclusive), write group totals --------
__global__ __launch_bounds__(256) void k_pass2a(
    f32x2* __restrict__ S, const f32x2* __restrict__ LCL, f32x2* __restrict__ G) {
  int lane = threadIdx.x & 63;
  int w = blockIdx.x * 4 + (threadIdx.x >> 6);  // 1024 waves: (b, g, dblock)
  int dblock = w & 15, g = (w >> 4) & 7, b = w >> 7;
  int dn = dblock * 64 + lane;                  // d*16 + n
  f32x2 lam = LCL[dn];
  float cr = 0.f, ci = 0.f;
  size_t base = (size_t)(b * NCq + g * 64) * 1024 + dn;
#pragma unroll 8
  for (int j = 0; j < 64; j++) {
    f32x2 t = S[base + (size_t)j * 1024];
    S[base + (size_t)j * 1024] = f32x2{cr, ci};
    float nr = fmaf(lam.x, cr, fmaf(-lam.y, ci, t.x));
    float ni = fmaf(lam.x, ci, fmaf(lam.y, cr, t.y));
    cr = nr; ci = ni;
  }
  G[(size_t)(b * 8 + g) * 1024 + dn] = f32x2{cr, ci};
}

// -------- pass2b: combine 8 group totals -> exclusive group carries (in-place) --------
__global__ __launch_bounds__(256) void k_pass2b(
    f32x2* __restrict__ G, const f32x2* __restrict__ LC64) {
  int tid = blockIdx.x * 256 + threadIdx.x;  // 8192
  int dn = tid & 1023, b = tid >> 10;
  f32x2 lam = LC64[dn];
  float cr = 0.f, ci = 0.f;
#pragma unroll
  for (int g = 0; g < 8; g++) {
    size_t idx = (size_t)(b * 8 + g) * 1024 + dn;
    f32x2 t = G[idx];
    G[idx] = f32x2{cr, ci};
    float nr = fmaf(lam.x, cr, fmaf(-lam.y, ci, t.x));
    float ni = fmaf(lam.x, ci, fmaf(lam.y, cr, t.y));
    cr = nr; ci = ni;
  }
}

// -------- pass3: rescan; init = S_local + lam_CL^j * C_group; y=2ReSum(dC*s)+Dskip*z, gelu --------
__global__ __launch_bounds__(256) void k_pass3(
    const float* __restrict__ X, const f32x2* __restrict__ STATS, const f32x2* __restrict__ S,
    const f32x2* __restrict__ LAM, const f32x2* __restrict__ DC2,
    const f32x2* __restrict__ LCL, const f32x2* __restrict__ G,
    const float* __restrict__ lnw, const float* __restrict__ lnb,
    const float* __restrict__ dskip, f16* __restrict__ Y16) {
  int lane = threadIdx.x & 63;
  int w = blockIdx.x * 4 + (threadIdx.x >> 6);
  int b = w / NCq, c = w % NCq;
  int d = lane;
  float lr[16], li[16], cr2[16], ci2[16];
  const f32x2* lam = LAM + d * 16;
  const f32x2* dc = DC2 + d * 16;
#pragma unroll
  for (int n = 0; n < 16; n++) {
    f32x2 t = lam[n]; lr[n] = t.x; li[n] = t.y;
    f32x2 u = dc[n]; cr2[n] = u.x; ci2[n] = u.y;
  }
  float wd = lnw[d], bd = lnb[d], dk = dskip[d];
  float sr[16], si[16];
  const f32x2* s0 = S + (size_t)((b * NCq + c) * 64 + d) * 16;
#pragma unroll
  for (int n = 0; n < 16; n++) { f32x2 t = s0[n]; sr[n] = t.x; si[n] = t.y; }
  // add group-carry correction: lam_CL^j * C
  {
    int g = c >> 6, j = c & 63;
    const f32x2* Cp = G + (size_t)(b * 8 + g) * 1024 + d * 16;
    const f32x2* lclp = LCL + d * 16;
#pragma unroll
    for (int n = 0; n < 16; n++) {
      f32x2 lc = lclp[n];
      float pr = 1.f, pi = 0.f, br = lc.x, bi = lc.y;
      int e = j;
      while (e) {
        if (e & 1) { float t = pr * br - pi * bi; pi = fmaf(pr, bi, pi * br); pr = t; }
        float t2 = br * br - bi * bi; bi = 2.f * br * bi; br = t2;
        e >>= 1;
      }
      f32x2 C = Cp[n];
      sr[n] = fmaf(pr, C.x, fmaf(-pi, C.y, sr[n]));
      si[n] = fmaf(pr, C.y, fmaf(pi, C.x, si[n]));
    }
  }
  const float* xp = X + ((size_t)b * Lq + (size_t)c * CLq) * 64 + d;
  f16* yp = Y16 + ((size_t)b * Lq + (size_t)c * CLq) * 64 + d;
  const f32x2* st = STATS + (b * Lq + c * CLq);
#pragma unroll 2
  for (int l = 0; l < CLq; l++) {
    float x = xp[(size_t)l * 64];
    f32x2 ms = st[l];
    float z = fmaf((x - ms.x) * ms.y, wd, bd);
    float y = dk * z;
#pragma unroll
    for (int n = 0; n < 16; n++) {
      float nr = fmaf(lr[n], sr[n], fmaf(-li[n], si[n], z));
      float ni = fmaf(lr[n], si[n], li[n] * sr[n]);
      sr[n] = nr; si[n] = ni;
      y = fmaf(cr2[n], nr, fmaf(-ci2[n], ni, y));
    }
    yp[(size_t)l * 64] = (f16)gelu_t(y);
  }
}

// ======== GLU kernel: u = Wg@y + bg; x += u_a*sigm(u_g); write ff-LN stats ========
// Weights in LDS as MFMA fragments; per-tile opaque offset defeats LICM (anti-spill).
__device__ __forceinline__ void glu_tile(
    int pos, half8 yb0, half8 yb1, f32x4* xv, const char* smembase,
    int qh, int lane, float* __restrict__ X, f32x2* __restrict__ STATS) {
  unsigned sb = 0;
  asm volatile("" : "+v"(sb));                  // opaque: forces per-tile LDS re-reads
  const char* sm = smembase + sb;
  const half8* sW = (const half8*)sm;           // [(et*2+ks)*64 + lane]
  const float* bgF = (const float*)(sm + 16384);
  f32x4 acc[8];
#pragma unroll
  for (int et = 0; et < 8; et++) acc[et] = *(const f32x4*)(bgF + et * 16 + qh * 4);
#pragma unroll
  for (int et = 0; et < 8; et++)
    acc[et] = __builtin_amdgcn_mfma_f32_16x16x32_f16(sW[(et * 2) * 64 + lane], yb0, acc[et], 0, 0, 0);
#pragma unroll
  for (int et = 0; et < 8; et++)
    acc[et] = __builtin_amdgcn_mfma_f32_16x16x32_f16(sW[(et * 2 + 1) * 64 + lane], yb1, acc[et], 0, 0, 0);
  float s = 0.f, s2 = 0.f;
#pragma unroll
  for (int q = 0; q < 4; q++) {
#pragma unroll
    for (int r = 0; r < 4; r++) {
      xv[q][r] += acc[q][r] * sigm(acc[q + 4][r]);
      s += xv[q][r]; s2 += xv[q][r] * xv[q][r];
    }
    *(f32x4*)(X + (size_t)pos * 64 + q * 16 + qh * 4) = xv[q];
  }
  s += __shfl_xor(s, 16); s += __shfl_xor(s, 32);
  s2 += __shfl_xor(s2, 16); s2 += __shfl_xor(s2, 32);
  if (qh == 0) {
    float m = s * (1.0f / 64.0f);
    float var = s2 * (1.0f / 64.0f) - m * m;
    STATS[pos] = f32x2{m, rsqrtf(var + 1e-5f)};
  }
}

__global__ __launch_bounds__(256) void k_glu(
    const f16* __restrict__ Y16, const float* __restrict__ Wg, const float* __restrict__ bg,
    float* __restrict__ X, f32x2* __restrict__ STATS) {
  __shared__ __align__(16) char smem[16896];
  int tid = threadIdx.x;
#pragma unroll
  for (int it = 0; it < 4; it++) {
    int s = it * 256 + tid;
    int l = s & 63, ks = (s >> 6) & 1, et = s >> 7;
    const float* wp = Wg + (et * 16 + (l & 15)) * 64 + ks * 32 + (l >> 4) * 8;
    f32x4 w0 = *(const f32x4*)wp, w1 = *(const f32x4*)(wp + 4);
    *(half8*)(smem + s * 16) = half8{(f16)w0[0], (f16)w0[1], (f16)w0[2], (f16)w0[3],
                                     (f16)w1[0], (f16)w1[1], (f16)w1[2], (f16)w1[3]};
  }
  if (tid < 128) ((float*)(smem + 16384))[tid] = bg[tid];
  __syncthreads();
  int lane = tid & 63, pl = lane & 15, qh = lane >> 4;
  int wv = (blockIdx.x * 256 + tid) >> 6, nw = gridDim.x * 4;
  for (int pt = wv; pt < PT; pt += 2 * nw) {
    int ptB = pt + nw;
    bool hasB = ptB < PT;
    int posA = pt * 16 + pl, posB = ptB * 16 + pl;
    half8 ybA0 = *(const half8*)(Y16 + (size_t)posA * 64 + qh * 8);
    half8 ybA1 = *(const half8*)(Y16 + (size_t)posA * 64 + 32 + qh * 8);
    f32x4 xvA[4];
#pragma unroll
    for (int q = 0; q < 4; q++) xvA[q] = *(const f32x4*)(X + (size_t)posA * 64 + q * 16 + qh * 4);
    half8 ybB0{}, ybB1{};
    f32x4 xvB[4];
    if (hasB) {
      ybB0 = *(const half8*)(Y16 + (size_t)posB * 64 + qh * 8);
      ybB1 = *(const half8*)(Y16 + (size_t)posB * 64 + 32 + qh * 8);
#pragma unroll
      for (int q = 0; q < 4; q++) xvB[q] = *(const f32x4*)(X + (size_t)posB * 64 + q * 16 + qh * 4);
    }
    glu_tile(posA, ybA0, ybA1, xvA, smem, qh, lane, X, STATS);
    if (hasB) glu_tile(posB, ybB0, ybB1, xvB, smem, qh, lane, X, STATS);
  }
}

// ======== FF kernel: z=LN(x); h=gelu(W1 z + b1); x += W2 h + b2; write next s4-LN stats ========
__device__ __forceinline__ void ff_tile(
    int pos, f32x2 st, const f32x4* xb, f32x4* xv, const char* smembase,
    int qh, int lane, float* __restrict__ X, f32x2* __restrict__ STATS) {
  unsigned sb = 0;
  asm volatile("" : "+v"(sb));
  const char* sm = smembase + sb;
  const half8* sW1 = (const half8*)sm;                 // [(et*2+ks)*64 + lane]
  const half4* sW2 = (const half4*)(sm + 16384);       // [(dt*8+ks)*64 + lane]
  const float* sf = (const float*)(sm + 32768);
  const float* b1F = sf;
  const float* b2F = sf + 128;
  const float* lnwF = sf + 192;
  const float* lnbF = sf + 256;
  float m = st.x, rs = st.y;
  half8 zb[2];
#pragma unroll
  for (int ks = 0; ks < 2; ks++) {
    f32x4 lw0 = *(const f32x4*)(lnwF + ks * 32 + qh * 8);
    f32x4 lw1 = *(const f32x4*)(lnwF + ks * 32 + qh * 8 + 4);
    f32x4 lb0 = *(const f32x4*)(lnbF + ks * 32 + qh * 8);
    f32x4 lb1 = *(const f32x4*)(lnbF + ks * 32 + qh * 8 + 4);
    f32x4 x0 = xb[ks * 2], x1 = xb[ks * 2 + 1];
    half8 z;
#pragma unroll
    for (int jj = 0; jj < 4; jj++) {
      z[jj] = (f16)fmaf((x0[jj] - m) * rs, lw0[jj], lb0[jj]);
      z[jj + 4] = (f16)fmaf((x1[jj] - m) * rs, lw1[jj], lb1[jj]);
    }
    zb[ks] = z;
  }
  f32x4 acc1[8];
#pragma unroll
  for (int et = 0; et < 8; et++) acc1[et] = *(const f32x4*)(b1F + et * 16 + qh * 4);
#pragma unroll
  for (int ks = 0; ks < 2; ks++)
#pragma unroll
    for (int et = 0; et < 8; et++)
      acc1[et] = __builtin_amdgcn_mfma_f32_16x16x32_f16(sW1[(et * 2 + ks) * 64 + lane], zb[ks], acc1[et], 0, 0, 0);
  half4 h2[8];
#pragma unroll
  for (int et = 0; et < 8; et++)
    h2[et] = half4{(f16)gelu_t(acc1[et][0]), (f16)gelu_t(acc1[et][1]),
                   (f16)gelu_t(acc1[et][2]), (f16)gelu_t(acc1[et][3])};
  f32x4 acc2[4];
#pragma unroll
  for (int dt = 0; dt < 4; dt++) acc2[dt] = *(const f32x4*)(b2F + dt * 16 + qh * 4);
#pragma unroll
  for (int ks = 0; ks < 8; ks++)
#pragma unroll
    for (int dt = 0; dt < 4; dt++)
      acc2[dt] = __builtin_amdgcn_mfma_f32_16x16x16f16(sW2[(dt * 8 + ks) * 64 + lane], h2[ks], acc2[dt], 0, 0, 0);
  float s = 0.f, s2 = 0.f;
#pragma unroll
  for (int dt = 0; dt < 4; dt++) {
#pragma unroll
    for (int r = 0; r < 4; r++) {
      xv[dt][r] += acc2[dt][r];
      s += xv[dt][r]; s2 += xv[dt][r] * xv[dt][r];
    }
    *(f32x4*)(X + (size_t)pos * 64 + dt * 16 + qh * 4) = xv[dt];
  }
  s += __shfl_xor(s, 16); s += __shfl_xor(s, 32);
  s2 += __shfl_xor(s2, 16); s2 += __shfl_xor(s2, 32);
  if (qh == 0) {
    float mm = s * (1.0f / 64.0f);
    float var = s2 * (1.0f / 64.0f) - mm * mm;
    STATS[pos] = f32x2{mm, rsqrtf(var + 1e-5f)};
  }
}

__global__ __launch_bounds__(256) void k_ff(
    const float* __restrict__ W1, const float* __restrict__ b1,
    const float* __restrict__ W2, const float* __restrict__ b2,
    const float* __restrict__ lnw, const float* __restrict__ lnb,
    float* __restrict__ X, f32x2* __restrict__ STATS) {
  __shared__ __align__(16) char smem[34048];
  int tid = threadIdx.x;
#pragma unroll
  for (int it = 0; it < 4; it++) {
    int s = it * 256 + tid;
    int l = s & 63, ks = (s >> 6) & 1, et = s >> 7;
    const float* wp = W1 + (et * 16 + (l & 15)) * 64 + ks * 32 + (l >> 4) * 8;
    f32x4 w0 = *(const f32x4*)wp, w1 = *(const f32x4*)(wp + 4);
    *(half8*)(smem + s * 16) = half8{(f16)w0[0], (f16)w0[1], (f16)w0[2], (f16)w0[3],
                                     (f16)w1[0], (f16)w1[1], (f16)w1[2], (f16)w1[3]};
  }
#pragma unroll
  for (int it = 0; it < 8; it++) {
    int s = it * 256 + tid;
    int l = s & 63, ks = (s >> 6) & 7, dt = s >> 9;
    const float* wp = W2 + (dt * 16 + (l & 15)) * 128 + ks * 16 + (l >> 4) * 4;
    f32x4 w0 = *(const f32x4*)wp;
    *(half4*)(smem + 16384 + s * 8) = half4{(f16)w0[0], (f16)w0[1], (f16)w0[2], (f16)w0[3]};
  }
  for (int idx = tid; idx < 320; idx += 256) {
    float v;
    if (idx < 128) v = b1[idx];
    else if (idx < 192) v = b2[idx - 128];
    else if (idx < 256) v = lnw[idx - 192];
    else v = lnb[idx - 256];
    ((float*)(smem + 32768))[idx] = v;
  }
  __syncthreads();
  int lane = tid & 63, pl = lane & 15, qh = lane >> 4;
  int wv = (blockIdx.x * 256 + tid) >> 6, nw = gridDim.x * 4;
  for (int pt = wv; pt < PT; pt += 2 * nw) {
    int ptB = pt + nw;
    bool hasB = ptB < PT;
    int posA = pt * 16 + pl, posB = ptB * 16 + pl;
    f32x2 stA = STATS[posA];
    f32x4 xbA[4], xvA[4];
#pragma unroll
    for (int k = 0; k < 2; k++) {
      xbA[k * 2] = *(const f32x4*)(X + (size_t)posA * 64 + k * 32 + qh * 8);
      xbA[k * 2 + 1] = *(const f32x4*)(X + (size_t)posA * 64 + k * 32 + qh * 8 + 4);
    }
#pragma unroll
    for (int q = 0; q < 4; q++) xvA[q] = *(const f32x4*)(X + (size_t)posA * 64 + q * 16 + qh * 4);
    f32x2 stB{0.f, 0.f};
    f32x4 xbB[4], xvB[4];
    if (hasB) {
      stB = STATS[posB];
#pragma unroll
      for (int k = 0; k < 2; k++) {
        xbB[k * 2] = *(const f32x4*)(X + (size_t)posB * 64 + k * 32 + qh * 8);
        xbB[k * 2 + 1] = *(const f32x4*)(X + (size_t)posB * 64 + k * 32 + qh * 8 + 4);
      }
#pragma unroll
      for (int q = 0; q < 4; q++) xvB[q] = *(const f32x4*)(X + (size_t)posB * 64 + q * 16 + qh * 4);
    }
    ff_tile(posA, stA, xbA, xvA, smem, qh, lane, X, STATS);
    if (hasB) ff_tile(posB, stB, xbB, xvB, smem, qh, lane, X, STATS);
  }
}

// -------- head: z=LN(x,norm); r=relu(Wf z + bf); out = wz.r + bz --------
__global__ __launch_bounds__(256) void k_head(
    const float* __restrict__ X, const f32x2* __restrict__ STATS,
    const float* __restrict__ nw_, const float* __restrict__ nb_,
    const float* __restrict__ Wf, const float* __restrict__ bfb,
    const float* __restrict__ wz, const float* __restrict__ bz,
    float* __restrict__ outp) {
  int lane = threadIdx.x & 63;
  int wv = (blockIdx.x * 256 + threadIdx.x) >> 6;
  int nwv = gridDim.x * 4;
  int pl = lane & 15, qh = lane >> 4;
  half4 af[4][4];
#pragma unroll
  for (int et = 0; et < 4; et++)
#pragma unroll
    for (int ks = 0; ks < 4; ks++) {
      f32x4 w4 = *(const f32x4*)(Wf + (et * 16 + pl) * 64 + ks * 16 + qh * 4);
      af[et][ks] = half4{(f16)w4[0], (f16)w4[1], (f16)w4[2], (f16)w4[3]};
    }
  float bz0 = bz[0];
  for (int pt = wv; pt < PT; pt += nwv) {
    int pos = pt * 16 + pl;
    f32x2 ms = STATS[pos];
    half4 bf[4];
#pragma unroll
    for (int ks = 0; ks < 4; ks++) {
      f32x4 x4 = *(const f32x4*)(X + (size_t)pos * 64 + ks * 16 + qh * 4);
      f32x4 lw = *(const f32x4*)(nw_ + ks * 16 + qh * 4);
      f32x4 lb = *(const f32x4*)(nb_ + ks * 16 + qh * 4);
      f32x4 z;
#pragma unroll
      for (int j = 0; j < 4; j++) z[j] = fmaf((x4[j] - ms.x) * ms.y, lw[j], lb[j]);
      bf[ks] = half4{(f16)z[0], (f16)z[1], (f16)z[2], (f16)z[3]};
    }
    f32x4 acc[4];
#pragma unroll
    for (int et = 0; et < 4; et++) acc[et] = *(const f32x4*)(bfb + et * 16 + qh * 4);
#pragma unroll
    for (int ks = 0; ks < 4; ks++)
#pragma unroll
      for (int et = 0; et < 4; et++)
        acc[et] = __builtin_amdgcn_mfma_f32_16x16x16f16(af[et][ks], bf[ks], acc[et], 0, 0, 0);
    float o = 0.f;
#pragma unroll
    for (int et = 0; et < 4; et++) {
      f32x4 wzv = *(const f32x4*)(wz + et * 16 + qh * 4);
#pragma unroll
      for (int r = 0; r < 4; r++) {
        float rv = acc[et][r];
        rv = rv > 0.f ? rv : 0.f;
        o = fmaf(wzv[r], rv, o);
      }
    }
    o += __shfl_xor(o, 16); o += __shfl_xor(o, 32);
    if (qh == 0) outp[pos] = o + bz0;
  }
}

extern "C" void kernel_launch(void* const* d_in, const int* in_sizes, int n_in,
                              void* d_out, int out_size, void* d_ws, size_t ws_size,
                              hipStream_t stream) {
  (void)in_sizes; (void)n_in; (void)out_size; (void)ws_size;
  const float* inputs   = (const float*)d_in[0];
  const float* w_init   = (const float*)d_in[1];
  const float* b_init   = (const float*)d_in[2];
  const float* s4_ln_w  = (const float*)d_in[3];
  const float* s4_ln_b  = (const float*)d_in[4];
  const float* log_dt   = (const float*)d_in[5];
  const float* log_A    = (const float*)d_in[6];
  const float* A_imag   = (const float*)d_in[7];
  const float* C_re     = (const float*)d_in[8];
  const float* C_im     = (const float*)d_in[9];
  const float* D_skip   = (const float*)d_in[10];
  const float* s4_out_w = (const float*)d_in[11];
  const float* s4_out_b = (const float*)d_in[12];
  const float* ff_ln_w  = (const float*)d_in[13];
  const float* ff_ln_b  = (const float*)d_in[14];
  const float* ff_w1    = (const float*)d_in[15];
  const float* ff_b1    = (const float*)d_in[16];
  const float* ff_w2    = (const float*)d_in[17];
  const float* ff_b2    = (const float*)d_in[18];
  const float* norm_w   = (const float*)d_in[19];
  const float* norm_b   = (const float*)d_in[20];
  const float* w_final1 = (const float*)d_in[21];
  const float* b_final1 = (const float*)d_in[22];
  const float* w_zero   = (const float*)d_in[23];
  const float* b_zero   = (const float*)d_in[24];

  char* w8 = (char*)d_ws;
  float* X    = (float*)w8;                                   // 64 MiB
  f16*   Y16  = (f16*)(w8 + (size_t)67108864);                // 32 MiB
  f32x2* S    = (f32x2*)(w8 + (size_t)67108864 + 33554432);   // 32 MiB
  f32x2* STATS= (f32x2*)(w8 + (size_t)67108864 + 33554432 + 33554432);  // 2 MiB
  f32x2* LAM  = STATS + (size_t)Bq * Lq;                      // 4096 each
  f32x2* DC2  = LAM + NLq * Dq * Nq;
  f32x2* LCL  = DC2 + NLq * Dq * Nq;
  f32x2* LC64 = LCL + NLq * Dq * Nq;
  f32x2* G    = LC64 + NLq * Dq * Nq;                         // 8*8*1024 = 64K f32x2

  k_setup<<<16, 256, 0, stream>>>(log_dt, log_A, A_imag, C_re, C_im, LAM, DC2, LCL, LC64);
  k_init<<<2048, 256, 0, stream>>>(inputs, w_init, b_init, X, STATS);
  for (int i = 0; i < NLq; i++) {
    k_pass1<<<Bq * NCq / 4, 256, 0, stream>>>(X, STATS, LAM + i * Dq * Nq,
                                              s4_ln_w + i * Dq, s4_ln_b + i * Dq, S);
    k_pass2a<<<256, 256, 0, stream>>>(S, LCL + i * Dq * Nq, G);
    k_pass2b<<<32, 256, 0, stream>>>(G, LC64 + i * Dq * Nq);
    k_pass3<<<Bq * NCq / 4, 256, 0, stream>>>(X, STATS, S, LAM + i * Dq * Nq, DC2 + i * Dq * Nq,
                                              LCL + i * Dq * Nq, G,
                                              s4_ln_w + i * Dq, s4_ln_b + i * Dq,
                                              D_skip + i * Dq, Y16);
    k_glu<<<1024, 256, 0, stream>>>(Y16, s4_out_w + i * 128 * 64, s4_out_b + i * 128, X, STATS);
    k_ff<<<1024, 256, 0, stream>>>(ff_w1 + i * 128 * 64, ff_b1 + i * 128,
                                   ff_w2 + i * 64 * 128, ff_b2 + i * 64,
                                   ff_ln_w + i * Dq, ff_ln_b + i * Dq, X, STATS);
  }
  k_head<<<2048, 256, 0, stream>>>(X, STATS, norm_w, norm_b, w_final1, b_final1,
                                   w_zero, b_zero, (float*)d_out);
}

// Round 5
// 755.592 us; speedup vs baseline: 2.0332x; 1.1891x over previous
//
#include <hip/hip_runtime.h>
#include <cmath>

constexpr int Bq = 8, Lq = 32768, Dq = 64, Nq = 16, NLq = 4;
constexpr int CLq = 128, NCq = 256;           // NCq*CLq == Lq ; chunks per batch
constexpr int BCt = Bq * NCq;                 // 2048 total chunks
constexpr int PT = Bq * Lq / 16;              // 16384 position-tiles of 16

typedef _Float16 f16;
typedef _Float16 half2t __attribute__((ext_vector_type(2)));
typedef _Float16 half4 __attribute__((ext_vector_type(4)));
typedef _Float16 half8 __attribute__((ext_vector_type(8)));
typedef float f32x4 __attribute__((ext_vector_type(4)));
typedef float f32x2 __attribute__((ext_vector_type(2)));

static __device__ __forceinline__ float sigm(float x) { return 1.0f / (1.0f + __expf(-x)); }
static __device__ __forceinline__ float gelu_t(float x) {
  return x * sigm(1.5957691216057308f * fmaf(0.044715f * x * x, x, x));
}

// -------- setup: lambda = exp(dtA), dC2 = 2*C*(lambda-1)/A, lambda^128, lambda^4096 --------
__global__ __launch_bounds__(256) void k_setup(
    const float* __restrict__ log_dt, const float* __restrict__ log_A_real,
    const float* __restrict__ A_imag, const float* __restrict__ C_re,
    const float* __restrict__ C_im,
    f32x2* __restrict__ LAM, f32x2* __restrict__ DC2, f32x2* __restrict__ LCL,
    f32x2* __restrict__ LC4K) {
  int idx = blockIdx.x * 256 + threadIdx.x;
  if (idx >= NLq * Dq * Nq) return;
  int di = idx / Nq;
  float dt = expf(log_dt[di]);
  float Ar = -expf(log_A_real[idx]);
  float Ai = A_imag[idx];
  float dr = Ar * dt, dmi = Ai * dt;
  float er = expf(dr);
  float lr = er * cosf(dmi), li = er * sinf(dmi);
  float inv = 1.0f / (Ar * Ar + Ai * Ai);
  float e1r = lr - 1.0f, e1i = li;
  float qr = (e1r * Ar + e1i * Ai) * inv;
  float qi = (e1i * Ar - e1r * Ai) * inv;
  float cr = C_re[idx], ci = C_im[idx];
  LAM[idx] = f32x2{lr, li};
  DC2[idx] = f32x2{2.0f * (cr * qr - ci * qi), 2.0f * (cr * qi + ci * qr)};
  float erc = expf(dr * (float)CLq);
  LCL[idx] = f32x2{erc * cosf(dmi * (float)CLq), erc * sinf(dmi * (float)CLq)};
  float e4 = expf(dr * (float)(CLq * 32));
  LC4K[idx] = f32x2{e4 * cosf(dmi * (float)(CLq * 32)), e4 * sinf(dmi * (float)(CLq * 32))};
}

// -------- k_wt: build frag-ordered f16 matrices TF (Toeplitz conv), VF (carry), WF (s_end) --------
// One block (128 thr) per d. pow[t][n] = lambda_n^t in shared.
__global__ __launch_bounds__(128) void k_wt(
    const f32x2* __restrict__ LAMl, const f32x2* __restrict__ DC2l,
    const f32x2* __restrict__ LCLl, const float* __restrict__ dskip,
    half8* __restrict__ TF, half8* __restrict__ VF, half8* __restrict__ WF) {
  __shared__ f32x2 pw[129][16];
  __shared__ float Ks[128];
  int d = blockIdx.x;
  int t = threadIdx.x;
#pragma unroll
  for (int n = 0; n < 16; n++) {
    f32x2 lam = LAMl[d * 16 + n];
    float pr = 1.f, pi = 0.f, br = lam.x, bi = lam.y;
    int e = t;
    while (e) {
      if (e & 1) { float tt = pr * br - pi * bi; pi = fmaf(pr, bi, pi * br); pr = tt; }
      float t2 = br * br - bi * bi; bi = 2.f * br * bi; br = t2; e >>= 1;
    }
    pw[t][n] = f32x2{pr, pi};
  }
  if (t < 16) pw[128][t] = LCLl[d * 16 + t];
  __syncthreads();
  {
    float k = 0.f;
#pragma unroll
    for (int n = 0; n < 16; n++) {
      f32x2 dc = DC2l[d * 16 + n];
      f32x2 p = pw[t][n];
      k += dc.x * p.x - dc.y * p.y;
    }
    if (t == 0) k += dskip[d];
    Ks[t] = k;
  }
  __syncthreads();
  // TF: 2048 slots = (mt 8, kt 4, lane 64); T[jo][ji] = jo>=ji ? K[jo-ji] : 0
  for (int s = t; s < 2048; s += 128) {
    int ln = s & 63, kt = (s >> 6) & 3, mt = s >> 8;
    int jo = mt * 16 + (ln & 15);
    int ji0 = kt * 32 + (ln >> 4) * 8;
    half8 v;
#pragma unroll
    for (int jj = 0; jj < 8; jj++) {
      int ji = ji0 + jj;
      v[jj] = (jo >= ji) ? (f16)Ks[jo - ji] : (f16)0.f;
    }
    TF[(size_t)d * 2048 + s] = v;
  }
  // VF: 512 slots = (mt 8, lane 64); V[jo][q]: q=2n -> Re(DC2*lam^{jo+1}), q=2n+1 -> -Im
  for (int s = t; s < 512; s += 128) {
    int ln = s & 63, mt = s >> 6;
    int jo = mt * 16 + (ln & 15);
    int q0 = (ln >> 4) * 8;
    half8 v;
#pragma unroll
    for (int jj = 0; jj < 8; jj++) {
      int q = q0 + jj, n = q >> 1;
      f32x2 dc = DC2l[d * 16 + n];
      f32x2 p = pw[jo + 1][n];
      float wr = dc.x * p.x - dc.y * p.y;
      float wi = dc.x * p.y + dc.y * p.x;
      v[jj] = (q & 1) ? (f16)(-wi) : (f16)wr;
    }
    VF[(size_t)d * 512 + s] = v;
  }
  // WF: 512 slots = (nt 2, kt 4, lane 64); Wend[p][j] = (p&1 ? Im : Re)(lam_{p>>1}^{127-j})
  for (int s = t; s < 512; s += 128) {
    int ln = s & 63, kt = (s >> 6) & 3, nt = s >> 8;
    int p_ = nt * 16 + (ln & 15);
    int n = p_ >> 1;
    int j0 = kt * 32 + (ln >> 4) * 8;
    half8 v;
#pragma unroll
    for (int jj = 0; jj < 8; jj++) {
      f32x2 p = pw[127 - (j0 + jj)][n];
      v[jj] = (p_ & 1) ? (f16)p.y : (f16)p.x;
    }
    WF[(size_t)d * 512 + s] = v;
  }
}

// -------- init: x = relu(w_init*in + b_init), write LN stats --------
__global__ __launch_bounds__(256) void k_init(
    const float* __restrict__ inp, const float* __restrict__ w_init,
    const float* __restrict__ b_init, float* __restrict__ X, f32x2* __restrict__ STATS) {
  int lane = threadIdx.x & 63;
  int wv = (blockIdx.x * 256 + threadIdx.x) >> 6;
  int nw = gridDim.x * 4;
  int pl = lane & 15, qh = lane >> 4;
  for (int pt = wv; pt < PT; pt += nw) {
    int pos = pt * 16 + pl;
    float v = inp[pos];
    float s = 0.f, s2 = 0.f;
#pragma unroll
    for (int q = 0; q < 4; q++) {
      int d0 = q * 16 + qh * 4;
      f32x4 w4 = *(const f32x4*)(w_init + d0);
      f32x4 b4 = *(const f32x4*)(b_init + d0);
      f32x4 o;
#pragma unroll
      for (int j = 0; j < 4; j++) {
        float t = fmaf(w4[j], v, b4[j]);
        t = t > 0.f ? t : 0.f;
        o[j] = t; s += t; s2 += t * t;
      }
      *(f32x4*)(X + (size_t)pos * 64 + d0) = o;
    }
    s += __shfl_xor(s, 16); s += __shfl_xor(s, 32);
    s2 += __shfl_xor(s2, 16); s2 += __shfl_xor(s2, 32);
    if (qh == 0) {
      float m = s * (1.0f / 64.0f);
      float var = s2 * (1.0f / 64.0f) - m * m;
      STATS[pos] = f32x2{m, rsqrtf(var + 1e-5f)};
    }
  }
}

// -------- k_zt: z = LN(x)*w+b -> f16, transposed to Z16[d][pos] via LDS --------
__global__ __launch_bounds__(256) void k_zt(
    const float* __restrict__ X, const f32x2* __restrict__ STATS,
    const float* __restrict__ lnw, const float* __restrict__ lnb, f16* __restrict__ Z16) {
  __shared__ f16 tr[4][64][68];
  int tid = threadIdx.x;
  int widx = tid >> 6, lane = tid & 63;
  int w = blockIdx.x * 4 + widx;
  int pos0 = w * 64;
  int jq = lane >> 4, dq = lane & 15;
  f32x4 lw = *(const f32x4*)(lnw + dq * 4);
  f32x4 lb = *(const f32x4*)(lnb + dq * 4);
#pragma unroll 4
  for (int jo = 0; jo < 64; jo += 4) {
    int j = jo + jq, pos = pos0 + j;
    f32x4 x4 = *(const f32x4*)(X + (size_t)pos * 64 + dq * 4);
    f32x2 ms = STATS[pos];
    half4 z;
#pragma unroll
    for (int i2 = 0; i2 < 4; i2++) z[i2] = (f16)fmaf((x4[i2] - ms.x) * ms.y, lw[i2], lb[i2]);
    *(half4*)(&tr[widx][j][dq * 4]) = z;
  }
  __syncthreads();
  int pl = lane & 15, qh = lane >> 4;
#pragma unroll 4
  for (int i = 0; i < 16; i++) {
    int d = i * 4 + qh;
    int j4 = pl * 4;
    half4 o = half4{tr[widx][j4][d], tr[widx][j4 + 1][d], tr[widx][j4 + 2][d], tr[widx][j4 + 3][d]};
    *(half4*)(Z16 + (size_t)d * 262144 + pos0 + j4) = o;
  }
}

// -------- k_p1g: chunk end-states S16[d][bc][p32] = Z(m=bc,k=j) @ Wend(k=j,n=p) --------
__global__ __launch_bounds__(256) void k_p1g(
    const f16* __restrict__ Z16, const half8* __restrict__ WF, f16* __restrict__ S16) {
  int tid = threadIdx.x;
  int lane = tid & 63;
  int task = blockIdx.x * 4 + (tid >> 6);
  int d = task >> 7, bct = task & 127;
  int bc0 = bct * 16;
  int pl = lane & 15, qh = lane >> 4;
  half8 az[4];
  const f16* zp = Z16 + ((size_t)d * 2048 + bc0 + pl) * 128 + qh * 8;
#pragma unroll
  for (int kt = 0; kt < 4; kt++) az[kt] = *(const half8*)(zp + kt * 32);
#pragma unroll
  for (int nt = 0; nt < 2; nt++) {
    f32x4 acc = f32x4{0.f, 0.f, 0.f, 0.f};
#pragma unroll
    for (int kt = 0; kt < 4; kt++)
      acc = __builtin_amdgcn_mfma_f32_16x16x32_f16(az[kt], WF[(size_t)d * 512 + (nt * 4 + kt) * 64 + lane], acc, 0, 0, 0);
#pragma unroll
    for (int r = 0; r < 4; r++)
      S16[((size_t)d * 2048 + bc0 + qh * 4 + r) * 32 + nt * 16 + pl] = (f16)acc[r];
  }
}

// -------- pass2a: group totals over 32-chunk groups (f32 carry from f16 states) --------
__global__ __launch_bounds__(256) void k_pass2a(
    const f16* __restrict__ S16, const f32x2* __restrict__ LCLl, f32x2* __restrict__ G) {
  int t = blockIdx.x * 256 + threadIdx.x;  // 65536 = d*16n*8b*8g
  int n = t & 15, g = (t >> 4) & 7, b = (t >> 7) & 7, d = t >> 10;
  f32x2 lam = LCLl[d * 16 + n];
  float cr = 0.f, ci = 0.f;
  const f16* p = S16 + ((size_t)d * 2048 + b * 256 + g * 32) * 32 + 2 * n;
#pragma unroll 8
  for (int j = 0; j < 32; j++) {
    half2t v = *(const half2t*)(p + (size_t)j * 32);
    float nr = fmaf(lam.x, cr, fmaf(-lam.y, ci, (float)v[0]));
    float ni = fmaf(lam.x, ci, fmaf(lam.y, cr, (float)v[1]));
    cr = nr; ci = ni;
  }
  G[((size_t)d * 64 + b * 8 + g) * 16 + n] = f32x2{cr, ci};
}

// -------- pass2b: exclusive scan over the 8 group totals per (d,n,b) --------
__global__ __launch_bounds__(256) void k_pass2b(
    f32x2* __restrict__ G, const f32x2* __restrict__ LC4Kl) {
  int t = blockIdx.x * 256 + threadIdx.x;  // 8192
  int n = t & 15, b = (t >> 4) & 7, d = t >> 7;
  f32x2 lam = LC4Kl[d * 16 + n];
  float cr = 0.f, ci = 0.f;
#pragma unroll
  for (int g = 0; g < 8; g++) {
    size_t idx = ((size_t)d * 64 + b * 8 + g) * 16 + n;
    f32x2 tt = G[idx];
    G[idx] = f32x2{cr, ci};
    float nr = fmaf(lam.x, cr, fmaf(-lam.y, ci, tt.x));
    float ni = fmaf(lam.x, ci, fmaf(lam.y, cr, tt.y));
    cr = nr; ci = ni;
  }
}

// -------- pass2c: within-group exclusive rescan + compose -> f16 carry matrix Sc --------
__global__ __launch_bounds__(256) void k_pass2c(
    const f16* __restrict__ S16, const f32x2* __restrict__ G,
    const f32x2* __restrict__ LCLl, f16* __restrict__ Sc) {
  int t = blockIdx.x * 256 + threadIdx.x;
  int n = t & 15, g = (t >> 4) & 7, b = (t >> 7) & 7, d = t >> 10;
  f32x2 lam = LCLl[d * 16 + n];
  f32x2 c0 = G[((size_t)d * 64 + b * 8 + g) * 16 + n];
  float cr = c0.x, ci = c0.y;
  size_t base = ((size_t)d * 2048 + b * 256 + g * 32) * 32 + 2 * n;
  const f16* sp = S16 + base;
  f16* cp = Sc + base;
#pragma unroll 8
  for (int j = 0; j < 32; j++) {
    *(half2t*)(cp + (size_t)j * 32) = half2t{(f16)cr, (f16)ci};
    half2t v = *(const half2t*)(sp + (size_t)j * 32);
    float nr = fmaf(lam.x, cr, fmaf(-lam.y, ci, (float)v[0]));
    float ni = fmaf(lam.x, ci, fmaf(lam.y, cr, (float)v[1]));
    cr = nr; ci = ni;
  }
}

// -------- k_p3g: y = T_d @ z + V_d @ carry, gelu, write Y16[pos][d] (d-packed half4) --------
template <int MTH>
__global__ __launch_bounds__(256) void k_p3g(
    const f16* __restrict__ Z16, const f16* __restrict__ Sc,
    const half8* __restrict__ TF, const half8* __restrict__ VF,
    f16* __restrict__ Y16) {
  int tid = threadIdx.x;
  int lane = tid & 63, widx = tid >> 6;
  int bct = blockIdx.x & 127, dg = blockIdx.x >> 7;  // grid 512: 4 dg x 128 bct
  int bc0 = bct * 16;
  int dbase = dg * 16 + widx * 4;
  int pl = lane & 15, qh = lane >> 4;
  constexpr int NKT = MTH ? 4 : 2;
  half8 zb[4][NKT];
  half8 sb[4];
#pragma unroll
  for (int di = 0; di < 4; di++) {
    int d = dbase + di;
    const f16* zp = Z16 + ((size_t)d * 2048 + bc0 + pl) * 128 + qh * 8;
#pragma unroll
    for (int kt = 0; kt < NKT; kt++) zb[di][kt] = *(const half8*)(zp + kt * 32);
    sb[di] = *(const half8*)(Sc + ((size_t)d * 2048 + bc0 + pl) * 32 + qh * 8);
  }
#pragma unroll
  for (int u = 0; u < 4; u++) {
    const int mt = MTH * 4 + u;
    const int KTM = mt / 2 + 1;  // causal: tiles with ji0 <= jo_max
    f32x4 acc[4];
#pragma unroll
    for (int di = 0; di < 4; di++) {
      int d = dbase + di;
      acc[di] = f32x4{0.f, 0.f, 0.f, 0.f};
      const half8* tfp = TF + ((size_t)d * 8 + mt) * 256 + lane;
#pragma unroll
      for (int kt = 0; kt < KTM; kt++)
        acc[di] = __builtin_amdgcn_mfma_f32_16x16x32_f16(tfp[kt * 64], zb[di][kt], acc[di], 0, 0, 0);
      acc[di] = __builtin_amdgcn_mfma_f32_16x16x32_f16(VF[((size_t)d * 8 + mt) * 64 + lane], sb[di], acc[di], 0, 0, 0);
    }
#pragma unroll
    for (int r = 0; r < 4; r++) {
      int pos = (bc0 + pl) * 128 + mt * 16 + qh * 4 + r;
      half4 pk = half4{(f16)gelu_t(acc[0][r]), (f16)gelu_t(acc[1][r]),
                       (f16)gelu_t(acc[2][r]), (f16)gelu_t(acc[3][r])};
      *(half4*)(Y16 + (size_t)pos * 64 + dbase) = pk;
    }
  }
}

// ======== GLU kernel (unchanged, R4-verified): u = Wg@y + bg; x += u_a*sigm(u_g) ========
__device__ __forceinline__ void glu_tile(
    int pos, half8 yb0, half8 yb1, f32x4* xv, const char* smembase,
    int qh, int lane, float* __restrict__ X, f32x2* __restrict__ STATS) {
  unsigned sb = 0;
  asm volatile("" : "+v"(sb));
  const char* sm = smembase + sb;
  const half8* sW = (const half8*)sm;
  const float* bgF = (const float*)(sm + 16384);
  f32x4 acc[8];
#pragma unroll
  for (int et = 0; et < 8; et++) acc[et] = *(const f32x4*)(bgF + et * 16 + qh * 4);
#pragma unroll
  for (int et = 0; et < 8; et++)
    acc[et] = __builtin_amdgcn_mfma_f32_16x16x32_f16(sW[(et * 2) * 64 + lane], yb0, acc[et], 0, 0, 0);
#pragma unroll
  for (int et = 0; et < 8; et++)
    acc[et] = __builtin_amdgcn_mfma_f32_16x16x32_f16(sW[(et * 2 + 1) * 64 + lane], yb1, acc[et], 0, 0, 0);
  float s = 0.f, s2 = 0.f;
#pragma unroll
  for (int q = 0; q < 4; q++) {
#pragma unroll
    for (int r = 0; r < 4; r++) {
      xv[q][r] += acc[q][r] * sigm(acc[q + 4][r]);
      s += xv[q][r]; s2 += xv[q][r] * xv[q][r];
    }
    *(f32x4*)(X + (size_t)pos * 64 + q * 16 + qh * 4) = xv[q];
  }
  s += __shfl_xor(s, 16); s += __shfl_xor(s, 32);
  s2 += __shfl_xor(s2, 16); s2 += __shfl_xor(s2, 32);
  if (qh == 0) {
    float m = s * (1.0f / 64.0f);
    float var = s2 * (1.0f / 64.0f) - m * m;
    STATS[pos] = f32x2{m, rsqrtf(var + 1e-5f)};
  }
}

__global__ __launch_bounds__(256) void k_glu(
    const f16* __restrict__ Y16, const float* __restrict__ Wg, const float* __restrict__ bg,
    float* __restrict__ X, f32x2* __restrict__ STATS) {
  __shared__ __align__(16) char smem[16896];
  int tid = threadIdx.x;
#pragma unroll
  for (int it = 0; it < 4; it++) {
    int s = it * 256 + tid;
    int l = s & 63, ks = (s >> 6) & 1, et = s >> 7;
    const float* wp = Wg + (et * 16 + (l & 15)) * 64 + ks * 32 + (l >> 4) * 8;
    f32x4 w0 = *(const f32x4*)wp, w1 = *(const f32x4*)(wp + 4);
    *(half8*)(smem + s * 16) = half8{(f16)w0[0], (f16)w0[1], (f16)w0[2], (f16)w0[3],
                                     (f16)w1[0], (f16)w1[1], (f16)w1[2], (f16)w1[3]};
  }
  if (tid < 128) ((float*)(smem + 16384))[tid] = bg[tid];
  __syncthreads();
  int lane = tid & 63, pl = lane & 15, qh = lane >> 4;
  int wv = (blockIdx.x * 256 + tid) >> 6, nw = gridDim.x * 4;
  for (int pt = wv; pt < PT; pt += 2 * nw) {
    int ptB = pt + nw;
    bool hasB = ptB < PT;
    int posA = pt * 16 + pl, posB = ptB * 16 + pl;
    half8 ybA0 = *(const half8*)(Y16 + (size_t)posA * 64 + qh * 8);
    half8 ybA1 = *(const half8*)(Y16 + (size_t)posA * 64 + 32 + qh * 8);
    f32x4 xvA[4];
#pragma unroll
    for (int q = 0; q < 4; q++) xvA[q] = *(const f32x4*)(X + (size_t)posA * 64 + q * 16 + qh * 4);
    half8 ybB0{}, ybB1{};
    f32x4 xvB[4];
    if (hasB) {
      ybB0 = *(const half8*)(Y16 + (size_t)posB * 64 + qh * 8);
      ybB1 = *(const half8*)(Y16 + (size_t)posB * 64 + 32 + qh * 8);
#pragma unroll
      for (int q = 0; q < 4; q++) xvB[q] = *(const f32x4*)(X + (size_t)posB * 64 + q * 16 + qh * 4);
    }
    glu_tile(posA, ybA0, ybA1, xvA, smem, qh, lane, X, STATS);
    if (hasB) glu_tile(posB, ybB0, ybB1, xvB, smem, qh, lane, X, STATS);
  }
}

// ======== FF kernel (unchanged, R4-verified) ========
__device__ __forceinline__ void ff_tile(
    int pos, f32x2 st, const f32x4* xb, f32x4* xv, const char* smembase,
    int qh, int lane, float* __restrict__ X, f32x2* __restrict__ STATS) {
  unsigned sb = 0;
  asm volatile("" : "+v"(sb));
  const char* sm = smembase + sb;
  const half8* sW1 = (const half8*)sm;
  const half4* sW2 = (const half4*)(sm + 16384);
  const float* sf = (const float*)(sm + 32768);
  const float* b1F = sf;
  const float* b2F = sf + 128;
  const float* lnwF = sf + 192;
  const float* lnbF = sf + 256;
  float m = st.x, rs = st.y;
  half8 zb[2];
#pragma unroll
  for (int ks = 0; ks < 2; ks++) {
    f32x4 lw0 = *(const f32x4*)(lnwF + ks * 32 + qh * 8);
    f32x4 lw1 = *(const f32x4*)(lnwF + ks * 32 + qh * 8 + 4);
    f32x4 lb0 = *(const f32x4*)(lnbF + ks * 32 + qh * 8);
    f32x4 lb1 = *(const f32x4*)(lnbF + ks * 32 + qh * 8 + 4);
    f32x4 x0 = xb[ks * 2], x1 = xb[ks * 2 + 1];
    half8 z;
#pragma unroll
    for (int jj = 0; jj < 4; jj++) {
      z[jj] = (f16)fmaf((x0[jj] - m) * rs, lw0[jj], lb0[jj]);
      z[jj + 4] = (f16)fmaf((x1[jj] - m) * rs, lw1[jj], lb1[jj]);
    }
    zb[ks] = z;
  }
  f32x4 acc1[8];
#pragma unroll
  for (int et = 0; et < 8; et++) acc1[et] = *(const f32x4*)(b1F + et * 16 + qh * 4);
#pragma unroll
  for (int ks = 0; ks < 2; ks++)
#pragma unroll
    for (int et = 0; et < 8; et++)
      acc1[et] = __builtin_amdgcn_mfma_f32_16x16x32_f16(sW1[(et * 2 + ks) * 64 + lane], zb[ks], acc1[et], 0, 0, 0);
  half4 h2[8];
#pragma unroll
  for (int et = 0; et < 8; et++)
    h2[et] = half4{(f16)gelu_t(acc1[et][0]), (f16)gelu_t(acc1[et][1]),
                   (f16)gelu_t(acc1[et][2]), (f16)gelu_t(acc1[et][3])};
  f32x4 acc2[4];
#pragma unroll
  for (int dt = 0; dt < 4; dt++) acc2[dt] = *(const f32x4*)(b2F + dt * 16 + qh * 4);
#pragma unroll
  for (int ks = 0; ks < 8; ks++)
#pragma unroll
    for (int dt = 0; dt < 4; dt++)
      acc2[dt] = __builtin_amdgcn_mfma_f32_16x16x16f16(sW2[(dt * 8 + ks) * 64 + lane], h2[ks], acc2[dt], 0, 0, 0);
  float s = 0.f, s2 = 0.f;
#pragma unroll
  for (int dt = 0; dt < 4; dt++) {
#pragma unroll
    for (int r = 0; r < 4; r++) {
      xv[dt][r] += acc2[dt][r];
      s += xv[dt][r]; s2 += xv[dt][r] * xv[dt][r];
    }
    *(f32x4*)(X + (size_t)pos * 64 + dt * 16 + qh * 4) = xv[dt];
  }
  s += __shfl_xor(s, 16); s += __shfl_xor(s, 32);
  s2 += __shfl_xor(s2, 16); s2 += __shfl_xor(s2, 32);
  if (qh == 0) {
    float mm = s * (1.0f / 64.0f);
    float var = s2 * (1.0f / 64.0f) - mm * mm;
    STATS[pos] = f32x2{mm, rsqrtf(var + 1e-5f)};
  }
}

__global__ __launch_bounds__(256) void k_ff(
    const float* __restrict__ W1, const float* __restrict__ b1,
    const float* __restrict__ W2, const float* __restrict__ b2,
    const float* __restrict__ lnw, const float* __restrict__ lnb,
    float* __restrict__ X, f32x2* __restrict__ STATS) {
  __shared__ __align__(16) char smem[34048];
  int tid = threadIdx.x;
#pragma unroll
  for (int it = 0; it < 4; it++) {
    int s = it * 256 + tid;
    int l = s & 63, ks = (s >> 6) & 1, et = s >> 7;
    const float* wp = W1 + (et * 16 + (l & 15)) * 64 + ks * 32 + (l >> 4) * 8;
    f32x4 w0 = *(const f32x4*)wp, w1 = *(const f32x4*)(wp + 4);
    *(half8*)(smem + s * 16) = half8{(f16)w0[0], (f16)w0[1], (f16)w0[2], (f16)w0[3],
                                     (f16)w1[0], (f16)w1[1], (f16)w1[2], (f16)w1[3]};
  }
#pragma unroll
  for (int it = 0; it < 8; it++) {
    int s = it * 256 + tid;
    int l = s & 63, ks = (s >> 6) & 7, dt = s >> 9;
    const float* wp = W2 + (dt * 16 + (l & 15)) * 128 + ks * 16 + (l >> 4) * 4;
    f32x4 w0 = *(const f32x4*)wp;
    *(half4*)(smem + 16384 + s * 8) = half4{(f16)w0[0], (f16)w0[1], (f16)w0[2], (f16)w0[3]};
  }
  for (int idx = tid; idx < 320; idx += 256) {
    float v;
    if (idx < 128) v = b1[idx];
    else if (idx < 192) v = b2[idx - 128];
    else if (idx < 256) v = lnw[idx - 192];
    else v = lnb[idx - 256];
    ((float*)(smem + 32768))[idx] = v;
  }
  __syncthreads();
  int lane = tid & 63, pl = lane & 15, qh = lane >> 4;
  int wv = (blockIdx.x * 256 + tid) >> 6, nw = gridDim.x * 4;
  for (int pt = wv; pt < PT; pt += 2 * nw) {
    int ptB = pt + nw;
    bool hasB = ptB < PT;
    int posA = pt * 16 + pl, posB = ptB * 16 + pl;
    f32x2 stA = STATS[posA];
    f32x4 xbA[4], xvA[4];
#pragma unroll
    for (int k = 0; k < 2; k++) {
      xbA[k * 2] = *(const f32x4*)(X + (size_t)posA * 64 + k * 32 + qh * 8);
      xbA[k * 2 + 1] = *(const f32x4*)(X + (size_t)posA * 64 + k * 32 + qh * 8 + 4);
    }
#pragma unroll
    for (int q = 0; q < 4; q++) xvA[q] = *(const f32x4*)(X + (size_t)posA * 64 + q * 16 + qh * 4);
    f32x2 stB{0.f, 0.f};
    f32x4 xbB[4], xvB[4];
    if (hasB) {
      stB = STATS[posB];
#pragma unroll
      for (int k = 0; k < 2; k++) {
        xbB[k * 2] = *(const f32x4*)(X + (size_t)posB * 64 + k * 32 + qh * 8);
        xbB[k * 2 + 1] = *(const f32x4*)(X + (size_t)posB * 64 + k * 32 + qh * 8 + 4);
      }
#pragma unroll
      for (int q = 0; q < 4; q++) xvB[q] = *(const f32x4*)(X + (size_t)posB * 64 + q * 16 + qh * 4);
    }
    ff_tile(posA, stA, xbA, xvA, smem, qh, lane, X, STATS);
    if (hasB) ff_tile(posB, stB, xbB, xvB, smem, qh, lane, X, STATS);
  }
}

// -------- head: z=LN(x,norm); r=relu(Wf z + bf); out = wz.r + bz --------
__global__ __launch_bounds__(256) void k_head(
    const float* __restrict__ X, const f32x2* __restrict__ STATS,
    const float* __restrict__ nw_, const float* __restrict__ nb_,
    const float* __restrict__ Wf, const float* __restrict__ bfb,
    const float* __restrict__ wz, const float* __restrict__ bz,
    float* __restrict__ outp) {
  int lane = threadIdx.x & 63;
  int wv = (blockIdx.x * 256 + threadIdx.x) >> 6;
  int nwv = gridDim.x * 4;
  int pl = lane & 15, qh = lane >> 4;
  half4 af[4][4];
#pragma unroll
  for (int et = 0; et < 4; et++)
#pragma unroll
    for (int ks = 0; ks < 4; ks++) {
      f32x4 w4 = *(const f32x4*)(Wf + (et * 16 + pl) * 64 + ks * 16 + qh * 4);
      af[et][ks] = half4{(f16)w4[0], (f16)w4[1], (f16)w4[2], (f16)w4[3]};
    }
  float bz0 = bz[0];
  for (int pt = wv; pt < PT; pt += nwv) {
    int pos = pt * 16 + pl;
    f32x2 ms = STATS[pos];
    half4 bf[4];
#pragma unroll
    for (int ks = 0; ks < 4; ks++) {
      f32x4 x4 = *(const f32x4*)(X + (size_t)pos * 64 + ks * 16 + qh * 4);
      f32x4 lw = *(const f32x4*)(nw_ + ks * 16 + qh * 4);
      f32x4 lb = *(const f32x4*)(nb_ + ks * 16 + qh * 4);
      f32x4 z;
#pragma unroll
      for (int j = 0; j < 4; j++) z[j] = fmaf((x4[j] - ms.x) * ms.y, lw[j], lb[j]);
      bf[ks] = half4{(f16)z[0], (f16)z[1], (f16)z[2], (f16)z[3]};
    }
    f32x4 acc[4];
#pragma unroll
    for (int et = 0; et < 4; et++) acc[et] = *(const f32x4*)(bfb + et * 16 + qh * 4);
#pragma unroll
    for (int ks = 0; ks < 4; ks++)
#pragma unroll
      for (int et = 0; et < 4; et++)
        acc[et] = __builtin_amdgcn_mfma_f32_16x16x16f16(af[et][ks], bf[ks], acc[et], 0, 0, 0);
    float o = 0.f;
#pragma unroll
    for (int et = 0; et < 4; et++) {
      f32x4 wzv = *(const f32x4*)(wz + et * 16 + qh * 4);
#pragma unroll
      for (int r = 0; r < 4; r++) {
        float rv = acc[et][r];
        rv = rv > 0.f ? rv : 0.f;
        o = fmaf(wzv[r], rv, o);
      }
    }
    o += __shfl_xor(o, 16); o += __shfl_xor(o, 32);
    if (qh == 0) outp[pos] = o + bz0;
  }
}

extern "C" void kernel_launch(void* const* d_in, const int* in_sizes, int n_in,
                              void* d_out, int out_size, void* d_ws, size_t ws_size,
                              hipStream_t stream) {
  (void)in_sizes; (void)n_in; (void)out_size; (void)ws_size;
  const float* inputs   = (const float*)d_in[0];
  const float* w_init   = (const float*)d_in[1];
  const float* b_init   = (const float*)d_in[2];
  const float* s4_ln_w  = (const float*)d_in[3];
  const float* s4_ln_b  = (const float*)d_in[4];
  const float* log_dt   = (const float*)d_in[5];
  const float* log_A    = (const float*)d_in[6];
  const float* A_imag   = (const float*)d_in[7];
  const float* C_re     = (const float*)d_in[8];
  const float* C_im     = (const float*)d_in[9];
  const float* D_skip   = (const float*)d_in[10];
  const float* s4_out_w = (const float*)d_in[11];
  const float* s4_out_b = (const float*)d_in[12];
  const float* ff_ln_w  = (const float*)d_in[13];
  const float* ff_ln_b  = (const float*)d_in[14];
  const float* ff_w1    = (const float*)d_in[15];
  const float* ff_b1    = (const float*)d_in[16];
  const float* ff_w2    = (const float*)d_in[17];
  const float* ff_b2    = (const float*)d_in[18];
  const float* norm_w   = (const float*)d_in[19];
  const float* norm_b   = (const float*)d_in[20];
  const float* w_final1 = (const float*)d_in[21];
  const float* b_final1 = (const float*)d_in[22];
  const float* w_zero   = (const float*)d_in[23];
  const float* b_zero   = (const float*)d_in[24];

  char* w8 = (char*)d_ws;
  size_t off = 0;
  float* X     = (float*)(w8 + off); off += (size_t)67108864;   // [pos][64] f32
  f16*   Z16   = (f16*)(w8 + off);   off += (size_t)33554432;   // [d][pos] f16
  f16*   Y16   = (f16*)(w8 + off);   off += (size_t)33554432;   // [pos][d] f16
  f16*   S16   = (f16*)(w8 + off);   off += (size_t)8388608;    // [d][bc][32] f16
  f16*   Sc    = (f16*)(w8 + off);   off += (size_t)8388608;    // [d][bc][32] f16
  f32x2* STATS = (f32x2*)(w8 + off); off += (size_t)2097152;
  f32x2* G     = (f32x2*)(w8 + off); off += (size_t)524288;     // [d][64grp][16] f32x2
  f32x2* LAM   = (f32x2*)(w8 + off); off += 32768;
  f32x2* DC2   = (f32x2*)(w8 + off); off += 32768;
  f32x2* LCL   = (f32x2*)(w8 + off); off += 32768;
  f32x2* LC4K  = (f32x2*)(w8 + off); off += 32768;
  half8* TF    = (half8*)(w8 + off); off += (size_t)2097152;    // per-layer rebuilt
  half8* VF    = (half8*)(w8 + off); off += (size_t)524288;
  half8* WF    = (half8*)(w8 + off); off += (size_t)524288;

  k_setup<<<16, 256, 0, stream>>>(log_dt, log_A, A_imag, C_re, C_im, LAM, DC2, LCL, LC4K);
  k_init<<<2048, 256, 0, stream>>>(inputs, w_init, b_init, X, STATS);
  for (int i = 0; i < NLq; i++) {
    k_wt<<<64, 128, 0, stream>>>(LAM + i * 1024, DC2 + i * 1024, LCL + i * 1024,
                                 D_skip + i * 64, TF, VF, WF);
    k_zt<<<1024, 256, 0, stream>>>(X, STATS, s4_ln_w + i * 64, s4_ln_b + i * 64, Z16);
    k_p1g<<<2048, 256, 0, stream>>>(Z16, WF, S16);
    k_pass2a<<<256, 256, 0, stream>>>(S16, LCL + i * 1024, G);
    k_pass2b<<<32, 256, 0, stream>>>(G, LC4K + i * 1024);
    k_pass2c<<<256, 256, 0, stream>>>(S16, G, LCL + i * 1024, Sc);
    k_p3g<0><<<512, 256, 0, stream>>>(Z16, Sc, TF, VF, Y16);
    k_p3g<1><<<512, 256, 0, stream>>>(Z16, Sc, TF, VF, Y16);
    k_glu<<<1024, 256, 0, stream>>>(Y16, s4_out_w + i * 8192, s4_out_b + i * 128, X, STATS);
    k_ff<<<1024, 256, 0, stream>>>(ff_w1 + i * 8192, ff_b1 + i * 128,
                                   ff_w2 + i * 8192, ff_b2 + i * 64,
                                   ff_ln_w + i * 64, ff_ln_b + i * 64, X, STATS);
  }
  k_head<<<2048, 256, 0, stream>>>(X, STATS, norm_w, norm_b, w_final1, b_final1,
                                   w_zero, b_zero, (float*)d_out);
}

// Round 6
// 641.899 us; speedup vs baseline: 2.3933x; 1.1771x over previous
//
#include <hip/hip_runtime.h>
#include <cmath>

constexpr int Bq = 8, Lq = 32768, Dq = 64, Nq = 16, NLq = 4;
constexpr int CLq = 128, NCq = 256;           // NCq*CLq == Lq ; chunks per batch
constexpr int PT = Bq * Lq / 16;              // 16384 position-tiles of 16

typedef _Float16 f16;
typedef _Float16 half2t __attribute__((ext_vector_type(2)));
typedef _Float16 half4 __attribute__((ext_vector_type(4)));
typedef _Float16 half8 __attribute__((ext_vector_type(8)));
typedef float f32x4 __attribute__((ext_vector_type(4)));
typedef float f32x2 __attribute__((ext_vector_type(2)));

static __device__ __forceinline__ float sigm(float x) { return 1.0f / (1.0f + __expf(-x)); }
static __device__ __forceinline__ float gelu_t(float x) {
  return x * sigm(1.5957691216057308f * fmaf(0.044715f * x * x, x, x));
}

// -------- setup: lambda = exp(dtA), dC2 = 2*C*(lambda-1)/A, lambda^128, lambda^4096 --------
__global__ __launch_bounds__(256) void k_setup(
    const float* __restrict__ log_dt, const float* __restrict__ log_A_real,
    const float* __restrict__ A_imag, const float* __restrict__ C_re,
    const float* __restrict__ C_im,
    f32x2* __restrict__ LAM, f32x2* __restrict__ DC2, f32x2* __restrict__ LCL,
    f32x2* __restrict__ LC4K) {
  int idx = blockIdx.x * 256 + threadIdx.x;
  if (idx >= NLq * Dq * Nq) return;
  int di = idx / Nq;
  float dt = expf(log_dt[di]);
  float Ar = -expf(log_A_real[idx]);
  float Ai = A_imag[idx];
  float dr = Ar * dt, dmi = Ai * dt;
  float er = expf(dr);
  float lr = er * cosf(dmi), li = er * sinf(dmi);
  float inv = 1.0f / (Ar * Ar + Ai * Ai);
  float e1r = lr - 1.0f, e1i = li;
  float qr = (e1r * Ar + e1i * Ai) * inv;
  float qi = (e1i * Ar - e1r * Ai) * inv;
  float cr = C_re[idx], ci = C_im[idx];
  LAM[idx] = f32x2{lr, li};
  DC2[idx] = f32x2{2.0f * (cr * qr - ci * qi), 2.0f * (cr * qi + ci * qr)};
  float erc = expf(dr * (float)CLq);
  LCL[idx] = f32x2{erc * cosf(dmi * (float)CLq), erc * sinf(dmi * (float)CLq)};
  float e4 = expf(dr * (float)(CLq * 32));
  LC4K[idx] = f32x2{e4 * cosf(dmi * (float)(CLq * 32)), e4 * sinf(dmi * (float)(CLq * 32))};
}

// -------- k_wt: build frag-ordered f16 matrices TF (Toeplitz conv), VF (carry), WF (s_end) --------
__global__ __launch_bounds__(128) void k_wt(
    const f32x2* __restrict__ LAMl, const f32x2* __restrict__ DC2l,
    const f32x2* __restrict__ LCLl, const float* __restrict__ dskip,
    half8* __restrict__ TF, half8* __restrict__ VF, half8* __restrict__ WF) {
  __shared__ f32x2 pw[129][16];
  __shared__ float Ks[128];
  int d = blockIdx.x;
  int t = threadIdx.x;
#pragma unroll
  for (int n = 0; n < 16; n++) {
    f32x2 lam = LAMl[d * 16 + n];
    float pr = 1.f, pi = 0.f, br = lam.x, bi = lam.y;
    int e = t;
    while (e) {
      if (e & 1) { float tt = pr * br - pi * bi; pi = fmaf(pr, bi, pi * br); pr = tt; }
      float t2 = br * br - bi * bi; bi = 2.f * br * bi; br = t2; e >>= 1;
    }
    pw[t][n] = f32x2{pr, pi};
  }
  if (t < 16) pw[128][t] = LCLl[d * 16 + t];
  __syncthreads();
  {
    float k = 0.f;
#pragma unroll
    for (int n = 0; n < 16; n++) {
      f32x2 dc = DC2l[d * 16 + n];
      f32x2 p = pw[t][n];
      k += dc.x * p.x - dc.y * p.y;
    }
    if (t == 0) k += dskip[d];
    Ks[t] = k;
  }
  __syncthreads();
  for (int s = t; s < 2048; s += 128) {
    int ln = s & 63, kt = (s >> 6) & 3, mt = s >> 8;
    int jo = mt * 16 + (ln & 15);
    int ji0 = kt * 32 + (ln >> 4) * 8;
    half8 v;
#pragma unroll
    for (int jj = 0; jj < 8; jj++) {
      int ji = ji0 + jj;
      v[jj] = (jo >= ji) ? (f16)Ks[jo - ji] : (f16)0.f;
    }
    TF[(size_t)d * 2048 + s] = v;
  }
  for (int s = t; s < 512; s += 128) {
    int ln = s & 63, mt = s >> 6;
    int jo = mt * 16 + (ln & 15);
    int q0 = (ln >> 4) * 8;
    half8 v;
#pragma unroll
    for (int jj = 0; jj < 8; jj++) {
      int q = q0 + jj, n = q >> 1;
      f32x2 dc = DC2l[d * 16 + n];
      f32x2 p = pw[jo + 1][n];
      float wr = dc.x * p.x - dc.y * p.y;
      float wi = dc.x * p.y + dc.y * p.x;
      v[jj] = (q & 1) ? (f16)(-wi) : (f16)wr;
    }
    VF[(size_t)d * 512 + s] = v;
  }
  for (int s = t; s < 512; s += 128) {
    int ln = s & 63, kt = (s >> 6) & 3, nt = s >> 8;
    int p_ = nt * 16 + (ln & 15);
    int n = p_ >> 1;
    int j0 = kt * 32 + (ln >> 4) * 8;
    half8 v;
#pragma unroll
    for (int jj = 0; jj < 8; jj++) {
      f32x2 p = pw[127 - (j0 + jj)][n];
      v[jj] = (p_ & 1) ? (f16)p.y : (f16)p.x;
    }
    WF[(size_t)d * 512 + s] = v;
  }
}

// -------- init: x = relu(w_init*in + b_init), write LN stats --------
__global__ __launch_bounds__(256) void k_init(
    const float* __restrict__ inp, const float* __restrict__ w_init,
    const float* __restrict__ b_init, float* __restrict__ X, f32x2* __restrict__ STATS) {
  int lane = threadIdx.x & 63;
  int wv = (blockIdx.x * 256 + threadIdx.x) >> 6;
  int nw = gridDim.x * 4;
  int pl = lane & 15, qh = lane >> 4;
  for (int pt = wv; pt < PT; pt += nw) {
    int pos = pt * 16 + pl;
    float v = inp[pos];
    float s = 0.f, s2 = 0.f;
#pragma unroll
    for (int q = 0; q < 4; q++) {
      int d0 = q * 16 + qh * 4;
      f32x4 w4 = *(const f32x4*)(w_init + d0);
      f32x4 b4 = *(const f32x4*)(b_init + d0);
      f32x4 o;
#pragma unroll
      for (int j = 0; j < 4; j++) {
        float t = fmaf(w4[j], v, b4[j]);
        t = t > 0.f ? t : 0.f;
        o[j] = t; s += t; s2 += t * t;
      }
      *(f32x4*)(X + (size_t)pos * 64 + d0) = o;
    }
    s += __shfl_xor(s, 16); s += __shfl_xor(s, 32);
    s2 += __shfl_xor(s2, 16); s2 += __shfl_xor(s2, 32);
    if (qh == 0) {
      float m = s * (1.0f / 64.0f);
      float var = s2 * (1.0f / 64.0f) - m * m;
      STATS[pos] = f32x2{m, rsqrtf(var + 1e-5f)};
    }
  }
}

// -------- k_zt: z = LN(x)*w+b -> f16, transposed to Z16[d][pos] via LDS --------
__global__ __launch_bounds__(256) void k_zt(
    const float* __restrict__ X, const f32x2* __restrict__ STATS,
    const float* __restrict__ lnw, const float* __restrict__ lnb, f16* __restrict__ Z16) {
  __shared__ f16 tr[4][64][68];
  int tid = threadIdx.x;
  int widx = tid >> 6, lane = tid & 63;
  int w = blockIdx.x * 4 + widx;
  int pos0 = w * 64;
  int jq = lane >> 4, dq = lane & 15;
  f32x4 lw = *(const f32x4*)(lnw + dq * 4);
  f32x4 lb = *(const f32x4*)(lnb + dq * 4);
#pragma unroll 4
  for (int jo = 0; jo < 64; jo += 4) {
    int j = jo + jq, pos = pos0 + j;
    f32x4 x4 = *(const f32x4*)(X + (size_t)pos * 64 + dq * 4);
    f32x2 ms = STATS[pos];
    half4 z;
#pragma unroll
    for (int i2 = 0; i2 < 4; i2++) z[i2] = (f16)fmaf((x4[i2] - ms.x) * ms.y, lw[i2], lb[i2]);
    *(half4*)(&tr[widx][j][dq * 4]) = z;
  }
  __syncthreads();
  int pl = lane & 15, qh = lane >> 4;
#pragma unroll 4
  for (int i = 0; i < 16; i++) {
    int d = i * 4 + qh;
    int j4 = pl * 4;
    half4 o = half4{tr[widx][j4][d], tr[widx][j4 + 1][d], tr[widx][j4 + 2][d], tr[widx][j4 + 3][d]};
    *(half4*)(Z16 + (size_t)d * 262144 + pos0 + j4) = o;
  }
}

// -------- k_p1g: chunk end-states S16[d][bc][p32] = Z(m=bc,k=j) @ Wend(k=j,n=p) --------
__global__ __launch_bounds__(256) void k_p1g(
    const f16* __restrict__ Z16, const half8* __restrict__ WF, f16* __restrict__ S16) {
  int tid = threadIdx.x;
  int lane = tid & 63;
  int task = blockIdx.x * 4 + (tid >> 6);
  int d = task >> 7, bct = task & 127;
  int bc0 = bct * 16;
  int pl = lane & 15, qh = lane >> 4;
  half8 az[4];
  const f16* zp = Z16 + ((size_t)d * 2048 + bc0 + pl) * 128 + qh * 8;
#pragma unroll
  for (int kt = 0; kt < 4; kt++) az[kt] = *(const half8*)(zp + kt * 32);
#pragma unroll
  for (int nt = 0; nt < 2; nt++) {
    f32x4 acc = f32x4{0.f, 0.f, 0.f, 0.f};
#pragma unroll
    for (int kt = 0; kt < 4; kt++)
      acc = __builtin_amdgcn_mfma_f32_16x16x32_f16(az[kt], WF[(size_t)d * 512 + (nt * 4 + kt) * 64 + lane], acc, 0, 0, 0);
#pragma unroll
    for (int r = 0; r < 4; r++)
      S16[((size_t)d * 2048 + bc0 + qh * 4 + r) * 32 + nt * 16 + pl] = (f16)acc[r];
  }
}

// -------- pass2a: group totals over 32-chunk groups --------
__global__ __launch_bounds__(256) void k_pass2a(
    const f16* __restrict__ S16, const f32x2* __restrict__ LCLl, f32x2* __restrict__ G) {
  int t = blockIdx.x * 256 + threadIdx.x;
  int n = t & 15, g = (t >> 4) & 7, b = (t >> 7) & 7, d = t >> 10;
  f32x2 lam = LCLl[d * 16 + n];
  float cr = 0.f, ci = 0.f;
  const f16* p = S16 + ((size_t)d * 2048 + b * 256 + g * 32) * 32 + 2 * n;
#pragma unroll 8
  for (int j = 0; j < 32; j++) {
    half2t v = *(const half2t*)(p + (size_t)j * 32);
    float nr = fmaf(lam.x, cr, fmaf(-lam.y, ci, (float)v[0]));
    float ni = fmaf(lam.x, ci, fmaf(lam.y, cr, (float)v[1]));
    cr = nr; ci = ni;
  }
  G[((size_t)d * 64 + b * 8 + g) * 16 + n] = f32x2{cr, ci};
}

// -------- pass2b: exclusive scan over the 8 group totals per (d,n,b) --------
__global__ __launch_bounds__(256) void k_pass2b(
    f32x2* __restrict__ G, const f32x2* __restrict__ LC4Kl) {
  int t = blockIdx.x * 256 + threadIdx.x;
  int n = t & 15, b = (t >> 4) & 7, d = t >> 7;
  f32x2 lam = LC4Kl[d * 16 + n];
  float cr = 0.f, ci = 0.f;
#pragma unroll
  for (int g = 0; g < 8; g++) {
    size_t idx = ((size_t)d * 64 + b * 8 + g) * 16 + n;
    f32x2 tt = G[idx];
    G[idx] = f32x2{cr, ci};
    float nr = fmaf(lam.x, cr, fmaf(-lam.y, ci, tt.x));
    float ni = fmaf(lam.x, ci, fmaf(lam.y, cr, tt.y));
    cr = nr; ci = ni;
  }
}

// -------- pass2c: within-group exclusive rescan + compose -> f16 carry matrix Sc --------
__global__ __launch_bounds__(256) void k_pass2c(
    const f16* __restrict__ S16, const f32x2* __restrict__ G,
    const f32x2* __restrict__ LCLl, f16* __restrict__ Sc) {
  int t = blockIdx.x * 256 + threadIdx.x;
  int n = t & 15, g = (t >> 4) & 7, b = (t >> 7) & 7, d = t >> 10;
  f32x2 lam = LCLl[d * 16 + n];
  f32x2 c0 = G[((size_t)d * 64 + b * 8 + g) * 16 + n];
  float cr = c0.x, ci = c0.y;
  size_t base = ((size_t)d * 2048 + b * 256 + g * 32) * 32 + 2 * n;
  const f16* sp = S16 + base;
  f16* cp = Sc + base;
#pragma unroll 8
  for (int j = 0; j < 32; j++) {
    *(half2t*)(cp + (size_t)j * 32) = half2t{(f16)cr, (f16)ci};
    half2t v = *(const half2t*)(sp + (size_t)j * 32);
    float nr = fmaf(lam.x, cr, fmaf(-lam.y, ci, (float)v[0]));
    float ni = fmaf(lam.x, ci, fmaf(lam.y, cr, (float)v[1]));
    cr = nr; ci = ni;
  }
}

// -------- k_p3g2: merged (both mt halves): y = T@z + V@carry, gelu -> Y16[pos][d] --------
__global__ __launch_bounds__(256) void k_p3g2(
    const f16* __restrict__ Z16, const f16* __restrict__ Sc,
    const half8* __restrict__ TF, const half8* __restrict__ VF,
    f16* __restrict__ Y16) {
  int tid = threadIdx.x;
  int lane = tid & 63, widx = tid >> 6;
  int bct = blockIdx.x & 127, dg = blockIdx.x >> 7;  // grid 512: 4 dg x 128 bct
  int bc0 = bct * 16;
  int dbase = dg * 16 + widx * 4;
  int pl = lane & 15, qh = lane >> 4;
  half8 zb[4][4];
  half8 sb[4];
#pragma unroll
  for (int di = 0; di < 4; di++) {
    int d = dbase + di;
    const f16* zp = Z16 + ((size_t)d * 2048 + bc0 + pl) * 128 + qh * 8;
#pragma unroll
    for (int kt = 0; kt < 4; kt++) zb[di][kt] = *(const half8*)(zp + kt * 32);
    sb[di] = *(const half8*)(Sc + ((size_t)d * 2048 + bc0 + pl) * 32 + qh * 8);
  }
#pragma unroll
  for (int mt = 0; mt < 8; mt++) {
    const int KTM = mt / 2 + 1;  // causal: tiles with ji0 <= jo_max
    f32x4 acc[4];
#pragma unroll
    for (int di = 0; di < 4; di++) {
      int d = dbase + di;
      acc[di] = f32x4{0.f, 0.f, 0.f, 0.f};
      const half8* tfp = TF + ((size_t)d * 8 + mt) * 256 + lane;
#pragma unroll
      for (int kt = 0; kt < KTM; kt++)
        acc[di] = __builtin_amdgcn_mfma_f32_16x16x32_f16(tfp[kt * 64], zb[di][kt], acc[di], 0, 0, 0);
      acc[di] = __builtin_amdgcn_mfma_f32_16x16x32_f16(VF[((size_t)d * 8 + mt) * 64 + lane], sb[di], acc[di], 0, 0, 0);
    }
#pragma unroll
    for (int r = 0; r < 4; r++) {
      int pos = (bc0 + pl) * 128 + mt * 16 + qh * 4 + r;
      half4 pk = half4{(f16)gelu_t(acc[0][r]), (f16)gelu_t(acc[1][r]),
                       (f16)gelu_t(acc[2][r]), (f16)gelu_t(acc[3][r])};
      *(half4*)(Y16 + (size_t)pos * 64 + dbase) = pk;
    }
  }
}

// ======== Fused GLU+FF: residual stays in registers end-to-end ========
// GLU: u = Wg@y + bg; x += u_a*sigm(u_g)    (GEMM 16x16x32, B=Y16 frags)
// FF : z = LN(x); h = gelu(W1 z + b1); x += W2 h + b2   (GEMMs 16x16x16 —
//      B-frag layout k=4*qh+jj matches the accumulator layout, no shuffles)
// LDS: sWg half8[1024]@0 (16KB), sW1 half4[2048]@16384 (16KB), sW2 half4[2048]@32768 (16KB),
//      floats@49152: bg128,b1 128,b2 64,lnw64,lnb64 (1792B). Total 50944 -> 3 blocks/CU.
__device__ __forceinline__ void gluff_tile(
    int pos, half8 yb0, half8 yb1, f32x4* xv, const char* smembase,
    int qh, int lane, float* __restrict__ X, f32x2* __restrict__ STATS) {
  unsigned sb = 0;
  asm volatile("" : "+v"(sb));                  // opaque: defeats LICM (anti-spill, R4-proven)
  const char* sm = smembase + sb;
  const half8* sWg = (const half8*)sm;
  const half4* sW1 = (const half4*)(sm + 16384);
  const half4* sW2 = (const half4*)(sm + 32768);
  const float* sf = (const float*)(sm + 49152);
  const float* bgF = sf;
  const float* b1F = sf + 128;
  const float* b2F = sf + 256;
  const float* lnwF = sf + 320;
  const float* lnbF = sf + 384;
  // ---- GLU ----
  f32x4 accg[8];
#pragma unroll
  for (int et = 0; et < 8; et++) accg[et] = *(const f32x4*)(bgF + et * 16 + qh * 4);
#pragma unroll
  for (int et = 0; et < 8; et++)
    accg[et] = __builtin_amdgcn_mfma_f32_16x16x32_f16(sWg[(et * 2) * 64 + lane], yb0, accg[et], 0, 0, 0);
#pragma unroll
  for (int et = 0; et < 8; et++)
    accg[et] = __builtin_amdgcn_mfma_f32_16x16x32_f16(sWg[(et * 2 + 1) * 64 + lane], yb1, accg[et], 0, 0, 0);
  float s = 0.f, s2 = 0.f;
#pragma unroll
  for (int q = 0; q < 4; q++)
#pragma unroll
    for (int r = 0; r < 4; r++) {
      xv[q][r] += accg[q][r] * sigm(accg[q + 4][r]);
      s += xv[q][r]; s2 += xv[q][r] * xv[q][r];
    }
  s += __shfl_xor(s, 16); s += __shfl_xor(s, 32);
  s2 += __shfl_xor(s2, 16); s2 += __shfl_xor(s2, 32);
  float m = s * (1.0f / 64.0f);
  float rstd = rsqrtf(s2 * (1.0f / 64.0f) - m * m + 1e-5f);
  // ---- FF: LN in accumulator layout, GEMM1 via 16x16x16 (B = zb, k=4qh+jj == acc layout) ----
  half4 zb[4];
#pragma unroll
  for (int ks = 0; ks < 4; ks++) {
    f32x4 lw = *(const f32x4*)(lnwF + ks * 16 + qh * 4);
    f32x4 lb = *(const f32x4*)(lnbF + ks * 16 + qh * 4);
    half4 z;
#pragma unroll
    for (int r = 0; r < 4; r++) z[r] = (f16)fmaf((xv[ks][r] - m) * rstd, lw[r], lb[r]);
    zb[ks] = z;
  }
  f32x4 acc1[8];
#pragma unroll
  for (int et = 0; et < 8; et++) acc1[et] = *(const f32x4*)(b1F + et * 16 + qh * 4);
#pragma unroll
  for (int ks = 0; ks < 4; ks++)
#pragma unroll
    for (int et = 0; et < 8; et++)
      acc1[et] = __builtin_amdgcn_mfma_f32_16x16x16f16(sW1[(et * 4 + ks) * 64 + lane], zb[ks], acc1[et], 0, 0, 0);
  half4 h2[8];
#pragma unroll
  for (int et = 0; et < 8; et++)
    h2[et] = half4{(f16)gelu_t(acc1[et][0]), (f16)gelu_t(acc1[et][1]),
                   (f16)gelu_t(acc1[et][2]), (f16)gelu_t(acc1[et][3])};
  f32x4 acc2[4];
#pragma unroll
  for (int dt = 0; dt < 4; dt++) acc2[dt] = *(const f32x4*)(b2F + dt * 16 + qh * 4);
#pragma unroll
  for (int ks = 0; ks < 8; ks++)
#pragma unroll
    for (int dt = 0; dt < 4; dt++)
      acc2[dt] = __builtin_amdgcn_mfma_f32_16x16x16f16(sW2[(dt * 8 + ks) * 64 + lane], h2[ks], acc2[dt], 0, 0, 0);
  s = 0.f; s2 = 0.f;
#pragma unroll
  for (int dt = 0; dt < 4; dt++) {
#pragma unroll
    for (int r = 0; r < 4; r++) {
      xv[dt][r] += acc2[dt][r];
      s += xv[dt][r]; s2 += xv[dt][r] * xv[dt][r];
    }
    *(f32x4*)(X + (size_t)pos * 64 + dt * 16 + qh * 4) = xv[dt];
  }
  s += __shfl_xor(s, 16); s += __shfl_xor(s, 32);
  s2 += __shfl_xor(s2, 16); s2 += __shfl_xor(s2, 32);
  if (qh == 0) {
    float mm = s * (1.0f / 64.0f);
    float var = s2 * (1.0f / 64.0f) - mm * mm;
    STATS[pos] = f32x2{mm, rsqrtf(var + 1e-5f)};
  }
}

__global__ __launch_bounds__(256) void k_gluff2(
    const f16* __restrict__ Y16, const float* __restrict__ Wg, const float* __restrict__ bg,
    const float* __restrict__ W1, const float* __restrict__ b1,
    const float* __restrict__ W2, const float* __restrict__ b2,
    const float* __restrict__ lnw, const float* __restrict__ lnb,
    float* __restrict__ X, f32x2* __restrict__ STATS) {
  __shared__ __align__(16) char smem[50944];
  int tid = threadIdx.x;
#pragma unroll
  for (int it = 0; it < 4; it++) {           // sWg: 1024 half8 slots (et,ks2,lane)
    int s = it * 256 + tid;
    int l = s & 63, ks = (s >> 6) & 1, et = s >> 7;
    const float* wp = Wg + (et * 16 + (l & 15)) * 64 + ks * 32 + (l >> 4) * 8;
    f32x4 w0 = *(const f32x4*)wp, w1 = *(const f32x4*)(wp + 4);
    *(half8*)(smem + s * 16) = half8{(f16)w0[0], (f16)w0[1], (f16)w0[2], (f16)w0[3],
                                     (f16)w1[0], (f16)w1[1], (f16)w1[2], (f16)w1[3]};
  }
#pragma unroll
  for (int it = 0; it < 8; it++) {           // sW1: 2048 half4 slots (et,ks4,lane)
    int s = it * 256 + tid;
    int l = s & 63, ks = (s >> 6) & 3, et = s >> 8;
    const float* wp = W1 + (et * 16 + (l & 15)) * 64 + ks * 16 + (l >> 4) * 4;
    f32x4 w0 = *(const f32x4*)wp;
    *(half4*)(smem + 16384 + s * 8) = half4{(f16)w0[0], (f16)w0[1], (f16)w0[2], (f16)w0[3]};
  }
#pragma unroll
  for (int it = 0; it < 8; it++) {           // sW2: 2048 half4 slots (dt,ks8,lane)
    int s = it * 256 + tid;
    int l = s & 63, ks = (s >> 6) & 7, dt = s >> 9;
    const float* wp = W2 + (dt * 16 + (l & 15)) * 128 + ks * 16 + (l >> 4) * 4;
    f32x4 w0 = *(const f32x4*)wp;
    *(half4*)(smem + 32768 + s * 8) = half4{(f16)w0[0], (f16)w0[1], (f16)w0[2], (f16)w0[3]};
  }
  for (int idx = tid; idx < 448; idx += 256) {
    float v;
    if (idx < 128) v = bg[idx];
    else if (idx < 256) v = b1[idx - 128];
    else if (idx < 320) v = b2[idx - 256];
    else if (idx < 384) v = lnw[idx - 320];
    else v = lnb[idx - 384];
    ((float*)(smem + 49152))[idx] = v;
  }
  __syncthreads();
  int lane = tid & 63, pl = lane & 15, qh = lane >> 4;
  int wv = (blockIdx.x * 256 + tid) >> 6, nw = gridDim.x * 4;
  for (int pt = wv; pt < PT; pt += 2 * nw) {
    int ptB = pt + nw;
    bool hasB = ptB < PT;
    int posA = pt * 16 + pl, posB = ptB * 16 + pl;
    half8 ybA0 = *(const half8*)(Y16 + (size_t)posA * 64 + qh * 8);
    half8 ybA1 = *(const half8*)(Y16 + (size_t)posA * 64 + 32 + qh * 8);
    f32x4 xvA[4];
#pragma unroll
    for (int q = 0; q < 4; q++) xvA[q] = *(const f32x4*)(X + (size_t)posA * 64 + q * 16 + qh * 4);
    half8 ybB0{}, ybB1{};
    f32x4 xvB[4];
    if (hasB) {
      ybB0 = *(const half8*)(Y16 + (size_t)posB * 64 + qh * 8);
      ybB1 = *(const half8*)(Y16 + (size_t)posB * 64 + 32 + qh * 8);
#pragma unroll
      for (int q = 0; q < 4; q++) xvB[q] = *(const f32x4*)(X + (size_t)posB * 64 + q * 16 + qh * 4);
    }
    gluff_tile(posA, ybA0, ybA1, xvA, smem, qh, lane, X, STATS);
    if (hasB) gluff_tile(posB, ybB0, ybB1, xvB, smem, qh, lane, X, STATS);
  }
}

// -------- head: z=LN(x,norm); r=relu(Wf z + bf); out = wz.r + bz --------
__global__ __launch_bounds__(256) void k_head(
    const float* __restrict__ X, const f32x2* __restrict__ STATS,
    const float* __restrict__ nw_, const float* __restrict__ nb_,
    const float* __restrict__ Wf, const float* __restrict__ bfb,
    const float* __restrict__ wz, const float* __restrict__ bz,
    float* __restrict__ outp) {
  int lane = threadIdx.x & 63;
  int wv = (blockIdx.x * 256 + threadIdx.x) >> 6;
  int nwv = gridDim.x * 4;
  int pl = lane & 15, qh = lane >> 4;
  half4 af[4][4];
#pragma unroll
  for (int et = 0; et < 4; et++)
#pragma unroll
    for (int ks = 0; ks < 4; ks++) {
      f32x4 w4 = *(const f32x4*)(Wf + (et * 16 + pl) * 64 + ks * 16 + qh * 4);
      af[et][ks] = half4{(f16)w4[0], (f16)w4[1], (f16)w4[2], (f16)w4[3]};
    }
  float bz0 = bz[0];
  for (int pt = wv; pt < PT; pt += nwv) {
    int pos = pt * 16 + pl;
    f32x2 ms = STATS[pos];
    half4 bf[4];
#pragma unroll
    for (int ks = 0; ks < 4; ks++) {
      f32x4 x4 = *(const f32x4*)(X + (size_t)pos * 64 + ks * 16 + qh * 4);
      f32x4 lw = *(const f32x4*)(nw_ + ks * 16 + qh * 4);
      f32x4 lb = *(const f32x4*)(nb_ + ks * 16 + qh * 4);
      f32x4 z;
#pragma unroll
      for (int j = 0; j < 4; j++) z[j] = fmaf((x4[j] - ms.x) * ms.y, lw[j], lb[j]);
      bf[ks] = half4{(f16)z[0], (f16)z[1], (f16)z[2], (f16)z[3]};
    }
    f32x4 acc[4];
#pragma unroll
    for (int et = 0; et < 4; et++) acc[et] = *(const f32x4*)(bfb + et * 16 + qh * 4);
#pragma unroll
    for (int ks = 0; ks < 4; ks++)
#pragma unroll
      for (int et = 0; et < 4; et++)
        acc[et] = __builtin_amdgcn_mfma_f32_16x16x16f16(af[et][ks], bf[ks], acc[et], 0, 0, 0);
    float o = 0.f;
#pragma unroll
    for (int et = 0; et < 4; et++) {
      f32x4 wzv = *(const f32x4*)(wz + et * 16 + qh * 4);
#pragma unroll
      for (int r = 0; r < 4; r++) {
        float rv = acc[et][r];
        rv = rv > 0.f ? rv : 0.f;
        o = fmaf(wzv[r], rv, o);
      }
    }
    o += __shfl_xor(o, 16); o += __shfl_xor(o, 32);
    if (qh == 0) outp[pos] = o + bz0;
  }
}

extern "C" void kernel_launch(void* const* d_in, const int* in_sizes, int n_in,
                              void* d_out, int out_size, void* d_ws, size_t ws_size,
                              hipStream_t stream) {
  (void)in_sizes; (void)n_in; (void)out_size; (void)ws_size;
  const float* inputs   = (const float*)d_in[0];
  const float* w_init   = (const float*)d_in[1];
  const float* b_init   = (const float*)d_in[2];
  const float* s4_ln_w  = (const float*)d_in[3];
  const float* s4_ln_b  = (const float*)d_in[4];
  const float* log_dt   = (const float*)d_in[5];
  const float* log_A    = (const float*)d_in[6];
  const float* A_imag   = (const float*)d_in[7];
  const float* C_re     = (const float*)d_in[8];
  const float* C_im     = (const float*)d_in[9];
  const float* D_skip   = (const float*)d_in[10];
  const float* s4_out_w = (const float*)d_in[11];
  const float* s4_out_b = (const float*)d_in[12];
  const float* ff_ln_w  = (const float*)d_in[13];
  const float* ff_ln_b  = (const float*)d_in[14];
  const float* ff_w1    = (const float*)d_in[15];
  const float* ff_b1    = (const float*)d_in[16];
  const float* ff_w2    = (const float*)d_in[17];
  const float* ff_b2    = (const float*)d_in[18];
  const float* norm_w   = (const float*)d_in[19];
  const float* norm_b   = (const float*)d_in[20];
  const float* w_final1 = (const float*)d_in[21];
  const float* b_final1 = (const float*)d_in[22];
  const float* w_zero   = (const float*)d_in[23];
  const float* b_zero   = (const float*)d_in[24];

  char* w8 = (char*)d_ws;
  size_t off = 0;
  float* X     = (float*)(w8 + off); off += (size_t)67108864;   // [pos][64] f32
  f16*   Z16   = (f16*)(w8 + off);   off += (size_t)33554432;   // [d][pos] f16
  f16*   Y16   = (f16*)(w8 + off);   off += (size_t)33554432;   // [pos][d] f16
  f16*   S16   = (f16*)(w8 + off);   off += (size_t)8388608;    // [d][bc][32] f16
  f16*   Sc    = (f16*)(w8 + off);   off += (size_t)8388608;    // [d][bc][32] f16
  f32x2* STATS = (f32x2*)(w8 + off); off += (size_t)2097152;
  f32x2* G     = (f32x2*)(w8 + off); off += (size_t)524288;
  f32x2* LAM   = (f32x2*)(w8 + off); off += 32768;
  f32x2* DC2   = (f32x2*)(w8 + off); off += 32768;
  f32x2* LCL   = (f32x2*)(w8 + off); off += 32768;
  f32x2* LC4K  = (f32x2*)(w8 + off); off += 32768;
  half8* TF    = (half8*)(w8 + off); off += (size_t)2097152;
  half8* VF    = (half8*)(w8 + off); off += (size_t)524288;
  half8* WF    = (half8*)(w8 + off); off += (size_t)524288;

  k_setup<<<16, 256, 0, stream>>>(log_dt, log_A, A_imag, C_re, C_im, LAM, DC2, LCL, LC4K);
  k_init<<<2048, 256, 0, stream>>>(inputs, w_init, b_init, X, STATS);
  for (int i = 0; i < NLq; i++) {
    k_wt<<<64, 128, 0, stream>>>(LAM + i * 1024, DC2 + i * 1024, LCL + i * 1024,
                                 D_skip + i * 64, TF, VF, WF);
    k_zt<<<1024, 256, 0, stream>>>(X, STATS, s4_ln_w + i * 64, s4_ln_b + i * 64, Z16);
    k_p1g<<<2048, 256, 0, stream>>>(Z16, WF, S16);
    k_pass2a<<<256, 256, 0, stream>>>(S16, LCL + i * 1024, G);
    k_pass2b<<<32, 256, 0, stream>>>(G, LC4K + i * 1024);
    k_pass2c<<<256, 256, 0, stream>>>(S16, G, LCL + i * 1024, Sc);
    k_p3g2<<<512, 256, 0, stream>>>(Z16, Sc, TF, VF, Y16);
    k_gluff2<<<768, 256, 0, stream>>>(Y16, s4_out_w + i * 8192, s4_out_b + i * 128,
                                      ff_w1 + i * 8192, ff_b1 + i * 128,
                                      ff_w2 + i * 8192, ff_b2 + i * 64,
                                      ff_ln_w + i * 64, ff_ln_b + i * 64, X, STATS);
  }
  k_head<<<2048, 256, 0, stream>>>(X, STATS, norm_w, norm_b, w_final1, b_final1,
                                   w_zero, b_zero, (float*)d_out);
}

// Round 7
// 587.422 us; speedup vs baseline: 2.6152x; 1.0927x over previous
//
#include <hip/hip_runtime.h>
#include <cmath>

constexpr int Bq = 8, Lq = 32768, Dq = 64, Nq = 16, NLq = 4;
constexpr int CLq = 128, NCq = 256;           // NCq*CLq == Lq ; chunks per batch
constexpr int PT = Bq * Lq / 16;              // 16384 position-tiles of 16

typedef _Float16 f16;
typedef _Float16 half2t __attribute__((ext_vector_type(2)));
typedef _Float16 half4 __attribute__((ext_vector_type(4)));
typedef _Float16 half8 __attribute__((ext_vector_type(8)));
typedef float f32x4 __attribute__((ext_vector_type(4)));
typedef float f32x2 __attribute__((ext_vector_type(2)));

static __device__ __forceinline__ float sigm(float x) { return 1.0f / (1.0f + __expf(-x)); }
static __device__ __forceinline__ float gelu_t(float x) {
  return x * sigm(1.5957691216057308f * fmaf(0.044715f * x * x, x, x));
}

// -------- setup: lambda = exp(dtA), dC2 = 2*C*(lambda-1)/A, lambda^128 --------
__global__ __launch_bounds__(256) void k_setup(
    const float* __restrict__ log_dt, const float* __restrict__ log_A_real,
    const float* __restrict__ A_imag, const float* __restrict__ C_re,
    const float* __restrict__ C_im,
    f32x2* __restrict__ LAM, f32x2* __restrict__ DC2, f32x2* __restrict__ LCL) {
  int idx = blockIdx.x * 256 + threadIdx.x;
  if (idx >= NLq * Dq * Nq) return;
  int di = idx / Nq;
  float dt = expf(log_dt[di]);
  float Ar = -expf(log_A_real[idx]);
  float Ai = A_imag[idx];
  float dr = Ar * dt, dmi = Ai * dt;
  float er = expf(dr);
  float lr = er * cosf(dmi), li = er * sinf(dmi);
  float inv = 1.0f / (Ar * Ar + Ai * Ai);
  float e1r = lr - 1.0f, e1i = li;
  float qr = (e1r * Ar + e1i * Ai) * inv;
  float qi = (e1i * Ar - e1r * Ai) * inv;
  float cr = C_re[idx], ci = C_im[idx];
  LAM[idx] = f32x2{lr, li};
  DC2[idx] = f32x2{2.0f * (cr * qr - ci * qi), 2.0f * (cr * qi + ci * qr)};
  float erc = expf(dr * (float)CLq);
  LCL[idx] = f32x2{erc * cosf(dmi * (float)CLq), erc * sinf(dmi * (float)CLq)};
}

// -------- k_wtall: all layers' frag-ordered f16 matrices TF/VF/WF. grid 256: (L, d) --------
__global__ __launch_bounds__(128) void k_wtall(
    const f32x2* __restrict__ LAM, const f32x2* __restrict__ DC2,
    const f32x2* __restrict__ LCL, const float* __restrict__ dskip,
    half8* __restrict__ TF, half8* __restrict__ VF, half8* __restrict__ WF) {
  __shared__ f32x2 pw[129][16];
  __shared__ float Ks[128];
  int d = blockIdx.x & 63, L = blockIdx.x >> 6;
  const f32x2* LAMl = LAM + L * 1024;
  const f32x2* DC2l = DC2 + L * 1024;
  const f32x2* LCLl = LCL + L * 1024;
  half8* TFl = TF + (size_t)L * 131072;
  half8* VFl = VF + (size_t)L * 32768;
  half8* WFl = WF + (size_t)L * 32768;
  int t = threadIdx.x;
#pragma unroll
  for (int n = 0; n < 16; n++) {
    f32x2 lam = LAMl[d * 16 + n];
    float pr = 1.f, pi = 0.f, br = lam.x, bi = lam.y;
    int e = t;
    while (e) {
      if (e & 1) { float tt = pr * br - pi * bi; pi = fmaf(pr, bi, pi * br); pr = tt; }
      float t2 = br * br - bi * bi; bi = 2.f * br * bi; br = t2; e >>= 1;
    }
    pw[t][n] = f32x2{pr, pi};
  }
  if (t < 16) pw[128][t] = LCLl[d * 16 + t];
  __syncthreads();
  {
    float k = 0.f;
#pragma unroll
    for (int n = 0; n < 16; n++) {
      f32x2 dc = DC2l[d * 16 + n];
      f32x2 p = pw[t][n];
      k += dc.x * p.x - dc.y * p.y;
    }
    if (t == 0) k += dskip[L * 64 + d];
    Ks[t] = k;
  }
  __syncthreads();
  for (int s = t; s < 2048; s += 128) {
    int ln = s & 63, kt = (s >> 6) & 3, mt = s >> 8;
    int jo = mt * 16 + (ln & 15);
    int ji0 = kt * 32 + (ln >> 4) * 8;
    half8 v;
#pragma unroll
    for (int jj = 0; jj < 8; jj++) {
      int ji = ji0 + jj;
      v[jj] = (jo >= ji) ? (f16)Ks[jo - ji] : (f16)0.f;
    }
    TFl[(size_t)d * 2048 + s] = v;
  }
  for (int s = t; s < 512; s += 128) {
    int ln = s & 63, mt = s >> 6;
    int jo = mt * 16 + (ln & 15);
    int q0 = (ln >> 4) * 8;
    half8 v;
#pragma unroll
    for (int jj = 0; jj < 8; jj++) {
      int q = q0 + jj, n = q >> 1;
      f32x2 dc = DC2l[d * 16 + n];
      f32x2 p = pw[jo + 1][n];
      float wr = dc.x * p.x - dc.y * p.y;
      float wi = dc.x * p.y + dc.y * p.x;
      v[jj] = (q & 1) ? (f16)(-wi) : (f16)wr;
    }
    VFl[(size_t)d * 512 + s] = v;
  }
  for (int s = t; s < 512; s += 128) {
    int ln = s & 63, kt = (s >> 6) & 3, nt = s >> 8;
    int p_ = nt * 16 + (ln & 15);
    int n = p_ >> 1;
    int j0 = kt * 32 + (ln >> 4) * 8;
    half8 v;
#pragma unroll
    for (int jj = 0; jj < 8; jj++) {
      f32x2 p = pw[127 - (j0 + jj)][n];
      v[jj] = (p_ & 1) ? (f16)p.y : (f16)p.x;
    }
    WFl[(size_t)d * 512 + s] = v;
  }
}

// -------- init: x = relu(w_init*in + b_init), write LN stats --------
__global__ __launch_bounds__(256) void k_init(
    const float* __restrict__ inp, const float* __restrict__ w_init,
    const float* __restrict__ b_init, float* __restrict__ X, f32x2* __restrict__ STATS) {
  int lane = threadIdx.x & 63;
  int wv = (blockIdx.x * 256 + threadIdx.x) >> 6;
  int nw = gridDim.x * 4;
  int pl = lane & 15, qh = lane >> 4;
  for (int pt = wv; pt < PT; pt += nw) {
    int pos = pt * 16 + pl;
    float v = inp[pos];
    float s = 0.f, s2 = 0.f;
#pragma unroll
    for (int q = 0; q < 4; q++) {
      int d0 = q * 16 + qh * 4;
      f32x4 w4 = *(const f32x4*)(w_init + d0);
      f32x4 b4 = *(const f32x4*)(b_init + d0);
      f32x4 o;
#pragma unroll
      for (int j = 0; j < 4; j++) {
        float t = fmaf(w4[j], v, b4[j]);
        t = t > 0.f ? t : 0.f;
        o[j] = t; s += t; s2 += t * t;
      }
      *(f32x4*)(X + (size_t)pos * 64 + d0) = o;
    }
    s += __shfl_xor(s, 16); s += __shfl_xor(s, 32);
    s2 += __shfl_xor(s2, 16); s2 += __shfl_xor(s2, 32);
    if (qh == 0) {
      float m = s * (1.0f / 64.0f);
      float var = s2 * (1.0f / 64.0f) - m * m;
      STATS[pos] = f32x2{m, rsqrtf(var + 1e-5f)};
    }
  }
}

// -------- k_zt: z = LN(x)*w+b -> f16, transposed to Z16[d][pos] via LDS --------
__global__ __launch_bounds__(256) void k_zt(
    const float* __restrict__ X, const f32x2* __restrict__ STATS,
    const float* __restrict__ lnw, const float* __restrict__ lnb, f16* __restrict__ Z16) {
  __shared__ f16 tr[4][64][68];
  int tid = threadIdx.x;
  int widx = tid >> 6, lane = tid & 63;
  int w = blockIdx.x * 4 + widx;
  int pos0 = w * 64;
  int jq = lane >> 4, dq = lane & 15;
  f32x4 lw = *(const f32x4*)(lnw + dq * 4);
  f32x4 lb = *(const f32x4*)(lnb + dq * 4);
#pragma unroll 4
  for (int jo = 0; jo < 64; jo += 4) {
    int j = jo + jq, pos = pos0 + j;
    f32x4 x4 = *(const f32x4*)(X + (size_t)pos * 64 + dq * 4);
    f32x2 ms = STATS[pos];
    half4 z;
#pragma unroll
    for (int i2 = 0; i2 < 4; i2++) z[i2] = (f16)fmaf((x4[i2] - ms.x) * ms.y, lw[i2], lb[i2]);
    *(half4*)(&tr[widx][j][dq * 4]) = z;
  }
  __syncthreads();
  int pl = lane & 15, qh = lane >> 4;
#pragma unroll 4
  for (int i = 0; i < 16; i++) {
    int d = i * 4 + qh;
    int j4 = pl * 4;
    half4 o = half4{tr[widx][j4][d], tr[widx][j4 + 1][d], tr[widx][j4 + 2][d], tr[widx][j4 + 3][d]};
    *(half4*)(Z16 + (size_t)d * 262144 + pos0 + j4) = o;
  }
}

// -------- k_p1g: chunk end-states S16[d][bc][p32] = Z(m=bc,k=j) @ Wend(k=j,n=p) --------
__global__ __launch_bounds__(256) void k_p1g(
    const f16* __restrict__ Z16, const half8* __restrict__ WF, f16* __restrict__ S16) {
  int tid = threadIdx.x;
  int lane = tid & 63;
  int task = blockIdx.x * 4 + (tid >> 6);
  int d = task >> 7, bct = task & 127;
  int bc0 = bct * 16;
  int pl = lane & 15, qh = lane >> 4;
  half8 az[4];
  const f16* zp = Z16 + ((size_t)d * 2048 + bc0 + pl) * 128 + qh * 8;
#pragma unroll
  for (int kt = 0; kt < 4; kt++) az[kt] = *(const half8*)(zp + kt * 32);
#pragma unroll
  for (int nt = 0; nt < 2; nt++) {
    f32x4 acc = f32x4{0.f, 0.f, 0.f, 0.f};
#pragma unroll
    for (int kt = 0; kt < 4; kt++)
      acc = __builtin_amdgcn_mfma_f32_16x16x32_f16(az[kt], WF[(size_t)d * 512 + (nt * 4 + kt) * 64 + lane], acc, 0, 0, 0);
#pragma unroll
    for (int r = 0; r < 4; r++)
      S16[((size_t)d * 2048 + bc0 + qh * 4 + r) * 32 + nt * 16 + pl] = (f16)acc[r];
  }
}

// -------- k_pass2: single-kernel exclusive scan over 256 chunks per (d,b,n) -> Sc --------
__global__ __launch_bounds__(128) void k_pass2(
    const f16* __restrict__ S16, const f32x2* __restrict__ LCLl, f16* __restrict__ Sc) {
  int d = blockIdx.x;                 // 64 blocks
  int t = threadIdx.x;                // 128 = (b 8, n 16)
  int n = t & 15, b = t >> 4;
  f32x2 lam = LCLl[d * 16 + n];
  float cr = 0.f, ci = 0.f;
  size_t base = ((size_t)d * 2048 + b * 256) * 32 + 2 * n;
  const f16* sp = S16 + base;
  f16* cp = Sc + base;
#pragma unroll 8
  for (int c = 0; c < 256; c++) {
    *(half2t*)(cp + (size_t)c * 32) = half2t{(f16)cr, (f16)ci};
    half2t v = *(const half2t*)(sp + (size_t)c * 32);
    float nr = fmaf(lam.x, cr, fmaf(-lam.y, ci, (float)v[0]));
    float ni = fmaf(lam.x, ci, fmaf(lam.y, cr, (float)v[1]));
    cr = nr; ci = ni;
  }
}

// -------- k_p3g2: y = T@z + V@carry, gelu -> Y16[pos][d] (d-packed half4) --------
__global__ __launch_bounds__(256) void k_p3g2(
    const f16* __restrict__ Z16, const f16* __restrict__ Sc,
    const half8* __restrict__ TF, const half8* __restrict__ VF,
    f16* __restrict__ Y16) {
  int tid = threadIdx.x;
  int lane = tid & 63, widx = tid >> 6;
  int bct = blockIdx.x & 127, dg = blockIdx.x >> 7;  // grid 512: 4 dg x 128 bct
  int bc0 = bct * 16;
  int dbase = dg * 16 + widx * 4;
  int pl = lane & 15, qh = lane >> 4;
  half8 zb[4][4];
  half8 sb[4];
#pragma unroll
  for (int di = 0; di < 4; di++) {
    int d = dbase + di;
    const f16* zp = Z16 + ((size_t)d * 2048 + bc0 + pl) * 128 + qh * 8;
#pragma unroll
    for (int kt = 0; kt < 4; kt++) zb[di][kt] = *(const half8*)(zp + kt * 32);
    sb[di] = *(const half8*)(Sc + ((size_t)d * 2048 + bc0 + pl) * 32 + qh * 8);
  }
#pragma unroll
  for (int mt = 0; mt < 8; mt++) {
    const int KTM = mt / 2 + 1;  // causal: tiles with ji0 <= jo_max
    f32x4 acc[4];
#pragma unroll
    for (int di = 0; di < 4; di++) {
      int d = dbase + di;
      acc[di] = f32x4{0.f, 0.f, 0.f, 0.f};
      const half8* tfp = TF + ((size_t)d * 8 + mt) * 256 + lane;
#pragma unroll
      for (int kt = 0; kt < KTM; kt++)
        acc[di] = __builtin_amdgcn_mfma_f32_16x16x32_f16(tfp[kt * 64], zb[di][kt], acc[di], 0, 0, 0);
      acc[di] = __builtin_amdgcn_mfma_f32_16x16x32_f16(VF[((size_t)d * 8 + mt) * 64 + lane], sb[di], acc[di], 0, 0, 0);
    }
#pragma unroll
    for (int r = 0; r < 4; r++) {
      int pos = (bc0 + pl) * 128 + mt * 16 + qh * 4 + r;
      half4 pk = half4{(f16)gelu_t(acc[0][r]), (f16)gelu_t(acc[1][r]),
                       (f16)gelu_t(acc[2][r]), (f16)gelu_t(acc[3][r])};
      *(half4*)(Y16 + (size_t)pos * 64 + dbase) = pk;
    }
  }
}

// ======== Fused GLU+FF: residual stays in registers; FF GEMMs in K=32 permuted frags ========
// Slot convention for FF GEMMs: slot(qh,jj) <-> k = ks*32 + (jj>>2)*16 + qh*4 + (jj&3),
// which equals the C/D accumulator layout, so z/h B-frags are concat of native half4s.
// LDS: sWg half8[1024]@0, sW1 half8[1024]@16384, sW2 half8[1024]@32768, floats@49152 (448).
__device__ __forceinline__ void gluff_tile(
    int pos, half8 yb0, half8 yb1, f32x4* xv, const char* smembase,
    int qh, int lane, float* __restrict__ X, f32x2* __restrict__ STATS) {
  unsigned sb = 0;
  asm volatile("" : "+v"(sb));                  // opaque: defeats LICM (anti-spill, R4-proven)
  const char* sm = smembase + sb;
  const half8* sWg = (const half8*)sm;
  const half8* sW1 = (const half8*)(sm + 16384);
  const half8* sW2 = (const half8*)(sm + 32768);
  const float* sf = (const float*)(sm + 49152);
  const float* bgF = sf;
  const float* b1F = sf + 128;
  const float* b2F = sf + 256;
  const float* lnwF = sf + 320;
  const float* lnbF = sf + 384;
  // ---- GLU (natural K=32 frags) ----
  f32x4 accg[8];
#pragma unroll
  for (int et = 0; et < 8; et++) accg[et] = *(const f32x4*)(bgF + et * 16 + qh * 4);
#pragma unroll
  for (int et = 0; et < 8; et++)
    accg[et] = __builtin_amdgcn_mfma_f32_16x16x32_f16(sWg[(et * 2) * 64 + lane], yb0, accg[et], 0, 0, 0);
#pragma unroll
  for (int et = 0; et < 8; et++)
    accg[et] = __builtin_amdgcn_mfma_f32_16x16x32_f16(sWg[(et * 2 + 1) * 64 + lane], yb1, accg[et], 0, 0, 0);
  float s = 0.f, s2 = 0.f;
#pragma unroll
  for (int q = 0; q < 4; q++)
#pragma unroll
    for (int r = 0; r < 4; r++) {
      xv[q][r] += accg[q][r] * sigm(accg[q + 4][r]);
      s += xv[q][r]; s2 += xv[q][r] * xv[q][r];
    }
  s += __shfl_xor(s, 16); s += __shfl_xor(s, 32);
  s2 += __shfl_xor(s2, 16); s2 += __shfl_xor(s2, 32);
  float m = s * (1.0f / 64.0f);
  float rstd = rsqrtf(s2 * (1.0f / 64.0f) - m * m + 1e-5f);
  // ---- FF GEMM1: K=64 as 2 chunks of 32, permuted slots ----
  half4 zb4[4];
#pragma unroll
  for (int ks = 0; ks < 4; ks++) {
    f32x4 lw = *(const f32x4*)(lnwF + ks * 16 + qh * 4);
    f32x4 lb = *(const f32x4*)(lnbF + ks * 16 + qh * 4);
    half4 z;
#pragma unroll
    for (int r = 0; r < 4; r++) z[r] = (f16)fmaf((xv[ks][r] - m) * rstd, lw[r], lb[r]);
    zb4[ks] = z;
  }
  f32x4 acc1[8];
#pragma unroll
  for (int et = 0; et < 8; et++) acc1[et] = *(const f32x4*)(b1F + et * 16 + qh * 4);
#pragma unroll
  for (int ks = 0; ks < 2; ks++) {
    half4 a = zb4[ks * 2], b = zb4[ks * 2 + 1];
    half8 zb8 = half8{a[0], a[1], a[2], a[3], b[0], b[1], b[2], b[3]};
#pragma unroll
    for (int et = 0; et < 8; et++)
      acc1[et] = __builtin_amdgcn_mfma_f32_16x16x32_f16(sW1[(et * 2 + ks) * 64 + lane], zb8, acc1[et], 0, 0, 0);
  }
  half4 h4[8];
#pragma unroll
  for (int et = 0; et < 8; et++)
    h4[et] = half4{(f16)gelu_t(acc1[et][0]), (f16)gelu_t(acc1[et][1]),
                   (f16)gelu_t(acc1[et][2]), (f16)gelu_t(acc1[et][3])};
  // ---- FF GEMM2: K=128 as 4 chunks of 32, permuted slots ----
  f32x4 acc2[4];
#pragma unroll
  for (int dt = 0; dt < 4; dt++) acc2[dt] = *(const f32x4*)(b2F + dt * 16 + qh * 4);
#pragma unroll
  for (int ks = 0; ks < 4; ks++) {
    half4 a = h4[ks * 2], b = h4[ks * 2 + 1];
    half8 hb8 = half8{a[0], a[1], a[2], a[3], b[0], b[1], b[2], b[3]};
#pragma unroll
    for (int dt = 0; dt < 4; dt++)
      acc2[dt] = __builtin_amdgcn_mfma_f32_16x16x32_f16(sW2[(dt * 4 + ks) * 64 + lane], hb8, acc2[dt], 0, 0, 0);
  }
  s = 0.f; s2 = 0.f;
#pragma unroll
  for (int dt = 0; dt < 4; dt++) {
#pragma unroll
    for (int r = 0; r < 4; r++) {
      xv[dt][r] += acc2[dt][r];
      s += xv[dt][r]; s2 += xv[dt][r] * xv[dt][r];
    }
    *(f32x4*)(X + (size_t)pos * 64 + dt * 16 + qh * 4) = xv[dt];
  }
  s += __shfl_xor(s, 16); s += __shfl_xor(s, 32);
  s2 += __shfl_xor(s2, 16); s2 += __shfl_xor(s2, 32);
  if (qh == 0) {
    float mm = s * (1.0f / 64.0f);
    float var = s2 * (1.0f / 64.0f) - mm * mm;
    STATS[pos] = f32x2{mm, rsqrtf(var + 1e-5f)};
  }
}

__global__ __launch_bounds__(512) void k_gluff2(
    const f16* __restrict__ Y16, const float* __restrict__ Wg, const float* __restrict__ bg,
    const float* __restrict__ W1, const float* __restrict__ b1,
    const float* __restrict__ W2, const float* __restrict__ b2,
    const float* __restrict__ lnw, const float* __restrict__ lnb,
    float* __restrict__ X, f32x2* __restrict__ STATS) {
  __shared__ __align__(16) char smem[50944];
  int tid = threadIdx.x;
#pragma unroll
  for (int it = 0; it < 2; it++) {           // sWg: 1024 half8 slots (et,ks2,lane) NATURAL k
    int s = it * 512 + tid;
    int l = s & 63, ks = (s >> 6) & 1, et = s >> 7;
    const float* wp = Wg + (et * 16 + (l & 15)) * 64 + ks * 32 + (l >> 4) * 8;
    f32x4 w0 = *(const f32x4*)wp, w1 = *(const f32x4*)(wp + 4);
    *(half8*)(smem + s * 16) = half8{(f16)w0[0], (f16)w0[1], (f16)w0[2], (f16)w0[3],
                                     (f16)w1[0], (f16)w1[1], (f16)w1[2], (f16)w1[3]};
  }
#pragma unroll
  for (int it = 0; it < 2; it++) {           // sW1: 1024 half8 slots (et,ks2,lane) PERMUTED k
    int s = it * 512 + tid;
    int l = s & 63, ks = (s >> 6) & 1, et = s >> 7;
    int pl = l & 15, qh = l >> 4;
    const float* wp = W1 + (et * 16 + pl) * 64 + ks * 32 + qh * 4;
    f32x4 w0 = *(const f32x4*)wp;            // k = ks*32 + qh*4 + (0..3)
    f32x4 w1 = *(const f32x4*)(wp + 16);     // k = ks*32 + 16 + qh*4 + (0..3)
    *(half8*)(smem + 16384 + s * 16) = half8{(f16)w0[0], (f16)w0[1], (f16)w0[2], (f16)w0[3],
                                             (f16)w1[0], (f16)w1[1], (f16)w1[2], (f16)w1[3]};
  }
#pragma unroll
  for (int it = 0; it < 2; it++) {           // sW2: 1024 half8 slots (dt,ks4,lane) PERMUTED k
    int s = it * 512 + tid;
    int l = s & 63, ks = (s >> 6) & 3, dt = s >> 8;
    int pl = l & 15, qh = l >> 4;
    const float* wp = W2 + (dt * 16 + pl) * 128 + ks * 32 + qh * 4;
    f32x4 w0 = *(const f32x4*)wp;
    f32x4 w1 = *(const f32x4*)(wp + 16);
    *(half8*)(smem + 32768 + s * 16) = half8{(f16)w0[0], (f16)w0[1], (f16)w0[2], (f16)w0[3],
                                             (f16)w1[0], (f16)w1[1], (f16)w1[2], (f16)w1[3]};
  }
  if (tid < 448) {
    float v;
    if (tid < 128) v = bg[tid];
    else if (tid < 256) v = b1[tid - 128];
    else if (tid < 320) v = b2[tid - 256];
    else if (tid < 384) v = lnw[tid - 320];
    else v = lnb[tid - 384];
    ((float*)(smem + 49152))[tid] = v;
  }
  __syncthreads();
  int lane = tid & 63, pl = lane & 15, qh = lane >> 4;
  int wv = (blockIdx.x * 512 + tid) >> 6;    // 0..4095
#pragma unroll
  for (int k = 0; k < 2; k++) {
    int ptA = wv + k * 8192;
    int ptB = ptA + 4096;
    int posA = ptA * 16 + pl, posB = ptB * 16 + pl;
    half8 ybA0 = *(const half8*)(Y16 + (size_t)posA * 64 + qh * 8);
    half8 ybA1 = *(const half8*)(Y16 + (size_t)posA * 64 + 32 + qh * 8);
    f32x4 xvA[4];
#pragma unroll
    for (int q = 0; q < 4; q++) xvA[q] = *(const f32x4*)(X + (size_t)posA * 64 + q * 16 + qh * 4);
    half8 ybB0 = *(const half8*)(Y16 + (size_t)posB * 64 + qh * 8);
    half8 ybB1 = *(const half8*)(Y16 + (size_t)posB * 64 + 32 + qh * 8);
    f32x4 xvB[4];
#pragma unroll
    for (int q = 0; q < 4; q++) xvB[q] = *(const f32x4*)(X + (size_t)posB * 64 + q * 16 + qh * 4);
    gluff_tile(posA, ybA0, ybA1, xvA, smem, qh, lane, X, STATS);
    gluff_tile(posB, ybB0, ybB1, xvB, smem, qh, lane, X, STATS);
  }
}

// -------- head: z=LN(x,norm); r=relu(Wf z + bf); out = wz.r + bz --------
__global__ __launch_bounds__(256) void k_head(
    const float* __restrict__ X, const f32x2* __restrict__ STATS,
    const float* __restrict__ nw_, const float* __restrict__ nb_,
    const float* __restrict__ Wf, const float* __restrict__ bfb,
    const float* __restrict__ wz, const float* __restrict__ bz,
    float* __restrict__ outp) {
  int lane = threadIdx.x & 63;
  int wv = (blockIdx.x * 256 + threadIdx.x) >> 6;
  int nwv = gridDim.x * 4;
  int pl = lane & 15, qh = lane >> 4;
  half4 af[4][4];
#pragma unroll
  for (int et = 0; et < 4; et++)
#pragma unroll
    for (int ks = 0; ks < 4; ks++) {
      f32x4 w4 = *(const f32x4*)(Wf + (et * 16 + pl) * 64 + ks * 16 + qh * 4);
      af[et][ks] = half4{(f16)w4[0], (f16)w4[1], (f16)w4[2], (f16)w4[3]};
    }
  float bz0 = bz[0];
  for (int pt = wv; pt < PT; pt += nwv) {
    int pos = pt * 16 + pl;
    f32x2 ms = STATS[pos];
    half4 bf[4];
#pragma unroll
    for (int ks = 0; ks < 4; ks++) {
      f32x4 x4 = *(const f32x4*)(X + (size_t)pos * 64 + ks * 16 + qh * 4);
      f32x4 lw = *(const f32x4*)(nw_ + ks * 16 + qh * 4);
      f32x4 lb = *(const f32x4*)(nb_ + ks * 16 + qh * 4);
      f32x4 z;
#pragma unroll
      for (int j = 0; j < 4; j++) z[j] = fmaf((x4[j] - ms.x) * ms.y, lw[j], lb[j]);
      bf[ks] = half4{(f16)z[0], (f16)z[1], (f16)z[2], (f16)z[3]};
    }
    f32x4 acc[4];
#pragma unroll
    for (int et = 0; et < 4; et++) acc[et] = *(const f32x4*)(bfb + et * 16 + qh * 4);
#pragma unroll
    for (int ks = 0; ks < 4; ks++)
#pragma unroll
      for (int et = 0; et < 4; et++)
        acc[et] = __builtin_amdgcn_mfma_f32_16x16x16f16(af[et][ks], bf[ks], acc[et], 0, 0, 0);
    float o = 0.f;
#pragma unroll
    for (int et = 0; et < 4; et++) {
      f32x4 wzv = *(const f32x4*)(wz + et * 16 + qh * 4);
#pragma unroll
      for (int r = 0; r < 4; r++) {
        float rv = acc[et][r];
        rv = rv > 0.f ? rv : 0.f;
        o = fmaf(wzv[r], rv, o);
      }
    }
    o += __shfl_xor(o, 16); o += __shfl_xor(o, 32);
    if (qh == 0) outp[pos] = o + bz0;
  }
}

extern "C" void kernel_launch(void* const* d_in, const int* in_sizes, int n_in,
                              void* d_out, int out_size, void* d_ws, size_t ws_size,
                              hipStream_t stream) {
  (void)in_sizes; (void)n_in; (void)out_size; (void)ws_size;
  const float* inputs   = (const float*)d_in[0];
  const float* w_init   = (const float*)d_in[1];
  const float* b_init   = (const float*)d_in[2];
  const float* s4_ln_w  = (const float*)d_in[3];
  const float* s4_ln_b  = (const float*)d_in[4];
  const float* log_dt   = (const float*)d_in[5];
  const float* log_A    = (const float*)d_in[6];
  const float* A_imag   = (const float*)d_in[7];
  const float* C_re     = (const float*)d_in[8];
  const float* C_im     = (const float*)d_in[9];
  const float* D_skip   = (const float*)d_in[10];
  const float* s4_out_w = (const float*)d_in[11];
  const float* s4_out_b = (const float*)d_in[12];
  const float* ff_ln_w  = (const float*)d_in[13];
  const float* ff_ln_b  = (const float*)d_in[14];
  const float* ff_w1    = (const float*)d_in[15];
  const float* ff_b1    = (const float*)d_in[16];
  const float* ff_w2    = (const float*)d_in[17];
  const float* ff_b2    = (const float*)d_in[18];
  const float* norm_w   = (const float*)d_in[19];
  const float* norm_b   = (const float*)d_in[20];
  const float* w_final1 = (const float*)d_in[21];
  const float* b_final1 = (const float*)d_in[22];
  const float* w_zero   = (const float*)d_in[23];
  const float* b_zero   = (const float*)d_in[24];

  char* w8 = (char*)d_ws;
  size_t off = 0;
  float* X     = (float*)(w8 + off); off += (size_t)67108864;   // [pos][64] f32
  f16*   Z16   = (f16*)(w8 + off);   off += (size_t)33554432;   // [d][pos] f16
  f16*   Y16   = (f16*)(w8 + off);   off += (size_t)33554432;   // [pos][d] f16
  f16*   S16   = (f16*)(w8 + off);   off += (size_t)8388608;    // [d][bc][32] f16
  f16*   Sc    = (f16*)(w8 + off);   off += (size_t)8388608;    // [d][bc][32] f16
  f32x2* STATS = (f32x2*)(w8 + off); off += (size_t)2097152;
  f32x2* LAM   = (f32x2*)(w8 + off); off += 32768;
  f32x2* DC2   = (f32x2*)(w8 + off); off += 32768;
  f32x2* LCL   = (f32x2*)(w8 + off); off += 32768;
  half8* TF    = (half8*)(w8 + off); off += (size_t)8388608;    // 4 layers x 2MB
  half8* VF    = (half8*)(w8 + off); off += (size_t)2097152;    // 4 layers x 0.5MB
  half8* WF    = (half8*)(w8 + off); off += (size_t)2097152;    // 4 layers x 0.5MB

  k_setup<<<16, 256, 0, stream>>>(log_dt, log_A, A_imag, C_re, C_im, LAM, DC2, LCL);
  k_wtall<<<256, 128, 0, stream>>>(LAM, DC2, LCL, D_skip, TF, VF, WF);
  k_init<<<2048, 256, 0, stream>>>(inputs, w_init, b_init, X, STATS);
  for (int i = 0; i < NLq; i++) {
    k_zt<<<1024, 256, 0, stream>>>(X, STATS, s4_ln_w + i * 64, s4_ln_b + i * 64, Z16);
    k_p1g<<<2048, 256, 0, stream>>>(Z16, WF + (size_t)i * 32768, S16);
    k_pass2<<<64, 128, 0, stream>>>(S16, LCL + i * 1024, Sc);
    k_p3g2<<<512, 256, 0, stream>>>(Z16, Sc, TF + (size_t)i * 131072, VF + (size_t)i * 32768, Y16);
    k_gluff2<<<512, 512, 0, stream>>>(Y16, s4_out_w + i * 8192, s4_out_b + i * 128,
                                      ff_w1 + i * 8192, ff_b1 + i * 128,
                                      ff_w2 + i * 8192, ff_b2 + i * 64,
                                      ff_ln_w + i * 64, ff_ln_b + i * 64, X, STATS);
  }
  k_head<<<2048, 256, 0, stream>>>(X, STATS, norm_w, norm_b, w_final1, b_final1,
                                   w_zero, b_zero, (float*)d_out);
}

// Round 8
// 533.989 us; speedup vs baseline: 2.8769x; 1.1001x over previous
//
#include <hip/hip_runtime.h>
#include <cmath>

constexpr int Bq = 8, Lq = 32768, Dq = 64, Nq = 16, NLq = 4;
constexpr int CLq = 128, NCq = 256;           // NCq*CLq == Lq ; chunks per batch
constexpr int PT = Bq * Lq / 16;              // 16384 position-tiles of 16

typedef _Float16 f16;
typedef _Float16 half2t __attribute__((ext_vector_type(2)));
typedef _Float16 half4 __attribute__((ext_vector_type(4)));
typedef _Float16 half8 __attribute__((ext_vector_type(8)));
typedef float f32x4 __attribute__((ext_vector_type(4)));
typedef float f32x2 __attribute__((ext_vector_type(2)));

static __device__ __forceinline__ float sigm(float x) { return 1.0f / (1.0f + __expf(-x)); }
static __device__ __forceinline__ float gelu_t(float x) {
  return x * sigm(1.5957691216057308f * fmaf(0.044715f * x * x, x, x));
}

// -------- setup: lambda = exp(dtA), dC2 = 2*C*(lambda-1)/A, lambda^128 --------
__global__ __launch_bounds__(256) void k_setup(
    const float* __restrict__ log_dt, const float* __restrict__ log_A_real,
    const float* __restrict__ A_imag, const float* __restrict__ C_re,
    const float* __restrict__ C_im,
    f32x2* __restrict__ LAM, f32x2* __restrict__ DC2, f32x2* __restrict__ LCL) {
  int idx = blockIdx.x * 256 + threadIdx.x;
  if (idx >= NLq * Dq * Nq) return;
  int di = idx / Nq;
  float dt = expf(log_dt[di]);
  float Ar = -expf(log_A_real[idx]);
  float Ai = A_imag[idx];
  float dr = Ar * dt, dmi = Ai * dt;
  float er = expf(dr);
  float lr = er * cosf(dmi), li = er * sinf(dmi);
  float inv = 1.0f / (Ar * Ar + Ai * Ai);
  float e1r = lr - 1.0f, e1i = li;
  float qr = (e1r * Ar + e1i * Ai) * inv;
  float qi = (e1i * Ar - e1r * Ai) * inv;
  float cr = C_re[idx], ci = C_im[idx];
  LAM[idx] = f32x2{lr, li};
  DC2[idx] = f32x2{2.0f * (cr * qr - ci * qi), 2.0f * (cr * qi + ci * qr)};
  float erc = expf(dr * (float)CLq);
  LCL[idx] = f32x2{erc * cosf(dmi * (float)CLq), erc * sinf(dmi * (float)CLq)};
}

// -------- k_wtall: all layers' frag-ordered f16 matrices TF/VF/WF. grid 256: (L, d) --------
__global__ __launch_bounds__(128) void k_wtall(
    const f32x2* __restrict__ LAM, const f32x2* __restrict__ DC2,
    const f32x2* __restrict__ LCL, const float* __restrict__ dskip,
    half8* __restrict__ TF, half8* __restrict__ VF, half8* __restrict__ WF) {
  __shared__ f32x2 pw[129][16];
  __shared__ float Ks[128];
  int d = blockIdx.x & 63, L = blockIdx.x >> 6;
  const f32x2* LAMl = LAM + L * 1024;
  const f32x2* DC2l = DC2 + L * 1024;
  const f32x2* LCLl = LCL + L * 1024;
  half8* TFl = TF + (size_t)L * 131072;
  half8* VFl = VF + (size_t)L * 32768;
  half8* WFl = WF + (size_t)L * 32768;
  int t = threadIdx.x;
#pragma unroll
  for (int n = 0; n < 16; n++) {
    f32x2 lam = LAMl[d * 16 + n];
    float pr = 1.f, pi = 0.f, br = lam.x, bi = lam.y;
    int e = t;
    while (e) {
      if (e & 1) { float tt = pr * br - pi * bi; pi = fmaf(pr, bi, pi * br); pr = tt; }
      float t2 = br * br - bi * bi; bi = 2.f * br * bi; br = t2; e >>= 1;
    }
    pw[t][n] = f32x2{pr, pi};
  }
  if (t < 16) pw[128][t] = LCLl[d * 16 + t];
  __syncthreads();
  {
    float k = 0.f;
#pragma unroll
    for (int n = 0; n < 16; n++) {
      f32x2 dc = DC2l[d * 16 + n];
      f32x2 p = pw[t][n];
      k += dc.x * p.x - dc.y * p.y;
    }
    if (t == 0) k += dskip[L * 64 + d];
    Ks[t] = k;
  }
  __syncthreads();
  for (int s = t; s < 2048; s += 128) {
    int ln = s & 63, kt = (s >> 6) & 3, mt = s >> 8;
    int jo = mt * 16 + (ln & 15);
    int ji0 = kt * 32 + (ln >> 4) * 8;
    half8 v;
#pragma unroll
    for (int jj = 0; jj < 8; jj++) {
      int ji = ji0 + jj;
      v[jj] = (jo >= ji) ? (f16)Ks[jo - ji] : (f16)0.f;
    }
    TFl[(size_t)d * 2048 + s] = v;
  }
  for (int s = t; s < 512; s += 128) {
    int ln = s & 63, mt = s >> 6;
    int jo = mt * 16 + (ln & 15);
    int q0 = (ln >> 4) * 8;
    half8 v;
#pragma unroll
    for (int jj = 0; jj < 8; jj++) {
      int q = q0 + jj, n = q >> 1;
      f32x2 dc = DC2l[d * 16 + n];
      f32x2 p = pw[jo + 1][n];
      float wr = dc.x * p.x - dc.y * p.y;
      float wi = dc.x * p.y + dc.y * p.x;
      v[jj] = (q & 1) ? (f16)(-wi) : (f16)wr;
    }
    VFl[(size_t)d * 512 + s] = v;
  }
  for (int s = t; s < 512; s += 128) {
    int ln = s & 63, kt = (s >> 6) & 3, nt = s >> 8;
    int p_ = nt * 16 + (ln & 15);
    int n = p_ >> 1;
    int j0 = kt * 32 + (ln >> 4) * 8;
    half8 v;
#pragma unroll
    for (int jj = 0; jj < 8; jj++) {
      f32x2 p = pw[127 - (j0 + jj)][n];
      v[jj] = (p_ & 1) ? (f16)p.y : (f16)p.x;
    }
    WFl[(size_t)d * 512 + s] = v;
  }
}

// -------- k_init3: x = relu(w_init*in + b_init); z = s4LN0(x) -> Z16 (LDS transpose) --------
__global__ __launch_bounds__(512) void k_init3(
    const float* __restrict__ inp, const float* __restrict__ w_init,
    const float* __restrict__ b_init, const float* __restrict__ lnw,
    const float* __restrict__ lnb, float* __restrict__ X, f16* __restrict__ Z16) {
  __shared__ __align__(16) f16 ztile[64 * 132];
  int tid = threadIdx.x;
  int widx = tid >> 6, lane = tid & 63;
  int pl = lane & 15, qh = lane >> 4;
  for (int k = 0; k < 4; ++k) {
    int pt = blockIdx.x * 8 + widx + k * 4096;
    int pos = pt * 16 + pl;
    float v = inp[pos];
    float s = 0.f, s2 = 0.f;
    f32x4 o[4];
#pragma unroll
    for (int q = 0; q < 4; q++) {
      int d0 = q * 16 + qh * 4;
      f32x4 w4 = *(const f32x4*)(w_init + d0);
      f32x4 b4 = *(const f32x4*)(b_init + d0);
#pragma unroll
      for (int j = 0; j < 4; j++) {
        float t = fmaf(w4[j], v, b4[j]);
        t = t > 0.f ? t : 0.f;
        o[q][j] = t; s += t; s2 += t * t;
      }
      *(f32x4*)(X + (size_t)pos * 64 + d0) = o[q];
    }
    s += __shfl_xor(s, 16); s += __shfl_xor(s, 32);
    s2 += __shfl_xor(s2, 16); s2 += __shfl_xor(s2, 32);
    float m = s * (1.0f / 64.0f);
    float rstd = rsqrtf(s2 * (1.0f / 64.0f) - m * m + 1e-5f);
    int prow = widx * 16 + pl;
#pragma unroll
    for (int q = 0; q < 4; q++) {
      int d0 = q * 16 + qh * 4;
      f32x4 lw = *(const f32x4*)(lnw + d0);
      f32x4 lb = *(const f32x4*)(lnb + d0);
#pragma unroll
      for (int r = 0; r < 4; r++)
        ztile[(d0 + r) * 132 + prow] = (f16)fmaf((o[q][r] - m) * rstd, lw[r], lb[r]);
    }
    __syncthreads();
    {
      int d = tid >> 3, c0 = (tid & 7) * 16;
      half8 z0 = *(const half8*)(ztile + d * 132 + c0);
      half8 z1 = *(const half8*)(ztile + d * 132 + c0 + 8);
      size_t zoff = (size_t)d * 262144 + (size_t)(blockIdx.x * 8 + k * 4096) * 16;
      *(half8*)(Z16 + zoff + c0) = z0;
      *(half8*)(Z16 + zoff + c0 + 8) = z1;
    }
    __syncthreads();
  }
}

// -------- k_p1g: chunk end-states S16[d][bc][p32] = Z(m=bc,k=j) @ Wend(k=j,n=p) --------
__global__ __launch_bounds__(256) void k_p1g(
    const f16* __restrict__ Z16, const half8* __restrict__ WF, f16* __restrict__ S16) {
  int tid = threadIdx.x;
  int lane = tid & 63;
  int task = blockIdx.x * 4 + (tid >> 6);
  int d = task >> 7, bct = task & 127;
  int bc0 = bct * 16;
  int pl = lane & 15, qh = lane >> 4;
  half8 az[4];
  const f16* zp = Z16 + ((size_t)d * 2048 + bc0 + pl) * 128 + qh * 8;
#pragma unroll
  for (int kt = 0; kt < 4; kt++) az[kt] = *(const half8*)(zp + kt * 32);
#pragma unroll
  for (int nt = 0; nt < 2; nt++) {
    f32x4 acc = f32x4{0.f, 0.f, 0.f, 0.f};
#pragma unroll
    for (int kt = 0; kt < 4; kt++)
      acc = __builtin_amdgcn_mfma_f32_16x16x32_f16(az[kt], WF[(size_t)d * 512 + (nt * 4 + kt) * 64 + lane], acc, 0, 0, 0);
#pragma unroll
    for (int r = 0; r < 4; r++)
      S16[((size_t)d * 2048 + bc0 + qh * 4 + r) * 32 + nt * 16 + pl] = (f16)acc[r];
  }
}

// -------- k_pass2: single-kernel exclusive scan over 256 chunks per (d,b,n) -> Sc --------
__global__ __launch_bounds__(128) void k_pass2(
    const f16* __restrict__ S16, const f32x2* __restrict__ LCLl, f16* __restrict__ Sc) {
  int d = blockIdx.x;                 // 64 blocks
  int t = threadIdx.x;                // 128 = (b 8, n 16)
  int n = t & 15, b = t >> 4;
  f32x2 lam = LCLl[d * 16 + n];
  float cr = 0.f, ci = 0.f;
  size_t base = ((size_t)d * 2048 + b * 256) * 32 + 2 * n;
  const f16* sp = S16 + base;
  f16* cp = Sc + base;
#pragma unroll 8
  for (int c = 0; c < 256; c++) {
    *(half2t*)(cp + (size_t)c * 32) = half2t{(f16)cr, (f16)ci};
    half2t v = *(const half2t*)(sp + (size_t)c * 32);
    float nr = fmaf(lam.x, cr, fmaf(-lam.y, ci, (float)v[0]));
    float ni = fmaf(lam.x, ci, fmaf(lam.y, cr, (float)v[1]));
    cr = nr; ci = ni;
  }
}

// -------- k_p3g2: y = T@z + V@carry, gelu -> Y16[pos][d] (d-packed half4) --------
__global__ __launch_bounds__(256) void k_p3g2(
    const f16* __restrict__ Z16, const f16* __restrict__ Sc,
    const half8* __restrict__ TF, const half8* __restrict__ VF,
    f16* __restrict__ Y16) {
  int tid = threadIdx.x;
  int lane = tid & 63, widx = tid >> 6;
  int bct = blockIdx.x & 127, dg = blockIdx.x >> 7;  // grid 512: 4 dg x 128 bct
  int bc0 = bct * 16;
  int dbase = dg * 16 + widx * 4;
  int pl = lane & 15, qh = lane >> 4;
  half8 zb[4][4];
  half8 sb[4];
#pragma unroll
  for (int di = 0; di < 4; di++) {
    int d = dbase + di;
    const f16* zp = Z16 + ((size_t)d * 2048 + bc0 + pl) * 128 + qh * 8;
#pragma unroll
    for (int kt = 0; kt < 4; kt++) zb[di][kt] = *(const half8*)(zp + kt * 32);
    sb[di] = *(const half8*)(Sc + ((size_t)d * 2048 + bc0 + pl) * 32 + qh * 8);
  }
#pragma unroll
  for (int mt = 0; mt < 8; mt++) {
    const int KTM = mt / 2 + 1;  // causal: tiles with ji0 <= jo_max
    f32x4 acc[4];
#pragma unroll
    for (int di = 0; di < 4; di++) {
      int d = dbase + di;
      acc[di] = f32x4{0.f, 0.f, 0.f, 0.f};
      const half8* tfp = TF + ((size_t)d * 8 + mt) * 256 + lane;
#pragma unroll
      for (int kt = 0; kt < KTM; kt++)
        acc[di] = __builtin_amdgcn_mfma_f32_16x16x32_f16(tfp[kt * 64], zb[di][kt], acc[di], 0, 0, 0);
      acc[di] = __builtin_amdgcn_mfma_f32_16x16x32_f16(VF[((size_t)d * 8 + mt) * 64 + lane], sb[di], acc[di], 0, 0, 0);
    }
#pragma unroll
    for (int r = 0; r < 4; r++) {
      int pos = (bc0 + pl) * 128 + mt * 16 + qh * 4 + r;
      half4 pk = half4{(f16)gelu_t(acc[0][r]), (f16)gelu_t(acc[1][r]),
                       (f16)gelu_t(acc[2][r]), (f16)gelu_t(acc[3][r])};
      *(half4*)(Y16 + (size_t)pos * 64 + dbase) = pk;
    }
  }
}

// ======== Fused GLU+FF(+next-layer z) ========
// WZ=1: apply next layer's s4-LN to the fresh residual and write Z16 (LDS transpose).
// WZ=0 (last layer): write STATS for the head instead.
// LDS: sWg half8[1024]@0, sW1 half8[1024]@16384, sW2 half8[1024]@32768,
//      floats[576]@49152, ztile f16[64][132]@51456. Total 68352 -> 2 blocks/CU.
template <int WZ>
__global__ __launch_bounds__(512) void k_gluff3(
    const f16* __restrict__ Y16, const float* __restrict__ Wg, const float* __restrict__ bg,
    const float* __restrict__ W1, const float* __restrict__ b1,
    const float* __restrict__ W2, const float* __restrict__ b2,
    const float* __restrict__ lnw, const float* __restrict__ lnb,
    const float* __restrict__ nlnw, const float* __restrict__ nlnb,
    float* __restrict__ X, f32x2* __restrict__ STATS, f16* __restrict__ Z16) {
  __shared__ __align__(16) char smem[68352];
  int tid = threadIdx.x;
#pragma unroll
  for (int it = 0; it < 2; it++) {           // sWg: 1024 half8 slots (et,ks2,lane) NATURAL k
    int s = it * 512 + tid;
    int l = s & 63, ks = (s >> 6) & 1, et = s >> 7;
    const float* wp = Wg + (et * 16 + (l & 15)) * 64 + ks * 32 + (l >> 4) * 8;
    f32x4 w0 = *(const f32x4*)wp, w1 = *(const f32x4*)(wp + 4);
    *(half8*)(smem + s * 16) = half8{(f16)w0[0], (f16)w0[1], (f16)w0[2], (f16)w0[3],
                                     (f16)w1[0], (f16)w1[1], (f16)w1[2], (f16)w1[3]};
  }
#pragma unroll
  for (int it = 0; it < 2; it++) {           // sW1: 1024 half8 slots (et,ks2,lane) PERMUTED k
    int s = it * 512 + tid;
    int l = s & 63, ks = (s >> 6) & 1, et = s >> 7;
    int pl = l & 15, qh = l >> 4;
    const float* wp = W1 + (et * 16 + pl) * 64 + ks * 32 + qh * 4;
    f32x4 w0 = *(const f32x4*)wp;
    f32x4 w1 = *(const f32x4*)(wp + 16);
    *(half8*)(smem + 16384 + s * 16) = half8{(f16)w0[0], (f16)w0[1], (f16)w0[2], (f16)w0[3],
                                             (f16)w1[0], (f16)w1[1], (f16)w1[2], (f16)w1[3]};
  }
#pragma unroll
  for (int it = 0; it < 2; it++) {           // sW2: 1024 half8 slots (dt,ks4,lane) PERMUTED k
    int s = it * 512 + tid;
    int l = s & 63, ks = (s >> 6) & 3, dt = s >> 8;
    int pl = l & 15, qh = l >> 4;
    const float* wp = W2 + (dt * 16 + pl) * 128 + ks * 32 + qh * 4;
    f32x4 w0 = *(const f32x4*)wp;
    f32x4 w1 = *(const f32x4*)(wp + 16);
    *(half8*)(smem + 32768 + s * 16) = half8{(f16)w0[0], (f16)w0[1], (f16)w0[2], (f16)w0[3],
                                             (f16)w1[0], (f16)w1[1], (f16)w1[2], (f16)w1[3]};
  }
  for (int idx = tid; idx < 576; idx += 512) {
    float v;
    if (idx < 128) v = bg[idx];
    else if (idx < 256) v = b1[idx - 128];
    else if (idx < 320) v = b2[idx - 256];
    else if (idx < 384) v = lnw[idx - 320];
    else if (idx < 448) v = lnb[idx - 384];
    else if (idx < 512) v = nlnw[idx - 448];
    else v = nlnb[idx - 512];
    ((float*)(smem + 49152))[idx] = v;
  }
  __syncthreads();
  int lane = tid & 63, pl = lane & 15, qh = lane >> 4;
  int widx = tid >> 6;
  f16* ztile = (f16*)(smem + 51456);

  for (int k = 0; k < 4; ++k) {
    int pt = blockIdx.x * 8 + widx + k * 4096;
    int pos = pt * 16 + pl;
    half8 yb0 = *(const half8*)(Y16 + (size_t)pos * 64 + qh * 8);
    half8 yb1 = *(const half8*)(Y16 + (size_t)pos * 64 + 32 + qh * 8);
    f32x4 xv[4];
#pragma unroll
    for (int q = 0; q < 4; q++) xv[q] = *(const f32x4*)(X + (size_t)pos * 64 + q * 16 + qh * 4);

    unsigned sb = 0;
    asm volatile("" : "+v"(sb));                // opaque: defeats LICM (anti-spill, R4-proven)
    const char* sm = smem + sb;
    const half8* sWg = (const half8*)sm;
    const half8* sW1 = (const half8*)(sm + 16384);
    const half8* sW2 = (const half8*)(sm + 32768);
    const float* sf = (const float*)(sm + 49152);
    // ---- GLU ----
    f32x4 accg[8];
#pragma unroll
    for (int et = 0; et < 8; et++) accg[et] = *(const f32x4*)(sf + et * 16 + qh * 4);
#pragma unroll
    for (int et = 0; et < 8; et++)
      accg[et] = __builtin_amdgcn_mfma_f32_16x16x32_f16(sWg[(et * 2) * 64 + lane], yb0, accg[et], 0, 0, 0);
#pragma unroll
    for (int et = 0; et < 8; et++)
      accg[et] = __builtin_amdgcn_mfma_f32_16x16x32_f16(sWg[(et * 2 + 1) * 64 + lane], yb1, accg[et], 0, 0, 0);
    float s = 0.f, s2 = 0.f;
#pragma unroll
    for (int q = 0; q < 4; q++)
#pragma unroll
      for (int r = 0; r < 4; r++) {
        xv[q][r] += accg[q][r] * sigm(accg[q + 4][r]);
        s += xv[q][r]; s2 += xv[q][r] * xv[q][r];
      }
    s += __shfl_xor(s, 16); s += __shfl_xor(s, 32);
    s2 += __shfl_xor(s2, 16); s2 += __shfl_xor(s2, 32);
    float m = s * (1.0f / 64.0f);
    float rstd = rsqrtf(s2 * (1.0f / 64.0f) - m * m + 1e-5f);
    // ---- FF GEMM1 (K=32 permuted frags) ----
    half4 zb4[4];
#pragma unroll
    for (int ks = 0; ks < 4; ks++) {
      f32x4 lw = *(const f32x4*)(sf + 320 + ks * 16 + qh * 4);
      f32x4 lb = *(const f32x4*)(sf + 384 + ks * 16 + qh * 4);
      half4 z;
#pragma unroll
      for (int r = 0; r < 4; r++) z[r] = (f16)fmaf((xv[ks][r] - m) * rstd, lw[r], lb[r]);
      zb4[ks] = z;
    }
    f32x4 acc1[8];
#pragma unroll
    for (int et = 0; et < 8; et++) acc1[et] = *(const f32x4*)(sf + 128 + et * 16 + qh * 4);
#pragma unroll
    for (int ks = 0; ks < 2; ks++) {
      half4 a = zb4[ks * 2], b = zb4[ks * 2 + 1];
      half8 zb8 = half8{a[0], a[1], a[2], a[3], b[0], b[1], b[2], b[3]};
#pragma unroll
      for (int et = 0; et < 8; et++)
        acc1[et] = __builtin_amdgcn_mfma_f32_16x16x32_f16(sW1[(et * 2 + ks) * 64 + lane], zb8, acc1[et], 0, 0, 0);
    }
    half4 h4[8];
#pragma unroll
    for (int et = 0; et < 8; et++)
      h4[et] = half4{(f16)gelu_t(acc1[et][0]), (f16)gelu_t(acc1[et][1]),
                     (f16)gelu_t(acc1[et][2]), (f16)gelu_t(acc1[et][3])};
    // ---- FF GEMM2 (K=128 as 4x32 permuted frags) ----
    f32x4 acc2[4];
#pragma unroll
    for (int dt = 0; dt < 4; dt++) acc2[dt] = *(const f32x4*)(sf + 256 + dt * 16 + qh * 4);
#pragma unroll
    for (int ks = 0; ks < 4; ks++) {
      half4 a = h4[ks * 2], b = h4[ks * 2 + 1];
      half8 hb8 = half8{a[0], a[1], a[2], a[3], b[0], b[1], b[2], b[3]};
#pragma unroll
      for (int dt = 0; dt < 4; dt++)
        acc2[dt] = __builtin_amdgcn_mfma_f32_16x16x32_f16(sW2[(dt * 4 + ks) * 64 + lane], hb8, acc2[dt], 0, 0, 0);
    }
    s = 0.f; s2 = 0.f;
#pragma unroll
    for (int dt = 0; dt < 4; dt++) {
#pragma unroll
      for (int r = 0; r < 4; r++) {
        xv[dt][r] += acc2[dt][r];
        s += xv[dt][r]; s2 += xv[dt][r] * xv[dt][r];
      }
      *(f32x4*)(X + (size_t)pos * 64 + dt * 16 + qh * 4) = xv[dt];
    }
    s += __shfl_xor(s, 16); s += __shfl_xor(s, 32);
    s2 += __shfl_xor(s2, 16); s2 += __shfl_xor(s2, 32);
    float m2 = s * (1.0f / 64.0f);
    float rstd2 = rsqrtf(s2 * (1.0f / 64.0f) - m2 * m2 + 1e-5f);

    if constexpr (WZ) {
      // next-layer s4-LN z, staged through LDS transpose, then coalesced Z16 write
      int prow = widx * 16 + pl;
#pragma unroll
      for (int q = 0; q < 4; q++) {
        int d0 = q * 16 + qh * 4;
        f32x4 lw = *(const f32x4*)(sf + 448 + d0);
        f32x4 lb = *(const f32x4*)(sf + 512 + d0);
#pragma unroll
        for (int r = 0; r < 4; r++)
          ztile[(d0 + r) * 132 + prow] = (f16)fmaf((xv[q][r] - m2) * rstd2, lw[r], lb[r]);
      }
      __syncthreads();
      {
        int d = tid >> 3, c0 = (tid & 7) * 16;
        half8 z0 = *(const half8*)(ztile + d * 132 + c0);
        half8 z1 = *(const half8*)(ztile + d * 132 + c0 + 8);
        size_t zoff = (size_t)d * 262144 + (size_t)(blockIdx.x * 8 + k * 4096) * 16;
        *(half8*)(Z16 + zoff + c0) = z0;
        *(half8*)(Z16 + zoff + c0 + 8) = z1;
      }
      __syncthreads();
    } else {
      if (qh == 0) STATS[pos] = f32x2{m2, rstd2};
    }
  }
}

// -------- head: z=LN(x,norm); r=relu(Wf z + bf); out = wz.r + bz --------
__global__ __launch_bounds__(256) void k_head(
    const float* __restrict__ X, const f32x2* __restrict__ STATS,
    const float* __restrict__ nw_, const float* __restrict__ nb_,
    const float* __restrict__ Wf, const float* __restrict__ bfb,
    const float* __restrict__ wz, const float* __restrict__ bz,
    float* __restrict__ outp) {
  int lane = threadIdx.x & 63;
  int wv = (blockIdx.x * 256 + threadIdx.x) >> 6;
  int nwv = gridDim.x * 4;
  int pl = lane & 15, qh = lane >> 4;
  half4 af[4][4];
#pragma unroll
  for (int et = 0; et < 4; et++)
#pragma unroll
    for (int ks = 0; ks < 4; ks++) {
      f32x4 w4 = *(const f32x4*)(Wf + (et * 16 + pl) * 64 + ks * 16 + qh * 4);
      af[et][ks] = half4{(f16)w4[0], (f16)w4[1], (f16)w4[2], (f16)w4[3]};
    }
  float bz0 = bz[0];
  for (int pt = wv; pt < PT; pt += nwv) {
    int pos = pt * 16 + pl;
    f32x2 ms = STATS[pos];
    half4 bf[4];
#pragma unroll
    for (int ks = 0; ks < 4; ks++) {
      f32x4 x4 = *(const f32x4*)(X + (size_t)pos * 64 + ks * 16 + qh * 4);
      f32x4 lw = *(const f32x4*)(nw_ + ks * 16 + qh * 4);
      f32x4 lb = *(const f32x4*)(nb_ + ks * 16 + qh * 4);
      f32x4 z;
#pragma unroll
      for (int j = 0; j < 4; j++) z[j] = fmaf((x4[j] - ms.x) * ms.y, lw[j], lb[j]);
      bf[ks] = half4{(f16)z[0], (f16)z[1], (f16)z[2], (f16)z[3]};
    }
    f32x4 acc[4];
#pragma unroll
    for (int et = 0; et < 4; et++) acc[et] = *(const f32x4*)(bfb + et * 16 + qh * 4);
#pragma unroll
    for (int ks = 0; ks < 4; ks++)
#pragma unroll
      for (int et = 0; et < 4; et++)
        acc[et] = __builtin_amdgcn_mfma_f32_16x16x16f16(af[et][ks], bf[ks], acc[et], 0, 0, 0);
    float o = 0.f;
#pragma unroll
    for (int et = 0; et < 4; et++) {
      f32x4 wzv = *(const f32x4*)(wz + et * 16 + qh * 4);
#pragma unroll
      for (int r = 0; r < 4; r++) {
        float rv = acc[et][r];
        rv = rv > 0.f ? rv : 0.f;
        o = fmaf(wzv[r], rv, o);
      }
    }
    o += __shfl_xor(o, 16); o += __shfl_xor(o, 32);
    if (qh == 0) outp[pos] = o + bz0;
  }
}

extern "C" void kernel_launch(void* const* d_in, const int* in_sizes, int n_in,
                              void* d_out, int out_size, void* d_ws, size_t ws_size,
                              hipStream_t stream) {
  (void)in_sizes; (void)n_in; (void)out_size; (void)ws_size;
  const float* inputs   = (const float*)d_in[0];
  const float* w_init   = (const float*)d_in[1];
  const float* b_init   = (const float*)d_in[2];
  const float* s4_ln_w  = (const float*)d_in[3];
  const float* s4_ln_b  = (const float*)d_in[4];
  const float* log_dt   = (const float*)d_in[5];
  const float* log_A    = (const float*)d_in[6];
  const float* A_imag   = (const float*)d_in[7];
  const float* C_re     = (const float*)d_in[8];
  const float* C_im     = (const float*)d_in[9];
  const float* D_skip   = (const float*)d_in[10];
  const float* s4_out_w = (const float*)d_in[11];
  const float* s4_out_b = (const float*)d_in[12];
  const float* ff_ln_w  = (const float*)d_in[13];
  const float* ff_ln_b  = (const float*)d_in[14];
  const float* ff_w1    = (const float*)d_in[15];
  const float* ff_b1    = (const float*)d_in[16];
  const float* ff_w2    = (const float*)d_in[17];
  const float* ff_b2    = (const float*)d_in[18];
  const float* norm_w   = (const float*)d_in[19];
  const float* norm_b   = (const float*)d_in[20];
  const float* w_final1 = (const float*)d_in[21];
  const float* b_final1 = (const float*)d_in[22];
  const float* w_zero   = (const float*)d_in[23];
  const float* b_zero   = (const float*)d_in[24];

  char* w8 = (char*)d_ws;
  size_t off = 0;
  float* X     = (float*)(w8 + off); off += (size_t)67108864;   // [pos][64] f32
  f16*   Z16   = (f16*)(w8 + off);   off += (size_t)33554432;   // [d][pos] f16
  f16*   Y16   = (f16*)(w8 + off);   off += (size_t)33554432;   // [pos][d] f16
  f16*   S16   = (f16*)(w8 + off);   off += (size_t)8388608;    // [d][bc][32] f16
  f16*   Sc    = (f16*)(w8 + off);   off += (size_t)8388608;    // [d][bc][32] f16
  f32x2* STATS = (f32x2*)(w8 + off); off += (size_t)2097152;
  f32x2* LAM   = (f32x2*)(w8 + off); off += 32768;
  f32x2* DC2   = (f32x2*)(w8 + off); off += 32768;
  f32x2* LCL   = (f32x2*)(w8 + off); off += 32768;
  half8* TF    = (half8*)(w8 + off); off += (size_t)8388608;    // 4 layers x 2MB
  half8* VF    = (half8*)(w8 + off); off += (size_t)2097152;
  half8* WF    = (half8*)(w8 + off); off += (size_t)2097152;

  k_setup<<<16, 256, 0, stream>>>(log_dt, log_A, A_imag, C_re, C_im, LAM, DC2, LCL);
  k_wtall<<<256, 128, 0, stream>>>(LAM, DC2, LCL, D_skip, TF, VF, WF);
  k_init3<<<512, 512, 0, stream>>>(inputs, w_init, b_init, s4_ln_w, s4_ln_b, X, Z16);
  for (int i = 0; i < NLq; i++) {
    k_p1g<<<2048, 256, 0, stream>>>(Z16, WF + (size_t)i * 32768, S16);
    k_pass2<<<64, 128, 0, stream>>>(S16, LCL + i * 1024, Sc);
    k_p3g2<<<512, 256, 0, stream>>>(Z16, Sc, TF + (size_t)i * 131072, VF + (size_t)i * 32768, Y16);
    if (i < NLq - 1) {
      k_gluff3<1><<<512, 512, 0, stream>>>(Y16, s4_out_w + i * 8192, s4_out_b + i * 128,
                                           ff_w1 + i * 8192, ff_b1 + i * 128,
                                           ff_w2 + i * 8192, ff_b2 + i * 64,
                                           ff_ln_w + i * 64, ff_ln_b + i * 64,
                                           s4_ln_w + (i + 1) * 64, s4_ln_b + (i + 1) * 64,
                                           X, STATS, Z16);
    } else {
      k_gluff3<0><<<512, 512, 0, stream>>>(Y16, s4_out_w + i * 8192, s4_out_b + i * 128,
                                           ff_w1 + i * 8192, ff_b1 + i * 128,
                                           ff_w2 + i * 8192, ff_b2 + i * 64,
                                           ff_ln_w + i * 64, ff_ln_b + i * 64,
                                           s4_ln_w, s4_ln_b,
                                           X, STATS, Z16);
    }
  }
  k_head<<<2048, 256, 0, stream>>>(X, STATS, norm_w, norm_b, w_final1, b_final1,
                                   w_zero, b_zero, (float*)d_out);
}

// Round 9
// 532.165 us; speedup vs baseline: 2.8868x; 1.0034x over previous
//
#include <hip/hip_runtime.h>
#include <cmath>

constexpr int Bq = 8, Lq = 32768, Dq = 64, Nq = 16, NLq = 4;
constexpr int CLq = 128, NCq = 256;           // NCq*CLq == Lq ; chunks per batch
constexpr int PT = Bq * Lq / 16;              // 16384 position-tiles of 16

typedef _Float16 f16;
typedef _Float16 half2t __attribute__((ext_vector_type(2)));
typedef _Float16 half4 __attribute__((ext_vector_type(4)));
typedef _Float16 half8 __attribute__((ext_vector_type(8)));
typedef float f32x4 __attribute__((ext_vector_type(4)));
typedef float f32x2 __attribute__((ext_vector_type(2)));

static __device__ __forceinline__ float sigm(float x) { return 1.0f / (1.0f + __expf(-x)); }
static __device__ __forceinline__ float gelu_t(float x) {
  return x * sigm(1.5957691216057308f * fmaf(0.044715f * x * x, x, x));
}

// -------- k_wtall: setup + all layers' frag-ordered f16 matrices TF/VF/WF, writes LCL --------
__global__ __launch_bounds__(128) void k_wtall(
    const float* __restrict__ log_dt, const float* __restrict__ log_A_real,
    const float* __restrict__ A_imag, const float* __restrict__ C_re,
    const float* __restrict__ C_im, const float* __restrict__ dskip,
    f32x2* __restrict__ LCL, half8* __restrict__ TF, half8* __restrict__ VF,
    half8* __restrict__ WF) {
  __shared__ f32x2 pw[129][16];
  __shared__ f32x2 lamS[16], dcS[16];
  __shared__ float Ks[128];
  int d = blockIdx.x & 63, L = blockIdx.x >> 6;
  half8* TFl = TF + (size_t)L * 131072;
  half8* VFl = VF + (size_t)L * 32768;
  half8* WFl = WF + (size_t)L * 32768;
  int t = threadIdx.x;
  if (t < 16) {
    int di = L * 64 + d;
    int idx = di * 16 + t;
    float dt = expf(log_dt[di]);
    float Ar = -expf(log_A_real[idx]);
    float Ai = A_imag[idx];
    float dr = Ar * dt, dmi = Ai * dt;
    float er = expf(dr);
    float lr = er * cosf(dmi), li = er * sinf(dmi);
    float inv = 1.0f / (Ar * Ar + Ai * Ai);
    float e1r = lr - 1.0f, e1i = li;
    float qr = (e1r * Ar + e1i * Ai) * inv;
    float qi = (e1i * Ar - e1r * Ai) * inv;
    float cr = C_re[idx], ci = C_im[idx];
    lamS[t] = f32x2{lr, li};
    dcS[t] = f32x2{2.0f * (cr * qr - ci * qi), 2.0f * (cr * qi + ci * qr)};
    float erc = expf(dr * 128.0f);
    f32x2 l128 = f32x2{erc * cosf(dmi * 128.0f), erc * sinf(dmi * 128.0f)};
    pw[128][t] = l128;
    LCL[(size_t)L * 1024 + d * 16 + t] = l128;
  }
  __syncthreads();
#pragma unroll
  for (int n = 0; n < 16; n++) {
    f32x2 lam = lamS[n];
    float pr = 1.f, pi = 0.f, br = lam.x, bi = lam.y;
    int e = t;
    while (e) {
      if (e & 1) { float tt = pr * br - pi * bi; pi = fmaf(pr, bi, pi * br); pr = tt; }
      float t2 = br * br - bi * bi; bi = 2.f * br * bi; br = t2; e >>= 1;
    }
    pw[t][n] = f32x2{pr, pi};
  }
  __syncthreads();
  {
    float k = 0.f;
#pragma unroll
    for (int n = 0; n < 16; n++) {
      f32x2 dc = dcS[n];
      f32x2 p = pw[t][n];
      k += dc.x * p.x - dc.y * p.y;
    }
    if (t == 0) k += dskip[L * 64 + d];
    Ks[t] = k;
  }
  __syncthreads();
  for (int s = t; s < 2048; s += 128) {
    int ln = s & 63, kt = (s >> 6) & 3, mt = s >> 8;
    int jo = mt * 16 + (ln & 15);
    int ji0 = kt * 32 + (ln >> 4) * 8;
    half8 v;
#pragma unroll
    for (int jj = 0; jj < 8; jj++) {
      int ji = ji0 + jj;
      v[jj] = (jo >= ji) ? (f16)Ks[jo - ji] : (f16)0.f;
    }
    TFl[(size_t)d * 2048 + s] = v;
  }
  for (int s = t; s < 512; s += 128) {
    int ln = s & 63, mt = s >> 6;
    int jo = mt * 16 + (ln & 15);
    int q0 = (ln >> 4) * 8;
    half8 v;
#pragma unroll
    for (int jj = 0; jj < 8; jj++) {
      int q = q0 + jj, n = q >> 1;
      f32x2 dc = dcS[n];
      f32x2 p = pw[jo + 1][n];
      float wr = dc.x * p.x - dc.y * p.y;
      float wi = dc.x * p.y + dc.y * p.x;
      v[jj] = (q & 1) ? (f16)(-wi) : (f16)wr;
    }
    VFl[(size_t)d * 512 + s] = v;
  }
  for (int s = t; s < 512; s += 128) {
    int ln = s & 63, kt = (s >> 6) & 3, nt = s >> 8;
    int p_ = nt * 16 + (ln & 15);
    int n = p_ >> 1;
    int j0 = kt * 32 + (ln >> 4) * 8;
    half8 v;
#pragma unroll
    for (int jj = 0; jj < 8; jj++) {
      f32x2 p = pw[127 - (j0 + jj)][n];
      v[jj] = (p_ & 1) ? (f16)p.y : (f16)p.x;
    }
    WFl[(size_t)d * 512 + s] = v;
  }
}

// -------- k_init3: x = relu(w_init*in + b_init); z = s4LN0(x) -> Z16 (LDS transpose) --------
__global__ __launch_bounds__(512) void k_init3(
    const float* __restrict__ inp, const float* __restrict__ w_init,
    const float* __restrict__ b_init, const float* __restrict__ lnw,
    const float* __restrict__ lnb, float* __restrict__ X, f16* __restrict__ Z16) {
  __shared__ __align__(16) f16 ztile[64 * 132];
  int tid = threadIdx.x;
  int widx = tid >> 6, lane = tid & 63;
  int pl = lane & 15, qh = lane >> 4;
  for (int k = 0; k < 4; ++k) {
    int pt = blockIdx.x * 8 + widx + k * 4096;
    int pos = pt * 16 + pl;
    float v = inp[pos];
    float s = 0.f, s2 = 0.f;
    f32x4 o[4];
#pragma unroll
    for (int q = 0; q < 4; q++) {
      int d0 = q * 16 + qh * 4;
      f32x4 w4 = *(const f32x4*)(w_init + d0);
      f32x4 b4 = *(const f32x4*)(b_init + d0);
#pragma unroll
      for (int j = 0; j < 4; j++) {
        float t = fmaf(w4[j], v, b4[j]);
        t = t > 0.f ? t : 0.f;
        o[q][j] = t; s += t; s2 += t * t;
      }
      *(f32x4*)(X + (size_t)pos * 64 + d0) = o[q];
    }
    s += __shfl_xor(s, 16); s += __shfl_xor(s, 32);
    s2 += __shfl_xor(s2, 16); s2 += __shfl_xor(s2, 32);
    float m = s * (1.0f / 64.0f);
    float rstd = rsqrtf(s2 * (1.0f / 64.0f) - m * m + 1e-5f);
    int prow = widx * 16 + pl;
#pragma unroll
    for (int q = 0; q < 4; q++) {
      int d0 = q * 16 + qh * 4;
      f32x4 lw = *(const f32x4*)(lnw + d0);
      f32x4 lb = *(const f32x4*)(lnb + d0);
#pragma unroll
      for (int r = 0; r < 4; r++)
        ztile[(d0 + r) * 132 + prow] = (f16)fmaf((o[q][r] - m) * rstd, lw[r], lb[r]);
    }
    __syncthreads();
    {
      int d = tid >> 3, c0 = (tid & 7) * 16;
      half8 z0 = *(const half8*)(ztile + d * 132 + c0);
      half8 z1 = *(const half8*)(ztile + d * 132 + c0 + 8);
      size_t zoff = (size_t)d * 262144 + (size_t)(blockIdx.x * 8 + k * 4096) * 16;
      *(half8*)(Z16 + zoff + c0) = z0;
      *(half8*)(Z16 + zoff + c0 + 8) = z1;
    }
    __syncthreads();
  }
}

// -------- k_p1g: chunk end-states S16[d][bc][p32] = Z(m=bc,k=j) @ Wend(k=j,n=p) --------
__global__ __launch_bounds__(256) void k_p1g(
    const f16* __restrict__ Z16, const half8* __restrict__ WF, f16* __restrict__ S16) {
  int tid = threadIdx.x;
  int lane = tid & 63;
  int task = blockIdx.x * 4 + (tid >> 6);
  int d = task >> 7, bct = task & 127;
  int bc0 = bct * 16;
  int pl = lane & 15, qh = lane >> 4;
  half8 az[4];
  const f16* zp = Z16 + ((size_t)d * 2048 + bc0 + pl) * 128 + qh * 8;
#pragma unroll
  for (int kt = 0; kt < 4; kt++) az[kt] = *(const half8*)(zp + kt * 32);
#pragma unroll
  for (int nt = 0; nt < 2; nt++) {
    f32x4 acc = f32x4{0.f, 0.f, 0.f, 0.f};
#pragma unroll
    for (int kt = 0; kt < 4; kt++)
      acc = __builtin_amdgcn_mfma_f32_16x16x32_f16(az[kt], WF[(size_t)d * 512 + (nt * 4 + kt) * 64 + lane], acc, 0, 0, 0);
#pragma unroll
    for (int r = 0; r < 4; r++)
      S16[((size_t)d * 2048 + bc0 + qh * 4 + r) * 32 + nt * 16 + pl] = (f16)acc[r];
  }
}

// -------- k_pass2: single-kernel exclusive scan over 256 chunks per (d,b,n) -> Sc --------
__global__ __launch_bounds__(128) void k_pass2(
    const f16* __restrict__ S16, const f32x2* __restrict__ LCLl, f16* __restrict__ Sc) {
  int d = blockIdx.x;                 // 64 blocks
  int t = threadIdx.x;                // 128 = (b 8, n 16)
  int n = t & 15, b = t >> 4;
  f32x2 lam = LCLl[d * 16 + n];
  float cr = 0.f, ci = 0.f;
  size_t base = ((size_t)d * 2048 + b * 256) * 32 + 2 * n;
  const f16* sp = S16 + base;
  f16* cp = Sc + base;
#pragma unroll 8
  for (int c = 0; c < 256; c++) {
    *(half2t*)(cp + (size_t)c * 32) = half2t{(f16)cr, (f16)ci};
    half2t v = *(const half2t*)(sp + (size_t)c * 32);
    float nr = fmaf(lam.x, cr, fmaf(-lam.y, ci, (float)v[0]));
    float ni = fmaf(lam.x, ci, fmaf(lam.y, cr, (float)v[1]));
    cr = nr; ci = ni;
  }
}

// -------- k_p3g2: y = T@z + V@carry, gelu -> Y16[pos][d] (d-packed half4) --------
__global__ __launch_bounds__(256) void k_p3g2(
    const f16* __restrict__ Z16, const f16* __restrict__ Sc,
    const half8* __restrict__ TF, const half8* __restrict__ VF,
    f16* __restrict__ Y16) {
  int tid = threadIdx.x;
  int lane = tid & 63, widx = tid >> 6;
  int bct = blockIdx.x & 127, dg = blockIdx.x >> 7;  // grid 512: 4 dg x 128 bct
  int bc0 = bct * 16;
  int dbase = dg * 16 + widx * 4;
  int pl = lane & 15, qh = lane >> 4;
  half8 zb[4][4];
  half8 sb[4];
#pragma unroll
  for (int di = 0; di < 4; di++) {
    int d = dbase + di;
    const f16* zp = Z16 + ((size_t)d * 2048 + bc0 + pl) * 128 + qh * 8;
#pragma unroll
    for (int kt = 0; kt < 4; kt++) zb[di][kt] = *(const half8*)(zp + kt * 32);
    sb[di] = *(const half8*)(Sc + ((size_t)d * 2048 + bc0 + pl) * 32 + qh * 8);
  }
#pragma unroll
  for (int mt = 0; mt < 8; mt++) {
    const int KTM = mt / 2 + 1;  // causal: tiles with ji0 <= jo_max
    f32x4 acc[4];
#pragma unroll
    for (int di = 0; di < 4; di++) {
      int d = dbase + di;
      acc[di] = f32x4{0.f, 0.f, 0.f, 0.f};
      const half8* tfp = TF + ((size_t)d * 8 + mt) * 256 + lane;
#pragma unroll
      for (int kt = 0; kt < KTM; kt++)
        acc[di] = __builtin_amdgcn_mfma_f32_16x16x32_f16(tfp[kt * 64], zb[di][kt], acc[di], 0, 0, 0);
      acc[di] = __builtin_amdgcn_mfma_f32_16x16x32_f16(VF[((size_t)d * 8 + mt) * 64 + lane], sb[di], acc[di], 0, 0, 0);
    }
#pragma unroll
    for (int r = 0; r < 4; r++) {
      int pos = (bc0 + pl) * 128 + mt * 16 + qh * 4 + r;
      half4 pk = half4{(f16)gelu_t(acc[0][r]), (f16)gelu_t(acc[1][r]),
                       (f16)gelu_t(acc[2][r]), (f16)gelu_t(acc[3][r])};
      *(half4*)(Y16 + (size_t)pos * 64 + dbase) = pk;
    }
  }
}

// ======== Fused GLU+FF(+next-layer z | +head) ========
// WZ=1: apply next layer's s4-LN to the fresh residual and write Z16 (LDS transpose).
// WZ=0 (last layer): head fused — norm-LN, Wf GEMM, relu, wz-dot -> out. No X write.
// LDS: sWg half8[1024]@0, sW1 half8[1024]@16384, sW2 half8[1024]@32768,
//      floats[576]@49152, ztile f16[64][132]@51456 (WZ=1) | sWf half8[512]@51456 +
//      headF float[129]@59648 (WZ=0). Total 68352 -> 2 blocks/CU.
template <int WZ>
__global__ __launch_bounds__(512) void k_gluff3(
    const f16* __restrict__ Y16, const float* __restrict__ Wg, const float* __restrict__ bg,
    const float* __restrict__ W1, const float* __restrict__ b1,
    const float* __restrict__ W2, const float* __restrict__ b2,
    const float* __restrict__ lnw, const float* __restrict__ lnb,
    const float* __restrict__ nlnw, const float* __restrict__ nlnb,
    float* __restrict__ X, f16* __restrict__ Z16,
    const float* __restrict__ Wf, const float* __restrict__ bfb,
    const float* __restrict__ wz, const float* __restrict__ bz,
    float* __restrict__ outp) {
  __shared__ __align__(16) char smem[68352];
  int tid = threadIdx.x;
#pragma unroll
  for (int it = 0; it < 2; it++) {           // sWg: NATURAL k
    int s = it * 512 + tid;
    int l = s & 63, ks = (s >> 6) & 1, et = s >> 7;
    const float* wp = Wg + (et * 16 + (l & 15)) * 64 + ks * 32 + (l >> 4) * 8;
    f32x4 w0 = *(const f32x4*)wp, w1 = *(const f32x4*)(wp + 4);
    *(half8*)(smem + s * 16) = half8{(f16)w0[0], (f16)w0[1], (f16)w0[2], (f16)w0[3],
                                     (f16)w1[0], (f16)w1[1], (f16)w1[2], (f16)w1[3]};
  }
#pragma unroll
  for (int it = 0; it < 2; it++) {           // sW1: PERMUTED k
    int s = it * 512 + tid;
    int l = s & 63, ks = (s >> 6) & 1, et = s >> 7;
    int pls = l & 15, qhs = l >> 4;
    const float* wp = W1 + (et * 16 + pls) * 64 + ks * 32 + qhs * 4;
    f32x4 w0 = *(const f32x4*)wp;
    f32x4 w1 = *(const f32x4*)(wp + 16);
    *(half8*)(smem + 16384 + s * 16) = half8{(f16)w0[0], (f16)w0[1], (f16)w0[2], (f16)w0[3],
                                             (f16)w1[0], (f16)w1[1], (f16)w1[2], (f16)w1[3]};
  }
#pragma unroll
  for (int it = 0; it < 2; it++) {           // sW2: PERMUTED k
    int s = it * 512 + tid;
    int l = s & 63, ks = (s >> 6) & 3, dt = s >> 8;
    int pls = l & 15, qhs = l >> 4;
    const float* wp = W2 + (dt * 16 + pls) * 128 + ks * 32 + qhs * 4;
    f32x4 w0 = *(const f32x4*)wp;
    f32x4 w1 = *(const f32x4*)(wp + 16);
    *(half8*)(smem + 32768 + s * 16) = half8{(f16)w0[0], (f16)w0[1], (f16)w0[2], (f16)w0[3],
                                             (f16)w1[0], (f16)w1[1], (f16)w1[2], (f16)w1[3]};
  }
  for (int idx = tid; idx < 576; idx += 512) {
    float v;
    if (idx < 128) v = bg[idx];
    else if (idx < 256) v = b1[idx - 128];
    else if (idx < 320) v = b2[idx - 256];
    else if (idx < 384) v = lnw[idx - 320];
    else if (idx < 448) v = lnb[idx - 384];
    else if (idx < 512) v = nlnw[idx - 448];
    else v = nlnb[idx - 512];
    ((float*)(smem + 49152))[idx] = v;
  }
  if constexpr (!WZ) {
    if (tid < 512) {                         // sWf: PERMUTED k (head GEMM)
      int s = tid;
      int l = s & 63, ks = (s >> 6) & 1, et = s >> 7;  // et < 4
      int pls = l & 15, qhs = l >> 4;
      const float* wp = Wf + (et * 16 + pls) * 64 + ks * 32 + qhs * 4;
      f32x4 w0 = *(const f32x4*)wp;
      f32x4 w1 = *(const f32x4*)(wp + 16);
      *(half8*)(smem + 51456 + s * 16) = half8{(f16)w0[0], (f16)w0[1], (f16)w0[2], (f16)w0[3],
                                               (f16)w1[0], (f16)w1[1], (f16)w1[2], (f16)w1[3]};
    }
    if (tid < 129) {
      float v = tid < 64 ? bfb[tid] : (tid < 128 ? wz[tid - 64] : bz[0]);
      ((float*)(smem + 59648))[tid] = v;
    }
  }
  __syncthreads();
  int lane = tid & 63, pl = lane & 15, qh = lane >> 4;
  int widx = tid >> 6;
  f16* ztile = (f16*)(smem + 51456);

  int pos = (blockIdx.x * 8 + widx) * 16 + pl;
  half8 yb0 = *(const half8*)(Y16 + (size_t)pos * 64 + qh * 8);
  half8 yb1 = *(const half8*)(Y16 + (size_t)pos * 64 + 32 + qh * 8);
  f32x4 xv[4];
#pragma unroll
  for (int q = 0; q < 4; q++) xv[q] = *(const f32x4*)(X + (size_t)pos * 64 + q * 16 + qh * 4);

  for (int k = 0; k < 4; ++k) {
    // ---- prefetch next tile (hides HBM latency under this tile's compute) ----
    half8 nyb0{}, nyb1{};
    f32x4 nxv[4] = {};
    int npos = pos + 65536;
    if (k < 3) {
      nyb0 = *(const half8*)(Y16 + (size_t)npos * 64 + qh * 8);
      nyb1 = *(const half8*)(Y16 + (size_t)npos * 64 + 32 + qh * 8);
#pragma unroll
      for (int q = 0; q < 4; q++) nxv[q] = *(const f32x4*)(X + (size_t)npos * 64 + q * 16 + qh * 4);
    }

    unsigned sb = 0;
    asm volatile("" : "+v"(sb));                // opaque: defeats LICM (anti-spill, R4-proven)
    const char* sm = smem + sb;
    const half8* sWg = (const half8*)sm;
    const half8* sW1 = (const half8*)(sm + 16384);
    const half8* sW2 = (const half8*)(sm + 32768);
    const float* sf = (const float*)(sm + 49152);
    // ---- GLU ----
    f32x4 accg[8];
#pragma unroll
    for (int et = 0; et < 8; et++) accg[et] = *(const f32x4*)(sf + et * 16 + qh * 4);
#pragma unroll
    for (int et = 0; et < 8; et++)
      accg[et] = __builtin_amdgcn_mfma_f32_16x16x32_f16(sWg[(et * 2) * 64 + lane], yb0, accg[et], 0, 0, 0);
#pragma unroll
    for (int et = 0; et < 8; et++)
      accg[et] = __builtin_amdgcn_mfma_f32_16x16x32_f16(sWg[(et * 2 + 1) * 64 + lane], yb1, accg[et], 0, 0, 0);
    float s = 0.f, s2 = 0.f;
#pragma unroll
    for (int q = 0; q < 4; q++)
#pragma unroll
      for (int r = 0; r < 4; r++) {
        xv[q][r] += accg[q][r] * sigm(accg[q + 4][r]);
        s += xv[q][r]; s2 += xv[q][r] * xv[q][r];
      }
    s += __shfl_xor(s, 16); s += __shfl_xor(s, 32);
    s2 += __shfl_xor(s2, 16); s2 += __shfl_xor(s2, 32);
    float m = s * (1.0f / 64.0f);
    float rstd = rsqrtf(s2 * (1.0f / 64.0f) - m * m + 1e-5f);
    // ---- FF GEMM1 (K=32 permuted frags) ----
    half4 zb4[4];
#pragma unroll
    for (int ks = 0; ks < 4; ks++) {
      f32x4 lw = *(const f32x4*)(sf + 320 + ks * 16 + qh * 4);
      f32x4 lb = *(const f32x4*)(sf + 384 + ks * 16 + qh * 4);
      half4 z;
#pragma unroll
      for (int r = 0; r < 4; r++) z[r] = (f16)fmaf((xv[ks][r] - m) * rstd, lw[r], lb[r]);
      zb4[ks] = z;
    }
    f32x4 acc1[8];
#pragma unroll
    for (int et = 0; et < 8; et++) acc1[et] = *(const f32x4*)(sf + 128 + et * 16 + qh * 4);
#pragma unroll
    for (int ks = 0; ks < 2; ks++) {
      half4 a = zb4[ks * 2], b = zb4[ks * 2 + 1];
      half8 zb8 = half8{a[0], a[1], a[2], a[3], b[0], b[1], b[2], b[3]};
#pragma unroll
      for (int et = 0; et < 8; et++)
        acc1[et] = __builtin_amdgcn_mfma_f32_16x16x32_f16(sW1[(et * 2 + ks) * 64 + lane], zb8, acc1[et], 0, 0, 0);
    }
    half4 h4[8];
#pragma unroll
    for (int et = 0; et < 8; et++)
      h4[et] = half4{(f16)gelu_t(acc1[et][0]), (f16)gelu_t(acc1[et][1]),
                     (f16)gelu_t(acc1[et][2]), (f16)gelu_t(acc1[et][3])};
    // ---- FF GEMM2 (K=128 as 4x32 permuted frags) ----
    f32x4 acc2[4];
#pragma unroll
    for (int dt = 0; dt < 4; dt++) acc2[dt] = *(const f32x4*)(sf + 256 + dt * 16 + qh * 4);
#pragma unroll
    for (int ks = 0; ks < 4; ks++) {
      half4 a = h4[ks * 2], b = h4[ks * 2 + 1];
      half8 hb8 = half8{a[0], a[1], a[2], a[3], b[0], b[1], b[2], b[3]};
#pragma unroll
      for (int dt = 0; dt < 4; dt++)
        acc2[dt] = __builtin_amdgcn_mfma_f32_16x16x32_f16(sW2[(dt * 4 + ks) * 64 + lane], hb8, acc2[dt], 0, 0, 0);
    }
    s = 0.f; s2 = 0.f;
#pragma unroll
    for (int dt = 0; dt < 4; dt++) {
#pragma unroll
      for (int r = 0; r < 4; r++) {
        xv[dt][r] += acc2[dt][r];
        s += xv[dt][r]; s2 += xv[dt][r] * xv[dt][r];
      }
      if constexpr (WZ) *(f32x4*)(X + (size_t)pos * 64 + dt * 16 + qh * 4) = xv[dt];
    }
    s += __shfl_xor(s, 16); s += __shfl_xor(s, 32);
    s2 += __shfl_xor(s2, 16); s2 += __shfl_xor(s2, 32);
    float m2 = s * (1.0f / 64.0f);
    float rstd2 = rsqrtf(s2 * (1.0f / 64.0f) - m2 * m2 + 1e-5f);

    if constexpr (WZ) {
      // next-layer s4-LN z, staged through LDS transpose, then coalesced Z16 write
      int prow = widx * 16 + pl;
#pragma unroll
      for (int q = 0; q < 4; q++) {
        int d0 = q * 16 + qh * 4;
        f32x4 lw = *(const f32x4*)(sf + 448 + d0);
        f32x4 lb = *(const f32x4*)(sf + 512 + d0);
#pragma unroll
        for (int r = 0; r < 4; r++)
          ztile[(d0 + r) * 132 + prow] = (f16)fmaf((xv[q][r] - m2) * rstd2, lw[r], lb[r]);
      }
      __syncthreads();
      {
        int d = tid >> 3, c0 = (tid & 7) * 16;
        half8 z0 = *(const half8*)(ztile + d * 132 + c0);
        half8 z1 = *(const half8*)(ztile + d * 132 + c0 + 8);
        size_t zoff = (size_t)d * 262144 + (size_t)(blockIdx.x * 8 + k * 4096) * 16;
        *(half8*)(Z16 + zoff + c0) = z0;
        *(half8*)(Z16 + zoff + c0 + 8) = z1;
      }
      __syncthreads();
    } else {
      // ---- fused head: z = normLN(x); u = Wf z + bfb; o = wz . relu(u) + bz ----
      const half8* sWf = (const half8*)(sm + 51456);
      const float* hf = (const float*)(sm + 59648);
      half4 hz[4];
#pragma unroll
      for (int ks = 0; ks < 4; ks++) {
        f32x4 lw = *(const f32x4*)(sf + 448 + ks * 16 + qh * 4);
        f32x4 lb = *(const f32x4*)(sf + 512 + ks * 16 + qh * 4);
        half4 z;
#pragma unroll
        for (int r = 0; r < 4; r++) z[r] = (f16)fmaf((xv[ks][r] - m2) * rstd2, lw[r], lb[r]);
        hz[ks] = z;
      }
      f32x4 acch[4];
#pragma unroll
      for (int et = 0; et < 4; et++) acch[et] = *(const f32x4*)(hf + et * 16 + qh * 4);
#pragma unroll
      for (int ks = 0; ks < 2; ks++) {
        half4 a = hz[ks * 2], b = hz[ks * 2 + 1];
        half8 zb8 = half8{a[0], a[1], a[2], a[3], b[0], b[1], b[2], b[3]};
#pragma unroll
        for (int et = 0; et < 4; et++)
          acch[et] = __builtin_amdgcn_mfma_f32_16x16x32_f16(sWf[(et * 2 + ks) * 64 + lane], zb8, acch[et], 0, 0, 0);
      }
      float o = 0.f;
#pragma unroll
      for (int et = 0; et < 4; et++) {
        f32x4 wzv = *(const f32x4*)(hf + 64 + et * 16 + qh * 4);
#pragma unroll
        for (int r = 0; r < 4; r++) {
          float rv = acch[et][r];
          rv = rv > 0.f ? rv : 0.f;
          o = fmaf(wzv[r], rv, o);
        }
      }
      o += __shfl_xor(o, 16); o += __shfl_xor(o, 32);
      if (qh == 0) outp[pos] = o + hf[128];
    }

    if (k < 3) {
      yb0 = nyb0; yb1 = nyb1;
#pragma unroll
      for (int q = 0; q < 4; q++) xv[q] = nxv[q];
      pos = npos;
    }
  }
}

extern "C" void kernel_launch(void* const* d_in, const int* in_sizes, int n_in,
                              void* d_out, int out_size, void* d_ws, size_t ws_size,
                              hipStream_t stream) {
  (void)in_sizes; (void)n_in; (void)out_size; (void)ws_size;
  const float* inputs   = (const float*)d_in[0];
  const float* w_init   = (const float*)d_in[1];
  const float* b_init   = (const float*)d_in[2];
  const float* s4_ln_w  = (const float*)d_in[3];
  const float* s4_ln_b  = (const float*)d_in[4];
  const float* log_dt   = (const float*)d_in[5];
  const float* log_A    = (const float*)d_in[6];
  const float* A_imag   = (const float*)d_in[7];
  const float* C_re     = (const float*)d_in[8];
  const float* C_im     = (const float*)d_in[9];
  const float* D_skip   = (const float*)d_in[10];
  const float* s4_out_w = (const float*)d_in[11];
  const float* s4_out_b = (const float*)d_in[12];
  const float* ff_ln_w  = (const float*)d_in[13];
  const float* ff_ln_b  = (const float*)d_in[14];
  const float* ff_w1    = (const float*)d_in[15];
  const float* ff_b1    = (const float*)d_in[16];
  const float* ff_w2    = (const float*)d_in[17];
  const float* ff_b2    = (const float*)d_in[18];
  const float* norm_w   = (const float*)d_in[19];
  const float* norm_b   = (const float*)d_in[20];
  const float* w_final1 = (const float*)d_in[21];
  const float* b_final1 = (const float*)d_in[22];
  const float* w_zero   = (const float*)d_in[23];
  const float* b_zero   = (const float*)d_in[24];

  char* w8 = (char*)d_ws;
  size_t off = 0;
  float* X     = (float*)(w8 + off); off += (size_t)67108864;   // [pos][64] f32
  f16*   Z16   = (f16*)(w8 + off);   off += (size_t)33554432;   // [d][pos] f16
  f16*   Y16   = (f16*)(w8 + off);   off += (size_t)33554432;   // [pos][d] f16
  f16*   S16   = (f16*)(w8 + off);   off += (size_t)8388608;    // [d][bc][32] f16
  f16*   Sc    = (f16*)(w8 + off);   off += (size_t)8388608;    // [d][bc][32] f16
  f32x2* LCL   = (f32x2*)(w8 + off); off += 32768;
  half8* TF    = (half8*)(w8 + off); off += (size_t)8388608;    // 4 layers x 2MB
  half8* VF    = (half8*)(w8 + off); off += (size_t)2097152;
  half8* WF    = (half8*)(w8 + off); off += (size_t)2097152;

  k_wtall<<<256, 128, 0, stream>>>(log_dt, log_A, A_imag, C_re, C_im, D_skip,
                                   LCL, TF, VF, WF);
  k_init3<<<512, 512, 0, stream>>>(inputs, w_init, b_init, s4_ln_w, s4_ln_b, X, Z16);
  for (int i = 0; i < NLq; i++) {
    k_p1g<<<2048, 256, 0, stream>>>(Z16, WF + (size_t)i * 32768, S16);
    k_pass2<<<64, 128, 0, stream>>>(S16, LCL + i * 1024, Sc);
    k_p3g2<<<512, 256, 0, stream>>>(Z16, Sc, TF + (size_t)i * 131072, VF + (size_t)i * 32768, Y16);
    if (i < NLq - 1) {
      k_gluff3<1><<<512, 512, 0, stream>>>(Y16, s4_out_w + i * 8192, s4_out_b + i * 128,
                                           ff_w1 + i * 8192, ff_b1 + i * 128,
                                           ff_w2 + i * 8192, ff_b2 + i * 64,
                                           ff_ln_w + i * 64, ff_ln_b + i * 64,
                                           s4_ln_w + (i + 1) * 64, s4_ln_b + (i + 1) * 64,
                                           X, Z16, nullptr, nullptr, nullptr, nullptr, nullptr);
    } else {
      k_gluff3<0><<<512, 512, 0, stream>>>(Y16, s4_out_w + i * 8192, s4_out_b + i * 128,
                                           ff_w1 + i * 8192, ff_b1 + i * 128,
                                           ff_w2 + i * 8192, ff_b2 + i * 64,
                                           ff_ln_w + i * 64, ff_ln_b + i * 64,
                                           norm_w, norm_b,
                                           X, Z16, w_final1, b_final1, w_zero, b_zero,
                                           (float*)d_out);
    }
  }
}

// Round 10
// 469.726 us; speedup vs baseline: 3.2705x; 1.1329x over previous
//
#include <hip/hip_runtime.h>
#include <cmath>

constexpr int Bq = 8, Lq = 32768, Dq = 64, Nq = 16, NLq = 4;
constexpr int CLq = 128, NCq = 256;           // NCq*CLq == Lq ; chunks per batch
constexpr int PT = Bq * Lq / 16;              // 16384 position-tiles of 16

typedef _Float16 f16;
typedef _Float16 half2t __attribute__((ext_vector_type(2)));
typedef _Float16 half4 __attribute__((ext_vector_type(4)));
typedef _Float16 half8 __attribute__((ext_vector_type(8)));
typedef float f32x4 __attribute__((ext_vector_type(4)));
typedef float f32x2 __attribute__((ext_vector_type(2)));

static __device__ __forceinline__ float sigm(float x) { return 1.0f / (1.0f + __expf(-x)); }
static __device__ __forceinline__ float gelu_t(float x) {
  return x * sigm(1.5957691216057308f * fmaf(0.044715f * x * x, x, x));
}

// -------- k_wtall: setup + all layers' frag-ordered f16 matrices TF/VF/WF; LCL, LC2K --------
__global__ __launch_bounds__(128) void k_wtall(
    const float* __restrict__ log_dt, const float* __restrict__ log_A_real,
    const float* __restrict__ A_imag, const float* __restrict__ C_re,
    const float* __restrict__ C_im, const float* __restrict__ dskip,
    f32x2* __restrict__ LCL, f32x2* __restrict__ LC2K, half8* __restrict__ TF,
    half8* __restrict__ VF, half8* __restrict__ WF) {
  __shared__ f32x2 pw[129][16];
  __shared__ f32x2 lamS[16], dcS[16];
  __shared__ float Ks[128];
  int d = blockIdx.x & 63, L = blockIdx.x >> 6;
  half8* TFl = TF + (size_t)L * 131072;
  half8* VFl = VF + (size_t)L * 32768;
  half8* WFl = WF + (size_t)L * 32768;
  int t = threadIdx.x;
  if (t < 16) {
    int di = L * 64 + d;
    int idx = di * 16 + t;
    float dt = expf(log_dt[di]);
    float Ar = -expf(log_A_real[idx]);
    float Ai = A_imag[idx];
    float dr = Ar * dt, dmi = Ai * dt;
    float er = expf(dr);
    float lr = er * cosf(dmi), li = er * sinf(dmi);
    float inv = 1.0f / (Ar * Ar + Ai * Ai);
    float e1r = lr - 1.0f, e1i = li;
    float qr = (e1r * Ar + e1i * Ai) * inv;
    float qi = (e1i * Ar - e1r * Ai) * inv;
    float cr = C_re[idx], ci = C_im[idx];
    lamS[t] = f32x2{lr, li};
    dcS[t] = f32x2{2.0f * (cr * qr - ci * qi), 2.0f * (cr * qi + ci * qr)};
    float erc = expf(dr * 128.0f);
    f32x2 l128 = f32x2{erc * cosf(dmi * 128.0f), erc * sinf(dmi * 128.0f)};
    pw[128][t] = l128;
    LCL[(size_t)L * 1024 + d * 16 + t] = l128;
    // lambda^2048 = (lambda^128)^16 via 4 squarings
    float br = l128.x, bi = l128.y;
#pragma unroll
    for (int q = 0; q < 4; q++) {
      float t2 = br * br - bi * bi;
      bi = 2.f * br * bi; br = t2;
    }
    LC2K[(size_t)L * 1024 + d * 16 + t] = f32x2{br, bi};
  }
  __syncthreads();
#pragma unroll
  for (int n = 0; n < 16; n++) {
    f32x2 lam = lamS[n];
    float pr = 1.f, pi = 0.f, br = lam.x, bi = lam.y;
    int e = t;
    while (e) {
      if (e & 1) { float tt = pr * br - pi * bi; pi = fmaf(pr, bi, pi * br); pr = tt; }
      float t2 = br * br - bi * bi; bi = 2.f * br * bi; br = t2; e >>= 1;
    }
    pw[t][n] = f32x2{pr, pi};
  }
  __syncthreads();
  {
    float k = 0.f;
#pragma unroll
    for (int n = 0; n < 16; n++) {
      f32x2 dc = dcS[n];
      f32x2 p = pw[t][n];
      k += dc.x * p.x - dc.y * p.y;
    }
    if (t == 0) k += dskip[L * 64 + d];
    Ks[t] = k;
  }
  __syncthreads();
  for (int s = t; s < 2048; s += 128) {
    int ln = s & 63, kt = (s >> 6) & 3, mt = s >> 8;
    int jo = mt * 16 + (ln & 15);
    int ji0 = kt * 32 + (ln >> 4) * 8;
    half8 v;
#pragma unroll
    for (int jj = 0; jj < 8; jj++) {
      int ji = ji0 + jj;
      v[jj] = (jo >= ji) ? (f16)Ks[jo - ji] : (f16)0.f;
    }
    TFl[(size_t)d * 2048 + s] = v;
  }
  for (int s = t; s < 512; s += 128) {
    int ln = s & 63, mt = s >> 6;
    int jo = mt * 16 + (ln & 15);
    int q0 = (ln >> 4) * 8;
    half8 v;
#pragma unroll
    for (int jj = 0; jj < 8; jj++) {
      int q = q0 + jj, n = q >> 1;
      f32x2 dc = dcS[n];
      f32x2 p = pw[jo + 1][n];
      float wr = dc.x * p.x - dc.y * p.y;
      float wi = dc.x * p.y + dc.y * p.x;
      v[jj] = (q & 1) ? (f16)(-wi) : (f16)wr;
    }
    VFl[(size_t)d * 512 + s] = v;
  }
  for (int s = t; s < 512; s += 128) {
    int ln = s & 63, kt = (s >> 6) & 3, nt = s >> 8;
    int p_ = nt * 16 + (ln & 15);
    int n = p_ >> 1;
    int j0 = kt * 32 + (ln >> 4) * 8;
    half8 v;
#pragma unroll
    for (int jj = 0; jj < 8; jj++) {
      f32x2 p = pw[127 - (j0 + jj)][n];
      v[jj] = (p_ & 1) ? (f16)p.y : (f16)p.x;
    }
    WFl[(size_t)d * 512 + s] = v;
  }
}

// -------- k_init3: x = relu(w_init*in + b_init); z = s4LN0(x) -> Z16 (LDS transpose) --------
__global__ __launch_bounds__(512) void k_init3(
    const float* __restrict__ inp, const float* __restrict__ w_init,
    const float* __restrict__ b_init, const float* __restrict__ lnw,
    const float* __restrict__ lnb, float* __restrict__ X, f16* __restrict__ Z16) {
  __shared__ __align__(16) f16 ztile[64 * 132];
  int tid = threadIdx.x;
  int widx = tid >> 6, lane = tid & 63;
  int pl = lane & 15, qh = lane >> 4;
  for (int k = 0; k < 4; ++k) {
    int pt = blockIdx.x * 8 + widx + k * 4096;
    int pos = pt * 16 + pl;
    float v = inp[pos];
    float s = 0.f, s2 = 0.f;
    f32x4 o[4];
#pragma unroll
    for (int q = 0; q < 4; q++) {
      int d0 = q * 16 + qh * 4;
      f32x4 w4 = *(const f32x4*)(w_init + d0);
      f32x4 b4 = *(const f32x4*)(b_init + d0);
#pragma unroll
      for (int j = 0; j < 4; j++) {
        float t = fmaf(w4[j], v, b4[j]);
        t = t > 0.f ? t : 0.f;
        o[q][j] = t; s += t; s2 += t * t;
      }
      *(f32x4*)(X + (size_t)pos * 64 + d0) = o[q];
    }
    s += __shfl_xor(s, 16); s += __shfl_xor(s, 32);
    s2 += __shfl_xor(s2, 16); s2 += __shfl_xor(s2, 32);
    float m = s * (1.0f / 64.0f);
    float rstd = rsqrtf(s2 * (1.0f / 64.0f) - m * m + 1e-5f);
    int prow = widx * 16 + pl;
#pragma unroll
    for (int q = 0; q < 4; q++) {
      int d0 = q * 16 + qh * 4;
      f32x4 lw = *(const f32x4*)(lnw + d0);
      f32x4 lb = *(const f32x4*)(lnb + d0);
#pragma unroll
      for (int r = 0; r < 4; r++)
        ztile[(d0 + r) * 132 + prow] = (f16)fmaf((o[q][r] - m) * rstd, lw[r], lb[r]);
    }
    __syncthreads();
    {
      int d = tid >> 3, c0 = (tid & 7) * 16;
      half8 z0 = *(const half8*)(ztile + d * 132 + c0);
      half8 z1 = *(const half8*)(ztile + d * 132 + c0 + 8);
      size_t zoff = (size_t)d * 262144 + (size_t)(blockIdx.x * 8 + k * 4096) * 16;
      *(half8*)(Z16 + zoff + c0) = z0;
      *(half8*)(Z16 + zoff + c0 + 8) = z1;
    }
    __syncthreads();
  }
}

// -------- k_p1g: chunk end-states S16[d][bc][p32] = Z(m=bc,k=j) @ Wend(k=j,n=p) --------
__global__ __launch_bounds__(256) void k_p1g(
    const f16* __restrict__ Z16, const half8* __restrict__ WF, f16* __restrict__ S16) {
  int tid = threadIdx.x;
  int lane = tid & 63;
  int task = blockIdx.x * 4 + (tid >> 6);
  int d = task >> 7, bct = task & 127;
  int bc0 = bct * 16;
  int pl = lane & 15, qh = lane >> 4;
  half8 az[4];
  const f16* zp = Z16 + ((size_t)d * 2048 + bc0 + pl) * 128 + qh * 8;
#pragma unroll
  for (int kt = 0; kt < 4; kt++) az[kt] = *(const half8*)(zp + kt * 32);
#pragma unroll
  for (int nt = 0; nt < 2; nt++) {
    f32x4 acc = f32x4{0.f, 0.f, 0.f, 0.f};
#pragma unroll
    for (int kt = 0; kt < 4; kt++)
      acc = __builtin_amdgcn_mfma_f32_16x16x32_f16(az[kt], WF[(size_t)d * 512 + (nt * 4 + kt) * 64 + lane], acc, 0, 0, 0);
#pragma unroll
    for (int r = 0; r < 4; r++)
      S16[((size_t)d * 2048 + bc0 + qh * 4 + r) * 32 + nt * 16 + pl] = (f16)acc[r];
  }
}

// -------- k_pass2: 3-phase block-local scan. grid 512 = (d,b); 256 thr = (g16, n16) --------
__global__ __launch_bounds__(256) void k_pass2(
    const f16* __restrict__ S16, const f32x2* __restrict__ LCLl,
    const f32x2* __restrict__ LC2Kl, f16* __restrict__ Sc) {
  __shared__ f32x2 gc[16][17];
  int blk = blockIdx.x;               // d*8 + b
  int d = blk >> 3, b = blk & 7;
  int t = threadIdx.x;                // g*16 + n
  int n = t & 15, g = t >> 4;
  f32x2 lam = LCLl[d * 16 + n];
  size_t base = ((size_t)d * 2048 + b * 256 + g * 16) * 32 + 2 * n;
  const f16* sp = S16 + base;
  // phase A: local group carry over 16 chunks
  float cr = 0.f, ci = 0.f;
#pragma unroll 4
  for (int j = 0; j < 16; j++) {
    half2t v = *(const half2t*)(sp + (size_t)j * 32);
    float nr = fmaf(lam.x, cr, fmaf(-lam.y, ci, (float)v[0]));
    float ni = fmaf(lam.x, ci, fmaf(lam.y, cr, (float)v[1]));
    cr = nr; ci = ni;
  }
  gc[g][n] = f32x2{cr, ci};
  __syncthreads();
  // phase B: exclusive combine across groups with lambda^2048
  f32x2 l2 = LC2Kl[d * 16 + n];
  float er = 0.f, ei = 0.f;
  for (int gg = 0; gg < g; gg++) {
    f32x2 c = gc[gg][n];
    float nr = fmaf(l2.x, er, fmaf(-l2.y, ei, c.x));
    float ni = fmaf(l2.x, ei, fmaf(l2.y, er, c.y));
    er = nr; ei = ni;
  }
  // phase C: rescan writing exclusive carries
  f16* cp = Sc + base;
  float cr2 = er, ci2 = ei;
#pragma unroll 4
  for (int j = 0; j < 16; j++) {
    *(half2t*)(cp + (size_t)j * 32) = half2t{(f16)cr2, (f16)ci2};
    half2t v = *(const half2t*)(sp + (size_t)j * 32);
    float nr = fmaf(lam.x, cr2, fmaf(-lam.y, ci2, (float)v[0]));
    float ni = fmaf(lam.x, ci2, fmaf(lam.y, cr2, (float)v[1]));
    cr2 = nr; ci2 = ni;
  }
}

// -------- k_p3g2: y = T@z + V@carry, gelu -> Y16[pos][d] (d-packed half4) --------
__global__ __launch_bounds__(256) void k_p3g2(
    const f16* __restrict__ Z16, const f16* __restrict__ Sc,
    const half8* __restrict__ TF, const half8* __restrict__ VF,
    f16* __restrict__ Y16) {
  int tid = threadIdx.x;
  int lane = tid & 63, widx = tid >> 6;
  int bct = blockIdx.x & 127, dg = blockIdx.x >> 7;  // grid 512: 4 dg x 128 bct
  int bc0 = bct * 16;
  int dbase = dg * 16 + widx * 4;
  int pl = lane & 15, qh = lane >> 4;
  half8 zb[4][4];
  half8 sb[4];
#pragma unroll
  for (int di = 0; di < 4; di++) {
    int d = dbase + di;
    const f16* zp = Z16 + ((size_t)d * 2048 + bc0 + pl) * 128 + qh * 8;
#pragma unroll
    for (int kt = 0; kt < 4; kt++) zb[di][kt] = *(const half8*)(zp + kt * 32);
    sb[di] = *(const half8*)(Sc + ((size_t)d * 2048 + bc0 + pl) * 32 + qh * 8);
  }
#pragma unroll
  for (int mt = 0; mt < 8; mt++) {
    const int KTM = mt / 2 + 1;  // causal: tiles with ji0 <= jo_max
    f32x4 acc[4];
#pragma unroll
    for (int di = 0; di < 4; di++) {
      int d = dbase + di;
      acc[di] = f32x4{0.f, 0.f, 0.f, 0.f};
      const half8* tfp = TF + ((size_t)d * 8 + mt) * 256 + lane;
#pragma unroll
      for (int kt = 0; kt < KTM; kt++)
        acc[di] = __builtin_amdgcn_mfma_f32_16x16x32_f16(tfp[kt * 64], zb[di][kt], acc[di], 0, 0, 0);
      acc[di] = __builtin_amdgcn_mfma_f32_16x16x32_f16(VF[((size_t)d * 8 + mt) * 64 + lane], sb[di], acc[di], 0, 0, 0);
    }
#pragma unroll
    for (int r = 0; r < 4; r++) {
      int pos = (bc0 + pl) * 128 + mt * 16 + qh * 4 + r;
      half4 pk = half4{(f16)gelu_t(acc[0][r]), (f16)gelu_t(acc[1][r]),
                       (f16)gelu_t(acc[2][r]), (f16)gelu_t(acc[3][r])};
      *(half4*)(Y16 + (size_t)pos * 64 + dbase) = pk;
    }
  }
}

// ======== Fused GLU+FF(+next-layer z | +head), R8 loop structure (no manual prefetch) ========
template <int WZ>
__global__ __launch_bounds__(512) void k_gluff3(
    const f16* __restrict__ Y16, const float* __restrict__ Wg, const float* __restrict__ bg,
    const float* __restrict__ W1, const float* __restrict__ b1,
    const float* __restrict__ W2, const float* __restrict__ b2,
    const float* __restrict__ lnw, const float* __restrict__ lnb,
    const float* __restrict__ nlnw, const float* __restrict__ nlnb,
    float* __restrict__ X, f16* __restrict__ Z16,
    const float* __restrict__ Wf, const float* __restrict__ bfb,
    const float* __restrict__ wz, const float* __restrict__ bz,
    float* __restrict__ outp) {
  __shared__ __align__(16) char smem[68352];
  int tid = threadIdx.x;
#pragma unroll
  for (int it = 0; it < 2; it++) {           // sWg: NATURAL k
    int s = it * 512 + tid;
    int l = s & 63, ks = (s >> 6) & 1, et = s >> 7;
    const float* wp = Wg + (et * 16 + (l & 15)) * 64 + ks * 32 + (l >> 4) * 8;
    f32x4 w0 = *(const f32x4*)wp, w1 = *(const f32x4*)(wp + 4);
    *(half8*)(smem + s * 16) = half8{(f16)w0[0], (f16)w0[1], (f16)w0[2], (f16)w0[3],
                                     (f16)w1[0], (f16)w1[1], (f16)w1[2], (f16)w1[3]};
  }
#pragma unroll
  for (int it = 0; it < 2; it++) {           // sW1: PERMUTED k
    int s = it * 512 + tid;
    int l = s & 63, ks = (s >> 6) & 1, et = s >> 7;
    int pls = l & 15, qhs = l >> 4;
    const float* wp = W1 + (et * 16 + pls) * 64 + ks * 32 + qhs * 4;
    f32x4 w0 = *(const f32x4*)wp;
    f32x4 w1 = *(const f32x4*)(wp + 16);
    *(half8*)(smem + 16384 + s * 16) = half8{(f16)w0[0], (f16)w0[1], (f16)w0[2], (f16)w0[3],
                                             (f16)w1[0], (f16)w1[1], (f16)w1[2], (f16)w1[3]};
  }
#pragma unroll
  for (int it = 0; it < 2; it++) {           // sW2: PERMUTED k
    int s = it * 512 + tid;
    int l = s & 63, ks = (s >> 6) & 3, dt = s >> 8;
    int pls = l & 15, qhs = l >> 4;
    const float* wp = W2 + (dt * 16 + pls) * 128 + ks * 32 + qhs * 4;
    f32x4 w0 = *(const f32x4*)wp;
    f32x4 w1 = *(const f32x4*)(wp + 16);
    *(half8*)(smem + 32768 + s * 16) = half8{(f16)w0[0], (f16)w0[1], (f16)w0[2], (f16)w0[3],
                                             (f16)w1[0], (f16)w1[1], (f16)w1[2], (f16)w1[3]};
  }
  for (int idx = tid; idx < 576; idx += 512) {
    float v;
    if (idx < 128) v = bg[idx];
    else if (idx < 256) v = b1[idx - 128];
    else if (idx < 320) v = b2[idx - 256];
    else if (idx < 384) v = lnw[idx - 320];
    else if (idx < 448) v = lnb[idx - 384];
    else if (idx < 512) v = nlnw[idx - 448];
    else v = nlnb[idx - 512];
    ((float*)(smem + 49152))[idx] = v;
  }
  if constexpr (!WZ) {
    if (tid < 512) {                         // sWf: PERMUTED k (head GEMM)
      int s = tid;
      int l = s & 63, ks = (s >> 6) & 1, et = s >> 7;  // et < 4
      int pls = l & 15, qhs = l >> 4;
      const float* wp = Wf + (et * 16 + pls) * 64 + ks * 32 + qhs * 4;
      f32x4 w0 = *(const f32x4*)wp;
      f32x4 w1 = *(const f32x4*)(wp + 16);
      *(half8*)(smem + 51456 + s * 16) = half8{(f16)w0[0], (f16)w0[1], (f16)w0[2], (f16)w0[3],
                                               (f16)w1[0], (f16)w1[1], (f16)w1[2], (f16)w1[3]};
    }
    if (tid < 129) {
      float v = tid < 64 ? bfb[tid] : (tid < 128 ? wz[tid - 64] : bz[0]);
      ((float*)(smem + 59648))[tid] = v;
    }
  }
  __syncthreads();
  int lane = tid & 63, pl = lane & 15, qh = lane >> 4;
  int widx = tid >> 6;
  f16* ztile = (f16*)(smem + 51456);

  for (int k = 0; k < 4; ++k) {
    int pt = blockIdx.x * 8 + widx + k * 4096;
    int pos = pt * 16 + pl;
    half8 yb0 = *(const half8*)(Y16 + (size_t)pos * 64 + qh * 8);
    half8 yb1 = *(const half8*)(Y16 + (size_t)pos * 64 + 32 + qh * 8);
    f32x4 xv[4];
#pragma unroll
    for (int q = 0; q < 4; q++) xv[q] = *(const f32x4*)(X + (size_t)pos * 64 + q * 16 + qh * 4);

    unsigned sb = 0;
    asm volatile("" : "+v"(sb));                // opaque: defeats LICM (anti-spill, R4-proven)
    const char* sm = smem + sb;
    const half8* sWg = (const half8*)sm;
    const half8* sW1 = (const half8*)(sm + 16384);
    const half8* sW2 = (const half8*)(sm + 32768);
    const float* sf = (const float*)(sm + 49152);
    // ---- GLU ----
    f32x4 accg[8];
#pragma unroll
    for (int et = 0; et < 8; et++) accg[et] = *(const f32x4*)(sf + et * 16 + qh * 4);
#pragma unroll
    for (int et = 0; et < 8; et++)
      accg[et] = __builtin_amdgcn_mfma_f32_16x16x32_f16(sWg[(et * 2) * 64 + lane], yb0, accg[et], 0, 0, 0);
#pragma unroll
    for (int et = 0; et < 8; et++)
      accg[et] = __builtin_amdgcn_mfma_f32_16x16x32_f16(sWg[(et * 2 + 1) * 64 + lane], yb1, accg[et], 0, 0, 0);
    float s = 0.f, s2 = 0.f;
#pragma unroll
    for (int q = 0; q < 4; q++)
#pragma unroll
      for (int r = 0; r < 4; r++) {
        xv[q][r] += accg[q][r] * sigm(accg[q + 4][r]);
        s += xv[q][r]; s2 += xv[q][r] * xv[q][r];
      }
    s += __shfl_xor(s, 16); s += __shfl_xor(s, 32);
    s2 += __shfl_xor(s2, 16); s2 += __shfl_xor(s2, 32);
    float m = s * (1.0f / 64.0f);
    float rstd = rsqrtf(s2 * (1.0f / 64.0f) - m * m + 1e-5f);
    // ---- FF GEMM1 (K=32 permuted frags) ----
    half4 zb4[4];
#pragma unroll
    for (int ks = 0; ks < 4; ks++) {
      f32x4 lw = *(const f32x4*)(sf + 320 + ks * 16 + qh * 4);
      f32x4 lb = *(const f32x4*)(sf + 384 + ks * 16 + qh * 4);
      half4 z;
#pragma unroll
      for (int r = 0; r < 4; r++) z[r] = (f16)fmaf((xv[ks][r] - m) * rstd, lw[r], lb[r]);
      zb4[ks] = z;
    }
    f32x4 acc1[8];
#pragma unroll
    for (int et = 0; et < 8; et++) acc1[et] = *(const f32x4*)(sf + 128 + et * 16 + qh * 4);
#pragma unroll
    for (int ks = 0; ks < 2; ks++) {
      half4 a = zb4[ks * 2], b = zb4[ks * 2 + 1];
      half8 zb8 = half8{a[0], a[1], a[2], a[3], b[0], b[1], b[2], b[3]};
#pragma unroll
      for (int et = 0; et < 8; et++)
        acc1[et] = __builtin_amdgcn_mfma_f32_16x16x32_f16(sW1[(et * 2 + ks) * 64 + lane], zb8, acc1[et], 0, 0, 0);
    }
    half4 h4[8];
#pragma unroll
    for (int et = 0; et < 8; et++)
      h4[et] = half4{(f16)gelu_t(acc1[et][0]), (f16)gelu_t(acc1[et][1]),
                     (f16)gelu_t(acc1[et][2]), (f16)gelu_t(acc1[et][3])};
    // ---- FF GEMM2 (K=128 as 4x32 permuted frags) ----
    f32x4 acc2[4];
#pragma unroll
    for (int dt = 0; dt < 4; dt++) acc2[dt] = *(const f32x4*)(sf + 256 + dt * 16 + qh * 4);
#pragma unroll
    for (int ks = 0; ks < 4; ks++) {
      half4 a = h4[ks * 2], b = h4[ks * 2 + 1];
      half8 hb8 = half8{a[0], a[1], a[2], a[3], b[0], b[1], b[2], b[3]};
#pragma unroll
      for (int dt = 0; dt < 4; dt++)
        acc2[dt] = __builtin_amdgcn_mfma_f32_16x16x32_f16(sW2[(dt * 4 + ks) * 64 + lane], hb8, acc2[dt], 0, 0, 0);
    }
    s = 0.f; s2 = 0.f;
#pragma unroll
    for (int dt = 0; dt < 4; dt++) {
#pragma unroll
      for (int r = 0; r < 4; r++) {
        xv[dt][r] += acc2[dt][r];
        s += xv[dt][r]; s2 += xv[dt][r] * xv[dt][r];
      }
      if constexpr (WZ) *(f32x4*)(X + (size_t)pos * 64 + dt * 16 + qh * 4) = xv[dt];
    }
    s += __shfl_xor(s, 16); s += __shfl_xor(s, 32);
    s2 += __shfl_xor(s2, 16); s2 += __shfl_xor(s2, 32);
    float m2 = s * (1.0f / 64.0f);
    float rstd2 = rsqrtf(s2 * (1.0f / 64.0f) - m2 * m2 + 1e-5f);

    if constexpr (WZ) {
      int prow = widx * 16 + pl;
#pragma unroll
      for (int q = 0; q < 4; q++) {
        int d0 = q * 16 + qh * 4;
        f32x4 lw = *(const f32x4*)(sf + 448 + d0);
        f32x4 lb = *(const f32x4*)(sf + 512 + d0);
#pragma unroll
        for (int r = 0; r < 4; r++)
          ztile[(d0 + r) * 132 + prow] = (f16)fmaf((xv[q][r] - m2) * rstd2, lw[r], lb[r]);
      }
      __syncthreads();
      {
        int d = tid >> 3, c0 = (tid & 7) * 16;
        half8 z0 = *(const half8*)(ztile + d * 132 + c0);
        half8 z1 = *(const half8*)(ztile + d * 132 + c0 + 8);
        size_t zoff = (size_t)d * 262144 + (size_t)(blockIdx.x * 8 + k * 4096) * 16;
        *(half8*)(Z16 + zoff + c0) = z0;
        *(half8*)(Z16 + zoff + c0 + 8) = z1;
      }
      __syncthreads();
    } else {
      // ---- fused head: z = normLN(x); u = Wf z + bfb; o = wz . relu(u) + bz ----
      const half8* sWf = (const half8*)(sm + 51456);
      const float* hf = (const float*)(sm + 59648);
      half4 hz[4];
#pragma unroll
      for (int ks = 0; ks < 4; ks++) {
        f32x4 lw = *(const f32x4*)(sf + 448 + ks * 16 + qh * 4);
        f32x4 lb = *(const f32x4*)(sf + 512 + ks * 16 + qh * 4);
        half4 z;
#pragma unroll
        for (int r = 0; r < 4; r++) z[r] = (f16)fmaf((xv[ks][r] - m2) * rstd2, lw[r], lb[r]);
        hz[ks] = z;
      }
      f32x4 acch[4];
#pragma unroll
      for (int et = 0; et < 4; et++) acch[et] = *(const f32x4*)(hf + et * 16 + qh * 4);
#pragma unroll
      for (int ks = 0; ks < 2; ks++) {
        half4 a = hz[ks * 2], b = hz[ks * 2 + 1];
        half8 zb8 = half8{a[0], a[1], a[2], a[3], b[0], b[1], b[2], b[3]};
#pragma unroll
        for (int et = 0; et < 4; et++)
          acch[et] = __builtin_amdgcn_mfma_f32_16x16x32_f16(sWf[(et * 2 + ks) * 64 + lane], zb8, acch[et], 0, 0, 0);
      }
      float o = 0.f;
#pragma unroll
      for (int et = 0; et < 4; et++) {
        f32x4 wzv = *(const f32x4*)(hf + 64 + et * 16 + qh * 4);
#pragma unroll
        for (int r = 0; r < 4; r++) {
          float rv = acch[et][r];
          rv = rv > 0.f ? rv : 0.f;
          o = fmaf(wzv[r], rv, o);
        }
      }
      o += __shfl_xor(o, 16); o += __shfl_xor(o, 32);
      if (qh == 0) outp[pos] = o + hf[128];
    }
  }
}

extern "C" void kernel_launch(void* const* d_in, const int* in_sizes, int n_in,
                              void* d_out, int out_size, void* d_ws, size_t ws_size,
                              hipStream_t stream) {
  (void)in_sizes; (void)n_in; (void)out_size; (void)ws_size;
  const float* inputs   = (const float*)d_in[0];
  const float* w_init   = (const float*)d_in[1];
  const float* b_init   = (const float*)d_in[2];
  const float* s4_ln_w  = (const float*)d_in[3];
  const float* s4_ln_b  = (const float*)d_in[4];
  const float* log_dt   = (const float*)d_in[5];
  const float* log_A    = (const float*)d_in[6];
  const float* A_imag   = (const float*)d_in[7];
  const float* C_re     = (const float*)d_in[8];
  const float* C_im     = (const float*)d_in[9];
  const float* D_skip   = (const float*)d_in[10];
  const float* s4_out_w = (const float*)d_in[11];
  const float* s4_out_b = (const float*)d_in[12];
  const float* ff_ln_w  = (const float*)d_in[13];
  const float* ff_ln_b  = (const float*)d_in[14];
  const float* ff_w1    = (const float*)d_in[15];
  const float* ff_b1    = (const float*)d_in[16];
  const float* ff_w2    = (const float*)d_in[17];
  const float* ff_b2    = (const float*)d_in[18];
  const float* norm_w   = (const float*)d_in[19];
  const float* norm_b   = (const float*)d_in[20];
  const float* w_final1 = (const float*)d_in[21];
  const float* b_final1 = (const float*)d_in[22];
  const float* w_zero   = (const float*)d_in[23];
  const float* b_zero   = (const float*)d_in[24];

  char* w8 = (char*)d_ws;
  size_t off = 0;
  float* X     = (float*)(w8 + off); off += (size_t)67108864;   // [pos][64] f32
  f16*   Z16   = (f16*)(w8 + off);   off += (size_t)33554432;   // [d][pos] f16
  f16*   Y16   = (f16*)(w8 + off);   off += (size_t)33554432;   // [pos][d] f16
  f16*   S16   = (f16*)(w8 + off);   off += (size_t)8388608;    // [d][bc][32] f16
  f16*   Sc    = (f16*)(w8 + off);   off += (size_t)8388608;    // [d][bc][32] f16
  f32x2* LCL   = (f32x2*)(w8 + off); off += 32768;
  f32x2* LC2K  = (f32x2*)(w8 + off); off += 32768;
  half8* TF    = (half8*)(w8 + off); off += (size_t)8388608;    // 4 layers x 2MB
  half8* VF    = (half8*)(w8 + off); off += (size_t)2097152;
  half8* WF    = (half8*)(w8 + off); off += (size_t)2097152;

  k_wtall<<<256, 128, 0, stream>>>(log_dt, log_A, A_imag, C_re, C_im, D_skip,
                                   LCL, LC2K, TF, VF, WF);
  k_init3<<<512, 512, 0, stream>>>(inputs, w_init, b_init, s4_ln_w, s4_ln_b, X, Z16);
  for (int i = 0; i < NLq; i++) {
    k_p1g<<<2048, 256, 0, stream>>>(Z16, WF + (size_t)i * 32768, S16);
    k_pass2<<<512, 256, 0, stream>>>(S16, LCL + i * 1024, LC2K + i * 1024, Sc);
    k_p3g2<<<512, 256, 0, stream>>>(Z16, Sc, TF + (size_t)i * 131072, VF + (size_t)i * 32768, Y16);
    if (i < NLq - 1) {
      k_gluff3<1><<<512, 512, 0, stream>>>(Y16, s4_out_w + i * 8192, s4_out_b + i * 128,
                                           ff_w1 + i * 8192, ff_b1 + i * 128,
                                           ff_w2 + i * 8192, ff_b2 + i * 64,
                                           ff_ln_w + i * 64, ff_ln_b + i * 64,
                                           s4_ln_w + (i + 1) * 64, s4_ln_b + (i + 1) * 64,
                                           X, Z16, nullptr, nullptr, nullptr, nullptr, nullptr);
    } else {
      k_gluff3<0><<<512, 512, 0, stream>>>(Y16, s4_out_w + i * 8192, s4_out_b + i * 128,
                                           ff_w1 + i * 8192, ff_b1 + i * 128,
                                           ff_w2 + i * 8192, ff_b2 + i * 64,
                                           ff_ln_w + i * 64, ff_ln_b + i * 64,
                                           norm_w, norm_b,
                                           X, Z16, w_final1, b_final1, w_zero, b_zero,
                                           (float*)d_out);
    }
  }
}

// Round 11
// 457.218 us; speedup vs baseline: 3.3600x; 1.0274x over previous
//
#include <hip/hip_runtime.h>
#include <cmath>

constexpr int Bq = 8, Lq = 32768, Dq = 64, Nq = 16, NLq = 4;
constexpr int CLq = 128, NCq = 256;           // NCq*CLq == Lq ; chunks per batch
constexpr int PT = Bq * Lq / 16;              // 16384 position-tiles of 16

typedef _Float16 f16;
typedef _Float16 half2t __attribute__((ext_vector_type(2)));
typedef _Float16 half4 __attribute__((ext_vector_type(4)));
typedef _Float16 half8 __attribute__((ext_vector_type(8)));
typedef float f32x4 __attribute__((ext_vector_type(4)));
typedef float f32x2 __attribute__((ext_vector_type(2)));

static __device__ __forceinline__ float sigm(float x) { return 1.0f / (1.0f + __expf(-x)); }
static __device__ __forceinline__ float gelu_t(float x) {
  return x * sigm(1.5957691216057308f * fmaf(0.044715f * x * x, x, x));
}

// -------- k_wtall: setup + all layers' frag-ordered f16 matrices TF/VF/WF; LCL, LC2K --------
__global__ __launch_bounds__(128) void k_wtall(
    const float* __restrict__ log_dt, const float* __restrict__ log_A_real,
    const float* __restrict__ A_imag, const float* __restrict__ C_re,
    const float* __restrict__ C_im, const float* __restrict__ dskip,
    f32x2* __restrict__ LCL, f32x2* __restrict__ LC2K, half8* __restrict__ TF,
    half8* __restrict__ VF, half8* __restrict__ WF) {
  __shared__ f32x2 pw[129][16];
  __shared__ f32x2 lamS[16], dcS[16];
  __shared__ float Ks[128];
  int d = blockIdx.x & 63, L = blockIdx.x >> 6;
  half8* TFl = TF + (size_t)L * 131072;
  half8* VFl = VF + (size_t)L * 32768;
  half8* WFl = WF + (size_t)L * 32768;
  int t = threadIdx.x;
  if (t < 16) {
    int di = L * 64 + d;
    int idx = di * 16 + t;
    float dt = expf(log_dt[di]);
    float Ar = -expf(log_A_real[idx]);
    float Ai = A_imag[idx];
    float dr = Ar * dt, dmi = Ai * dt;
    float er = expf(dr);
    float lr = er * cosf(dmi), li = er * sinf(dmi);
    float inv = 1.0f / (Ar * Ar + Ai * Ai);
    float e1r = lr - 1.0f, e1i = li;
    float qr = (e1r * Ar + e1i * Ai) * inv;
    float qi = (e1i * Ar - e1r * Ai) * inv;
    float cr = C_re[idx], ci = C_im[idx];
    lamS[t] = f32x2{lr, li};
    dcS[t] = f32x2{2.0f * (cr * qr - ci * qi), 2.0f * (cr * qi + ci * qr)};
    float erc = expf(dr * 128.0f);
    f32x2 l128 = f32x2{erc * cosf(dmi * 128.0f), erc * sinf(dmi * 128.0f)};
    pw[128][t] = l128;
    LCL[(size_t)L * 1024 + d * 16 + t] = l128;
    float br = l128.x, bi = l128.y;
#pragma unroll
    for (int q = 0; q < 4; q++) {
      float t2 = br * br - bi * bi;
      bi = 2.f * br * bi; br = t2;
    }
    LC2K[(size_t)L * 1024 + d * 16 + t] = f32x2{br, bi};
  }
  __syncthreads();
#pragma unroll
  for (int n = 0; n < 16; n++) {
    f32x2 lam = lamS[n];
    float pr = 1.f, pi = 0.f, br = lam.x, bi = lam.y;
    int e = t;
    while (e) {
      if (e & 1) { float tt = pr * br - pi * bi; pi = fmaf(pr, bi, pi * br); pr = tt; }
      float t2 = br * br - bi * bi; bi = 2.f * br * bi; br = t2; e >>= 1;
    }
    pw[t][n] = f32x2{pr, pi};
  }
  __syncthreads();
  {
    float k = 0.f;
#pragma unroll
    for (int n = 0; n < 16; n++) {
      f32x2 dc = dcS[n];
      f32x2 p = pw[t][n];
      k += dc.x * p.x - dc.y * p.y;
    }
    if (t == 0) k += dskip[L * 64 + d];
    Ks[t] = k;
  }
  __syncthreads();
  for (int s = t; s < 2048; s += 128) {
    int ln = s & 63, kt = (s >> 6) & 3, mt = s >> 8;
    int jo = mt * 16 + (ln & 15);
    int ji0 = kt * 32 + (ln >> 4) * 8;
    half8 v;
#pragma unroll
    for (int jj = 0; jj < 8; jj++) {
      int ji = ji0 + jj;
      v[jj] = (jo >= ji) ? (f16)Ks[jo - ji] : (f16)0.f;
    }
    TFl[(size_t)d * 2048 + s] = v;
  }
  for (int s = t; s < 512; s += 128) {
    int ln = s & 63, mt = s >> 6;
    int jo = mt * 16 + (ln & 15);
    int q0 = (ln >> 4) * 8;
    half8 v;
#pragma unroll
    for (int jj = 0; jj < 8; jj++) {
      int q = q0 + jj, n = q >> 1;
      f32x2 dc = dcS[n];
      f32x2 p = pw[jo + 1][n];
      float wr = dc.x * p.x - dc.y * p.y;
      float wi = dc.x * p.y + dc.y * p.x;
      v[jj] = (q & 1) ? (f16)(-wi) : (f16)wr;
    }
    VFl[(size_t)d * 512 + s] = v;
  }
  for (int s = t; s < 512; s += 128) {
    int ln = s & 63, kt = (s >> 6) & 3, nt = s >> 8;
    int p_ = nt * 16 + (ln & 15);
    int n = p_ >> 1;
    int j0 = kt * 32 + (ln >> 4) * 8;
    half8 v;
#pragma unroll
    for (int jj = 0; jj < 8; jj++) {
      f32x2 p = pw[127 - (j0 + jj)][n];
      v[jj] = (p_ & 1) ? (f16)p.y : (f16)p.x;
    }
    WFl[(size_t)d * 512 + s] = v;
  }
}

// -------- k_init3: x = relu(w_init*in + b_init) -> X f16; z = s4LN0(x) -> Z16 --------
__global__ __launch_bounds__(512) void k_init3(
    const float* __restrict__ inp, const float* __restrict__ w_init,
    const float* __restrict__ b_init, const float* __restrict__ lnw,
    const float* __restrict__ lnb, f16* __restrict__ X, f16* __restrict__ Z16) {
  __shared__ __align__(16) f16 ztile[64 * 132];
  int tid = threadIdx.x;
  int widx = tid >> 6, lane = tid & 63;
  int pl = lane & 15, qh = lane >> 4;
  for (int k = 0; k < 4; ++k) {
    int pt = blockIdx.x * 8 + widx + k * 4096;
    int pos = pt * 16 + pl;
    float v = inp[pos];
    float s = 0.f, s2 = 0.f;
    f32x4 o[4];
#pragma unroll
    for (int q = 0; q < 4; q++) {
      int d0 = q * 16 + qh * 4;
      f32x4 w4 = *(const f32x4*)(w_init + d0);
      f32x4 b4 = *(const f32x4*)(b_init + d0);
#pragma unroll
      for (int j = 0; j < 4; j++) {
        float t = fmaf(w4[j], v, b4[j]);
        t = t > 0.f ? t : 0.f;
        o[q][j] = t; s += t; s2 += t * t;
      }
      half4 xo = half4{(f16)o[q][0], (f16)o[q][1], (f16)o[q][2], (f16)o[q][3]};
      *(half4*)(X + (size_t)pos * 64 + d0) = xo;
    }
    s += __shfl_xor(s, 16); s += __shfl_xor(s, 32);
    s2 += __shfl_xor(s2, 16); s2 += __shfl_xor(s2, 32);
    float m = s * (1.0f / 64.0f);
    float rstd = rsqrtf(s2 * (1.0f / 64.0f) - m * m + 1e-5f);
    int prow = widx * 16 + pl;
#pragma unroll
    for (int q = 0; q < 4; q++) {
      int d0 = q * 16 + qh * 4;
      f32x4 lw = *(const f32x4*)(lnw + d0);
      f32x4 lb = *(const f32x4*)(lnb + d0);
#pragma unroll
      for (int r = 0; r < 4; r++)
        ztile[(d0 + r) * 132 + prow] = (f16)fmaf((o[q][r] - m) * rstd, lw[r], lb[r]);
    }
    __syncthreads();
    {
      int d = tid >> 3, c0 = (tid & 7) * 16;
      half8 z0 = *(const half8*)(ztile + d * 132 + c0);
      half8 z1 = *(const half8*)(ztile + d * 132 + c0 + 8);
      size_t zoff = (size_t)d * 262144 + (size_t)(blockIdx.x * 8 + k * 4096) * 16;
      *(half8*)(Z16 + zoff + c0) = z0;
      *(half8*)(Z16 + zoff + c0 + 8) = z1;
    }
    __syncthreads();
  }
}

// -------- k_p1g: chunk end-states S16[d][bc][p32] = Z(m=bc,k=j) @ Wend(k=j,n=p) --------
__global__ __launch_bounds__(256) void k_p1g(
    const f16* __restrict__ Z16, const half8* __restrict__ WF, f16* __restrict__ S16) {
  int tid = threadIdx.x;
  int lane = tid & 63;
  int task = blockIdx.x * 4 + (tid >> 6);
  int d = task >> 7, bct = task & 127;
  int bc0 = bct * 16;
  int pl = lane & 15, qh = lane >> 4;
  half8 az[4];
  const f16* zp = Z16 + ((size_t)d * 2048 + bc0 + pl) * 128 + qh * 8;
#pragma unroll
  for (int kt = 0; kt < 4; kt++) az[kt] = *(const half8*)(zp + kt * 32);
#pragma unroll
  for (int nt = 0; nt < 2; nt++) {
    f32x4 acc = f32x4{0.f, 0.f, 0.f, 0.f};
#pragma unroll
    for (int kt = 0; kt < 4; kt++)
      acc = __builtin_amdgcn_mfma_f32_16x16x32_f16(az[kt], WF[(size_t)d * 512 + (nt * 4 + kt) * 64 + lane], acc, 0, 0, 0);
#pragma unroll
    for (int r = 0; r < 4; r++)
      S16[((size_t)d * 2048 + bc0 + qh * 4 + r) * 32 + nt * 16 + pl] = (f16)acc[r];
  }
}

// -------- k_pass2: 3-phase block-local scan. grid 512 = (d,b); 256 thr = (g16, n16) --------
__global__ __launch_bounds__(256) void k_pass2(
    const f16* __restrict__ S16, const f32x2* __restrict__ LCLl,
    const f32x2* __restrict__ LC2Kl, f16* __restrict__ Sc) {
  __shared__ f32x2 gc[16][17];
  int blk = blockIdx.x;               // d*8 + b
  int d = blk >> 3, b = blk & 7;
  int t = threadIdx.x;                // g*16 + n
  int n = t & 15, g = t >> 4;
  f32x2 lam = LCLl[d * 16 + n];
  size_t base = ((size_t)d * 2048 + b * 256 + g * 16) * 32 + 2 * n;
  const f16* sp = S16 + base;
  float cr = 0.f, ci = 0.f;
#pragma unroll 4
  for (int j = 0; j < 16; j++) {
    half2t v = *(const half2t*)(sp + (size_t)j * 32);
    float nr = fmaf(lam.x, cr, fmaf(-lam.y, ci, (float)v[0]));
    float ni = fmaf(lam.x, ci, fmaf(lam.y, cr, (float)v[1]));
    cr = nr; ci = ni;
  }
  gc[g][n] = f32x2{cr, ci};
  __syncthreads();
  f32x2 l2 = LC2Kl[d * 16 + n];
  float er = 0.f, ei = 0.f;
  for (int gg = 0; gg < g; gg++) {
    f32x2 c = gc[gg][n];
    float nr = fmaf(l2.x, er, fmaf(-l2.y, ei, c.x));
    float ni = fmaf(l2.x, ei, fmaf(l2.y, er, c.y));
    er = nr; ei = ni;
  }
  f16* cp = Sc + base;
  float cr2 = er, ci2 = ei;
#pragma unroll 4
  for (int j = 0; j < 16; j++) {
    *(half2t*)(cp + (size_t)j * 32) = half2t{(f16)cr2, (f16)ci2};
    half2t v = *(const half2t*)(sp + (size_t)j * 32);
    float nr = fmaf(lam.x, cr2, fmaf(-lam.y, ci2, (float)v[0]));
    float ni = fmaf(lam.x, ci2, fmaf(lam.y, cr2, (float)v[1]));
    cr2 = nr; ci2 = ni;
  }
}

// -------- k_p3g2: y = T@z + V@carry, gelu -> Y16[pos][d] (d-packed half4) --------
__global__ __launch_bounds__(256) void k_p3g2(
    const f16* __restrict__ Z16, const f16* __restrict__ Sc,
    const half8* __restrict__ TF, const half8* __restrict__ VF,
    f16* __restrict__ Y16) {
  int tid = threadIdx.x;
  int lane = tid & 63, widx = tid >> 6;
  int bct = blockIdx.x & 127, dg = blockIdx.x >> 7;  // grid 512: 4 dg x 128 bct
  int bc0 = bct * 16;
  int dbase = dg * 16 + widx * 4;
  int pl = lane & 15, qh = lane >> 4;
  half8 zb[4][4];
  half8 sb[4];
#pragma unroll
  for (int di = 0; di < 4; di++) {
    int d = dbase + di;
    const f16* zp = Z16 + ((size_t)d * 2048 + bc0 + pl) * 128 + qh * 8;
#pragma unroll
    for (int kt = 0; kt < 4; kt++) zb[di][kt] = *(const half8*)(zp + kt * 32);
    sb[di] = *(const half8*)(Sc + ((size_t)d * 2048 + bc0 + pl) * 32 + qh * 8);
  }
#pragma unroll
  for (int mt = 0; mt < 8; mt++) {
    const int KTM = mt / 2 + 1;  // causal: tiles with ji0 <= jo_max
    f32x4 acc[4];
#pragma unroll
    for (int di = 0; di < 4; di++) {
      int d = dbase + di;
      acc[di] = f32x4{0.f, 0.f, 0.f, 0.f};
      const half8* tfp = TF + ((size_t)d * 8 + mt) * 256 + lane;
#pragma unroll
      for (int kt = 0; kt < KTM; kt++)
        acc[di] = __builtin_amdgcn_mfma_f32_16x16x32_f16(tfp[kt * 64], zb[di][kt], acc[di], 0, 0, 0);
      acc[di] = __builtin_amdgcn_mfma_f32_16x16x32_f16(VF[((size_t)d * 8 + mt) * 64 + lane], sb[di], acc[di], 0, 0, 0);
    }
#pragma unroll
    for (int r = 0; r < 4; r++) {
      int pos = (bc0 + pl) * 128 + mt * 16 + qh * 4 + r;
      half4 pk = half4{(f16)gelu_t(acc[0][r]), (f16)gelu_t(acc[1][r]),
                       (f16)gelu_t(acc[2][r]), (f16)gelu_t(acc[3][r])};
      *(half4*)(Y16 + (size_t)pos * 64 + dbase) = pk;
    }
  }
}

// ======== Fused GLU+FF(+next-layer z | +head); X residual stored f16, f32 in-register ========
template <int WZ>
__global__ __launch_bounds__(512) void k_gluff3(
    const f16* __restrict__ Y16, const float* __restrict__ Wg, const float* __restrict__ bg,
    const float* __restrict__ W1, const float* __restrict__ b1,
    const float* __restrict__ W2, const float* __restrict__ b2,
    const float* __restrict__ lnw, const float* __restrict__ lnb,
    const float* __restrict__ nlnw, const float* __restrict__ nlnb,
    f16* __restrict__ X, f16* __restrict__ Z16,
    const float* __restrict__ Wf, const float* __restrict__ bfb,
    const float* __restrict__ wz, const float* __restrict__ bz,
    float* __restrict__ outp) {
  __shared__ __align__(16) char smem[68352];
  int tid = threadIdx.x;
#pragma unroll
  for (int it = 0; it < 2; it++) {           // sWg: NATURAL k
    int s = it * 512 + tid;
    int l = s & 63, ks = (s >> 6) & 1, et = s >> 7;
    const float* wp = Wg + (et * 16 + (l & 15)) * 64 + ks * 32 + (l >> 4) * 8;
    f32x4 w0 = *(const f32x4*)wp, w1 = *(const f32x4*)(wp + 4);
    *(half8*)(smem + s * 16) = half8{(f16)w0[0], (f16)w0[1], (f16)w0[2], (f16)w0[3],
                                     (f16)w1[0], (f16)w1[1], (f16)w1[2], (f16)w1[3]};
  }
#pragma unroll
  for (int it = 0; it < 2; it++) {           // sW1: PERMUTED k
    int s = it * 512 + tid;
    int l = s & 63, ks = (s >> 6) & 1, et = s >> 7;
    int pls = l & 15, qhs = l >> 4;
    const float* wp = W1 + (et * 16 + pls) * 64 + ks * 32 + qhs * 4;
    f32x4 w0 = *(const f32x4*)wp;
    f32x4 w1 = *(const f32x4*)(wp + 16);
    *(half8*)(smem + 16384 + s * 16) = half8{(f16)w0[0], (f16)w0[1], (f16)w0[2], (f16)w0[3],
                                             (f16)w1[0], (f16)w1[1], (f16)w1[2], (f16)w1[3]};
  }
#pragma unroll
  for (int it = 0; it < 2; it++) {           // sW2: PERMUTED k
    int s = it * 512 + tid;
    int l = s & 63, ks = (s >> 6) & 3, dt = s >> 8;
    int pls = l & 15, qhs = l >> 4;
    const float* wp = W2 + (dt * 16 + pls) * 128 + ks * 32 + qhs * 4;
    f32x4 w0 = *(const f32x4*)wp;
    f32x4 w1 = *(const f32x4*)(wp + 16);
    *(half8*)(smem + 32768 + s * 16) = half8{(f16)w0[0], (f16)w0[1], (f16)w0[2], (f16)w0[3],
                                             (f16)w1[0], (f16)w1[1], (f16)w1[2], (f16)w1[3]};
  }
  for (int idx = tid; idx < 576; idx += 512) {
    float v;
    if (idx < 128) v = bg[idx];
    else if (idx < 256) v = b1[idx - 128];
    else if (idx < 320) v = b2[idx - 256];
    else if (idx < 384) v = lnw[idx - 320];
    else if (idx < 448) v = lnb[idx - 384];
    else if (idx < 512) v = nlnw[idx - 448];
    else v = nlnb[idx - 512];
    ((float*)(smem + 49152))[idx] = v;
  }
  if constexpr (!WZ) {
    if (tid < 512) {                         // sWf: PERMUTED k (head GEMM)
      int s = tid;
      int l = s & 63, ks = (s >> 6) & 1, et = s >> 7;  // et < 4
      int pls = l & 15, qhs = l >> 4;
      const float* wp = Wf + (et * 16 + pls) * 64 + ks * 32 + qhs * 4;
      f32x4 w0 = *(const f32x4*)wp;
      f32x4 w1 = *(const f32x4*)(wp + 16);
      *(half8*)(smem + 51456 + s * 16) = half8{(f16)w0[0], (f16)w0[1], (f16)w0[2], (f16)w0[3],
                                               (f16)w1[0], (f16)w1[1], (f16)w1[2], (f16)w1[3]};
    }
    if (tid < 129) {
      float v = tid < 64 ? bfb[tid] : (tid < 128 ? wz[tid - 64] : bz[0]);
      ((float*)(smem + 59648))[tid] = v;
    }
  }
  __syncthreads();
  int lane = tid & 63, pl = lane & 15, qh = lane >> 4;
  int widx = tid >> 6;
  f16* ztile = (f16*)(smem + 51456);

  for (int k = 0; k < 4; ++k) {
    int pt = blockIdx.x * 8 + widx + k * 4096;
    int pos = pt * 16 + pl;
    half8 yb0 = *(const half8*)(Y16 + (size_t)pos * 64 + qh * 8);
    half8 yb1 = *(const half8*)(Y16 + (size_t)pos * 64 + 32 + qh * 8);
    f32x4 xv[4];
#pragma unroll
    for (int q = 0; q < 4; q++) {
      half4 xh = *(const half4*)(X + (size_t)pos * 64 + q * 16 + qh * 4);
#pragma unroll
      for (int r = 0; r < 4; r++) xv[q][r] = (float)xh[r];
    }

    unsigned sb = 0;
    asm volatile("" : "+v"(sb));                // opaque: defeats LICM (anti-spill, R4-proven)
    const char* sm = smem + sb;
    const half8* sWg = (const half8*)sm;
    const half8* sW1 = (const half8*)(sm + 16384);
    const half8* sW2 = (const half8*)(sm + 32768);
    const float* sf = (const float*)(sm + 49152);
    // ---- GLU ----
    f32x4 accg[8];
#pragma unroll
    for (int et = 0; et < 8; et++) accg[et] = *(const f32x4*)(sf + et * 16 + qh * 4);
#pragma unroll
    for (int et = 0; et < 8; et++)
      accg[et] = __builtin_amdgcn_mfma_f32_16x16x32_f16(sWg[(et * 2) * 64 + lane], yb0, accg[et], 0, 0, 0);
#pragma unroll
    for (int et = 0; et < 8; et++)
      accg[et] = __builtin_amdgcn_mfma_f32_16x16x32_f16(sWg[(et * 2 + 1) * 64 + lane], yb1, accg[et], 0, 0, 0);
    float s = 0.f, s2 = 0.f;
#pragma unroll
    for (int q = 0; q < 4; q++)
#pragma unroll
      for (int r = 0; r < 4; r++) {
        xv[q][r] += accg[q][r] * sigm(accg[q + 4][r]);
        s += xv[q][r]; s2 += xv[q][r] * xv[q][r];
      }
    s += __shfl_xor(s, 16); s += __shfl_xor(s, 32);
    s2 += __shfl_xor(s2, 16); s2 += __shfl_xor(s2, 32);
    float m = s * (1.0f / 64.0f);
    float rstd = rsqrtf(s2 * (1.0f / 64.0f) - m * m + 1e-5f);
    // ---- FF GEMM1 (K=32 permuted frags) ----
    half4 zb4[4];
#pragma unroll
    for (int ks = 0; ks < 4; ks++) {
      f32x4 lw = *(const f32x4*)(sf + 320 + ks * 16 + qh * 4);
      f32x4 lb = *(const f32x4*)(sf + 384 + ks * 16 + qh * 4);
      half4 z;
#pragma unroll
      for (int r = 0; r < 4; r++) z[r] = (f16)fmaf((xv[ks][r] - m) * rstd, lw[r], lb[r]);
      zb4[ks] = z;
    }
    f32x4 acc1[8];
#pragma unroll
    for (int et = 0; et < 8; et++) acc1[et] = *(const f32x4*)(sf + 128 + et * 16 + qh * 4);
#pragma unroll
    for (int ks = 0; ks < 2; ks++) {
      half4 a = zb4[ks * 2], b = zb4[ks * 2 + 1];
      half8 zb8 = half8{a[0], a[1], a[2], a[3], b[0], b[1], b[2], b[3]};
#pragma unroll
      for (int et = 0; et < 8; et++)
        acc1[et] = __builtin_amdgcn_mfma_f32_16x16x32_f16(sW1[(et * 2 + ks) * 64 + lane], zb8, acc1[et], 0, 0, 0);
    }
    half4 h4[8];
#pragma unroll
    for (int et = 0; et < 8; et++)
      h4[et] = half4{(f16)gelu_t(acc1[et][0]), (f16)gelu_t(acc1[et][1]),
                     (f16)gelu_t(acc1[et][2]), (f16)gelu_t(acc1[et][3])};
    // ---- FF GEMM2 (K=128 as 4x32 permuted frags) ----
    f32x4 acc2[4];
#pragma unroll
    for (int dt = 0; dt < 4; dt++) acc2[dt] = *(const f32x4*)(sf + 256 + dt * 16 + qh * 4);
#pragma unroll
    for (int ks = 0; ks < 4; ks++) {
      half4 a = h4[ks * 2], b = h4[ks * 2 + 1];
      half8 hb8 = half8{a[0], a[1], a[2], a[3], b[0], b[1], b[2], b[3]};
#pragma unroll
      for (int dt = 0; dt < 4; dt++)
        acc2[dt] = __builtin_amdgcn_mfma_f32_16x16x32_f16(sW2[(dt * 4 + ks) * 64 + lane], hb8, acc2[dt], 0, 0, 0);
    }
    s = 0.f; s2 = 0.f;
#pragma unroll
    for (int dt = 0; dt < 4; dt++) {
#pragma unroll
      for (int r = 0; r < 4; r++) {
        xv[dt][r] += acc2[dt][r];
        s += xv[dt][r]; s2 += xv[dt][r] * xv[dt][r];
      }
      if constexpr (WZ) {
        half4 xo = half4{(f16)xv[dt][0], (f16)xv[dt][1], (f16)xv[dt][2], (f16)xv[dt][3]};
        *(half4*)(X + (size_t)pos * 64 + dt * 16 + qh * 4) = xo;
      }
    }
    s += __shfl_xor(s, 16); s += __shfl_xor(s, 32);
    s2 += __shfl_xor(s2, 16); s2 += __shfl_xor(s2, 32);
    float m2 = s * (1.0f / 64.0f);
    float rstd2 = rsqrtf(s2 * (1.0f / 64.0f) - m2 * m2 + 1e-5f);

    if constexpr (WZ) {
      int prow = widx * 16 + pl;
#pragma unroll
      for (int q = 0; q < 4; q++) {
        int d0 = q * 16 + qh * 4;
        f32x4 lw = *(const f32x4*)(sf + 448 + d0);
        f32x4 lb = *(const f32x4*)(sf + 512 + d0);
#pragma unroll
        for (int r = 0; r < 4; r++)
          ztile[(d0 + r) * 132 + prow] = (f16)fmaf((xv[q][r] - m2) * rstd2, lw[r], lb[r]);
      }
      __syncthreads();
      {
        int d = tid >> 3, c0 = (tid & 7) * 16;
        half8 z0 = *(const half8*)(ztile + d * 132 + c0);
        half8 z1 = *(const half8*)(ztile + d * 132 + c0 + 8);
        size_t zoff = (size_t)d * 262144 + (size_t)(blockIdx.x * 8 + k * 4096) * 16;
        *(half8*)(Z16 + zoff + c0) = z0;
        *(half8*)(Z16 + zoff + c0 + 8) = z1;
      }
      __syncthreads();
    } else {
      // ---- fused head: z = normLN(x); u = Wf z + bfb; o = wz . relu(u) + bz ----
      const half8* sWf = (const half8*)(sm + 51456);
      const float* hf = (const float*)(sm + 59648);
      half4 hz[4];
#pragma unroll
      for (int ks = 0; ks < 4; ks++) {
        f32x4 lw = *(const f32x4*)(sf + 448 + ks * 16 + qh * 4);
        f32x4 lb = *(const f32x4*)(sf + 512 + ks * 16 + qh * 4);
        half4 z;
#pragma unroll
        for (int r = 0; r < 4; r++) z[r] = (f16)fmaf((xv[ks][r] - m2) * rstd2, lw[r], lb[r]);
        hz[ks] = z;
      }
      f32x4 acch[4];
#pragma unroll
      for (int et = 0; et < 4; et++) acch[et] = *(const f32x4*)(hf + et * 16 + qh * 4);
#pragma unroll
      for (int ks = 0; ks < 2; ks++) {
        half4 a = hz[ks * 2], b = hz[ks * 2 + 1];
        half8 zb8 = half8{a[0], a[1], a[2], a[3], b[0], b[1], b[2], b[3]};
#pragma unroll
        for (int et = 0; et < 4; et++)
          acch[et] = __builtin_amdgcn_mfma_f32_16x16x32_f16(sWf[(et * 2 + ks) * 64 + lane], zb8, acch[et], 0, 0, 0);
      }
      float o = 0.f;
#pragma unroll
      for (int et = 0; et < 4; et++) {
        f32x4 wzv = *(const f32x4*)(hf + 64 + et * 16 + qh * 4);
#pragma unroll
        for (int r = 0; r < 4; r++) {
          float rv = acch[et][r];
          rv = rv > 0.f ? rv : 0.f;
          o = fmaf(wzv[r], rv, o);
        }
      }
      o += __shfl_xor(o, 16); o += __shfl_xor(o, 32);
      if (qh == 0) outp[pos] = o + hf[128];
    }
  }
}

extern "C" void kernel_launch(void* const* d_in, const int* in_sizes, int n_in,
                              void* d_out, int out_size, void* d_ws, size_t ws_size,
                              hipStream_t stream) {
  (void)in_sizes; (void)n_in; (void)out_size; (void)ws_size;
  const float* inputs   = (const float*)d_in[0];
  const float* w_init   = (const float*)d_in[1];
  const float* b_init   = (const float*)d_in[2];
  const float* s4_ln_w  = (const float*)d_in[3];
  const float* s4_ln_b  = (const float*)d_in[4];
  const float* log_dt   = (const float*)d_in[5];
  const float* log_A    = (const float*)d_in[6];
  const float* A_imag   = (const float*)d_in[7];
  const float* C_re     = (const float*)d_in[8];
  const float* C_im     = (const float*)d_in[9];
  const float* D_skip   = (const float*)d_in[10];
  const float* s4_out_w = (const float*)d_in[11];
  const float* s4_out_b = (const float*)d_in[12];
  const float* ff_ln_w  = (const float*)d_in[13];
  const float* ff_ln_b  = (const float*)d_in[14];
  const float* ff_w1    = (const float*)d_in[15];
  const float* ff_b1    = (const float*)d_in[16];
  const float* ff_w2    = (const float*)d_in[17];
  const float* ff_b2    = (const float*)d_in[18];
  const float* norm_w   = (const float*)d_in[19];
  const float* norm_b   = (const float*)d_in[20];
  const float* w_final1 = (const float*)d_in[21];
  const float* b_final1 = (const float*)d_in[22];
  const float* w_zero   = (const float*)d_in[23];
  const float* b_zero   = (const float*)d_in[24];

  char* w8 = (char*)d_ws;
  size_t off = 0;
  f16*   X     = (f16*)(w8 + off);   off += (size_t)33554432;   // [pos][64] f16
  f16*   Z16   = (f16*)(w8 + off);   off += (size_t)33554432;   // [d][pos] f16
  f16*   Y16   = (f16*)(w8 + off);   off += (size_t)33554432;   // [pos][d] f16
  f16*   S16   = (f16*)(w8 + off);   off += (size_t)8388608;    // [d][bc][32] f16
  f16*   Sc    = (f16*)(w8 + off);   off += (size_t)8388608;    // [d][bc][32] f16
  f32x2* LCL   = (f32x2*)(w8 + off); off += 32768;
  f32x2* LC2K  = (f32x2*)(w8 + off); off += 32768;
  half8* TF    = (half8*)(w8 + off); off += (size_t)8388608;    // 4 layers x 2MB
  half8* VF    = (half8*)(w8 + off); off += (size_t)2097152;
  half8* WF    = (half8*)(w8 + off); off += (size_t)2097152;

  k_wtall<<<256, 128, 0, stream>>>(log_dt, log_A, A_imag, C_re, C_im, D_skip,
                                   LCL, LC2K, TF, VF, WF);
  k_init3<<<512, 512, 0, stream>>>(inputs, w_init, b_init, s4_ln_w, s4_ln_b, X, Z16);
  for (int i = 0; i < NLq; i++) {
    k_p1g<<<2048, 256, 0, stream>>>(Z16, WF + (size_t)i * 32768, S16);
    k_pass2<<<512, 256, 0, stream>>>(S16, LCL + i * 1024, LC2K + i * 1024, Sc);
    k_p3g2<<<512, 256, 0, stream>>>(Z16, Sc, TF + (size_t)i * 131072, VF + (size_t)i * 32768, Y16);
    if (i < NLq - 1) {
      k_gluff3<1><<<512, 512, 0, stream>>>(Y16, s4_out_w + i * 8192, s4_out_b + i * 128,
                                           ff_w1 + i * 8192, ff_b1 + i * 128,
                                           ff_w2 + i * 8192, ff_b2 + i * 64,
                                           ff_ln_w + i * 64, ff_ln_b + i * 64,
                                           s4_ln_w + (i + 1) * 64, s4_ln_b + (i + 1) * 64,
                                           X, Z16, nullptr, nullptr, nullptr, nullptr, nullptr);
    } else {
      k_gluff3<0><<<512, 512, 0, stream>>>(Y16, s4_out_w + i * 8192, s4_out_b + i * 128,
                                           ff_w1 + i * 8192, ff_b1 + i * 128,
                                           ff_w2 + i * 8192, ff_b2 + i * 64,
                                           ff_ln_w + i * 64, ff_ln_b + i * 64,
                                           norm_w, norm_b,
                                           X, Z16, w_final1, b_final1, w_zero, b_zero,
                                           (float*)d_out);
    }
  }
}